// Round 3
// baseline (2334.853 us; speedup 1.0000x reference)
//
#include <hip/hip_runtime.h>
#include <math.h>

typedef unsigned long long u64;
typedef unsigned int u32;

#define B_ 4
#define N_ 8192
#define K_ 16
#define W0_ 64
#define W1_ 128
#define W2_ 256
#define PH_ 16   // points per block in head kernel

// ---------------- prep: coords4 (x,y,z_eff,xx) + stem MLP ----------------
__global__ __launch_bounds__(64) void prep_kernel(
    const float* __restrict__ x,
    const float* __restrict__ stem_w, const float* __restrict__ stem_b,
    const float* __restrict__ hmix_a, const float* __restrict__ hmix_b,
    const float* __restrict__ hmix_c,
    float* __restrict__ coords4, float* __restrict__ f0) {
  const int p = blockIdx.x;          // global point 0..B*N-1
  const int o = threadIdx.x;         // 0..63
  const float x0 = x[p*4+0], x1 = x[p*4+1], x2 = x[p*4+2], x3 = x[p*4+3];
  float acc = stem_b[o];
  acc += x0*stem_w[0*W0_+o];
  acc += x1*stem_w[1*W0_+o];
  acc += x2*stem_w[2*W0_+o];
  acc += x3*stem_w[3*W0_+o];
  f0[p*W0_+o] = fmaxf(acc, 0.f);
  if (o == 0) {
    const float z  = hmix_a[0]*x2 + hmix_b[0]*x3 + hmix_c[0];
    const float xx = x0*x0 + x1*x1 + z*z;
    ((float4*)coords4)[p] = make_float4(x0, x1, z, xx);
  }
}

// ---------------- knn: one wave per 2 points (threshold-filtered exact top-16) ----------------
__global__ __launch_bounds__(64) void knn_kernel(
    const float* __restrict__ coords4, int* __restrict__ knn_idx) {
  const int p0 = blockIdx.x * 2;
  const int p1 = p0 + 1;
  const int b = p0 >> 13;
  const int lane = threadIdx.x;
  const float4* cb = ((const float4*)coords4) + (b << 13);
  const float4 c0 = ((const float4*)coords4)[p0];
  const float4 c1 = ((const float4*)coords4)[p1];

  u64 lk0 = ~0ull, lk1 = ~0ull;
  u64 k15_0 = ~0ull, k15_1 = ~0ull;
  float T0 = INFINITY, T1 = INFINITY;

  for (int it = 0; it < N_/64; ++it) {
    const int j = lane + it*64;
    const float4 cj = cb[j];
    float d0 = c0.w + cj.w - 2.f*(c0.x*cj.x + c0.y*cj.y + c0.z*cj.z);
    float d1 = c1.w + cj.w - 2.f*(c1.x*cj.x + c1.y*cj.y + c1.z*cj.z);
    d0 = fmaxf(d0, 0.f);
    d1 = fmaxf(d1, 0.f);

    u64 m0 = __ballot(d0 <= T0);
    while (m0) {
      const int s = (int)__ffsll((unsigned long long)m0) - 1;
      m0 &= m0 - 1;
      const float dc = __shfl(d0, s, 64);
      const u64 ck = ((u64)__float_as_uint(dc) << 32) | (u32)(s + it*64);
      if (ck < k15_0) {
        const bool cond = ck < lk0;
        const u64 pk = __shfl_up(lk0, 1, 64);
        const bool pc = (__shfl_up((int)cond, 1, 64) != 0) && (lane > 0);
        lk0 = cond ? (pc ? pk : ck) : lk0;
        k15_0 = __shfl(lk0, 15, 64);
        T0 = __uint_as_float((u32)(k15_0 >> 32));
      }
    }

    u64 m1 = __ballot(d1 <= T1);
    while (m1) {
      const int s = (int)__ffsll((unsigned long long)m1) - 1;
      m1 &= m1 - 1;
      const float dc = __shfl(d1, s, 64);
      const u64 ck = ((u64)__float_as_uint(dc) << 32) | (u32)(s + it*64);
      if (ck < k15_1) {
        const bool cond = ck < lk1;
        const u64 pk = __shfl_up(lk1, 1, 64);
        const bool pc = (__shfl_up((int)cond, 1, 64) != 0) && (lane > 0);
        lk1 = cond ? (pc ? pk : ck) : lk1;
        k15_1 = __shfl(lk1, 15, 64);
        T1 = __uint_as_float((u32)(k15_1 >> 32));
      }
    }
  }

  if (lane < K_) {
    knn_idx[p0*K_ + lane] = (int)(u32)(lk0 & 0xffffffffull);
    knn_idx[p1*K_ + lane] = (int)(u32)(lk1 & 0xffffffffull);
  }
}

// ---------------- local_agg: thread = (og,kg) owns 4 outputs x 4 neighbors ----------------
// per d: 1 ds_read_b128 (broadcast) + 1 global float4 + 16 FMA -> VALU-bound
template<int DIN, int DOUT>
__global__ __launch_bounds__(DOUT) void agg_kernel(
    const float* __restrict__ fin, const float* __restrict__ coords4,
    const int* __restrict__ knn_idx, const float* __restrict__ w,
    const float* __restrict__ bw, float* __restrict__ fout) {
  const int p = blockIdx.x;
  const int b = p >> 13;
  const int o = threadIdx.x;
  __shared__ float s_fi[DIN];
  __shared__ float s_nbT[DIN][K_];   // [d][k]
  __shared__ float s_np[K_][3];
  __shared__ int   s_idx[K_];

  if (o < K_) s_idx[o] = knn_idx[p*K_ + o];
  if (o < DIN) s_fi[o] = fin[p*DIN + o];
  __syncthreads();

  for (int t = o; t < K_*DIN/4; t += DOUT) {
    const int k  = t & (K_-1);
    const int dq = t >> 4;
    const float4 v = *(const float4*)&fin[(((size_t)(b<<13) + s_idx[k]))*DIN + dq*4];
    s_nbT[dq*4+0][k] = v.x; s_nbT[dq*4+1][k] = v.y;
    s_nbT[dq*4+2][k] = v.z; s_nbT[dq*4+3][k] = v.w;
  }
  if (o < K_) {
    const float4 c = ((const float4*)coords4)[(b<<13) + s_idx[o]];
    s_np[o][0] = c.x; s_np[o][1] = c.y; s_np[o][2] = c.z;
  }
  __syncthreads();

  const int og = o >> 2;
  const int kg = o & 3;
  const int oo = og * 4;

  const float4 ci  = ((const float4*)coords4)[p];
  const float4 wp0 = *(const float4*)&w[(2*DIN+0)*DOUT + oo];
  const float4 wp1 = *(const float4*)&w[(2*DIN+1)*DOUT + oo];
  const float4 wp2 = *(const float4*)&w[(2*DIN+2)*DOUT + oo];
  const float4 bw4 = *(const float4*)&bw[oo];

  // k-independent part, d-range split across the kg quad, shfl-summed
  float bp[4] = {0.f, 0.f, 0.f, 0.f};
  for (int d = kg*(DIN/4); d < (kg+1)*(DIN/4); ++d) {
    const float fi = s_fi[d];
    const float4 ws = *(const float4*)&w[d*DOUT + oo];
    const float4 wm = *(const float4*)&w[(DIN+d)*DOUT + oo];
    bp[0] += fi*(ws.x - wm.x);
    bp[1] += fi*(ws.y - wm.y);
    bp[2] += fi*(ws.z - wm.z);
    bp[3] += fi*(ws.w - wm.w);
  }
#pragma unroll
  for (int oi = 0; oi < 4; ++oi) {
    bp[oi] += __shfl_xor(bp[oi], 1, 64);
    bp[oi] += __shfl_xor(bp[oi], 2, 64);
  }
  bp[0] += bw4.x - (ci.x*wp0.x + ci.y*wp1.x + ci.z*wp2.x);
  bp[1] += bw4.y - (ci.x*wp0.y + ci.y*wp1.y + ci.z*wp2.y);
  bp[2] += bw4.z - (ci.x*wp0.z + ci.y*wp1.z + ci.z*wp2.z);
  bp[3] += bw4.w - (ci.x*wp0.w + ci.y*wp1.w + ci.z*wp2.w);

  float acc[4][4];   // [oi][ki]
#pragma unroll
  for (int ki = 0; ki < 4; ++ki) {
    const int kk = kg*4 + ki;
    const float nx = s_np[kk][0], ny = s_np[kk][1], nz = s_np[kk][2];
    acc[0][ki] = bp[0] + nx*wp0.x + ny*wp1.x + nz*wp2.x;
    acc[1][ki] = bp[1] + nx*wp0.y + ny*wp1.y + nz*wp2.y;
    acc[2][ki] = bp[2] + nx*wp0.z + ny*wp1.z + nz*wp2.z;
    acc[3][ki] = bp[3] + nx*wp0.w + ny*wp1.w + nz*wp2.w;
  }

  for (int d = 0; d < DIN; ++d) {
    const float4 nb = *(const float4*)&s_nbT[d][kg*4];
    const float4 wm = *(const float4*)&w[(DIN+d)*DOUT + oo];
    acc[0][0] += nb.x*wm.x; acc[0][1] += nb.y*wm.x; acc[0][2] += nb.z*wm.x; acc[0][3] += nb.w*wm.x;
    acc[1][0] += nb.x*wm.y; acc[1][1] += nb.y*wm.y; acc[1][2] += nb.z*wm.y; acc[1][3] += nb.w*wm.y;
    acc[2][0] += nb.x*wm.z; acc[2][1] += nb.y*wm.z; acc[2][2] += nb.z*wm.z; acc[2][3] += nb.w*wm.z;
    acc[3][0] += nb.x*wm.w; acc[3][1] += nb.y*wm.w; acc[3][2] += nb.z*wm.w; acc[3][3] += nb.w*wm.w;
  }

  float m[4];
#pragma unroll
  for (int oi = 0; oi < 4; ++oi) {
    m[oi] = fmaxf(fmaxf(acc[oi][0], acc[oi][1]), fmaxf(acc[oi][2], acc[oi][3]));
    m[oi] = fmaxf(m[oi], 0.f);       // relu folded into max
    m[oi] = fmaxf(m[oi], __shfl_xor(m[oi], 1, 64));
    m[oi] = fmaxf(m[oi], __shfl_xor(m[oi], 2, 64));
  }
  const float v = (kg == 0) ? m[0] : (kg == 1) ? m[1] : (kg == 2) ? m[2] : m[3];
  fout[p*DOUT + oo + kg] = v;        // lane t writes element t: coalesced
}

// ---------------- global max (stage 1: partial over 256-point segments) ----------------
__global__ __launch_bounds__(256) void gmax_kernel(
    const float* __restrict__ f2, float* __restrict__ part) {
  const int b = blockIdx.x >> 5;
  const int seg = blockIdx.x & 31;
  const int o = threadIdx.x;
  float m = -INFINITY;
  const int n0 = seg * 256;
  for (int n = n0; n < n0 + 256; ++n)
    m = fmaxf(m, f2[((size_t)(b<<13) + n)*W2_ + o]);
  part[(size_t)blockIdx.x*W2_ + o] = m;
}

// ---------------- global max reduce + glob FC ----------------
__global__ __launch_bounds__(256) void gfc_kernel(
    const float* __restrict__ part, const float* __restrict__ gw,
    const float* __restrict__ gb, float* __restrict__ g2) {
  const int b = blockIdx.x;
  const int o = threadIdx.x;
  __shared__ float s_g[W2_];
  float m = -INFINITY;
  for (int s = 0; s < 32; ++s) m = fmaxf(m, part[(size_t)(b*32+s)*W2_ + o]);
  s_g[o] = m;
  __syncthreads();
  float acc = gb[o];
  for (int d = 0; d < W2_; ++d) acc += s_g[d]*gw[d*W2_ + o];
  g2[b*W2_ + o] = fmaxf(acc, 0.f);
}

// ---------------- head: 16 points/block, thread = (og,pg) owns 4 outputs x 4 points ----------------
__global__ __launch_bounds__(256) void head_kernel(
    const float* __restrict__ f2, const float* __restrict__ g2,
    const float* __restrict__ h1w, const float* __restrict__ h1b,
    const float* __restrict__ h2w, const float* __restrict__ h2b,
    const float* __restrict__ x,
    const float* __restrict__ thresh, const float* __restrict__ sharp,
    const float* __restrict__ scale,
    float* __restrict__ out) {
  const int p0 = blockIdx.x * PH_;
  const int b = p0 >> 13;
  const int o = threadIdx.x;
  __shared__ float s_in[512][PH_];         // [d][pt]
  __shared__ float s_h[PH_][W2_ + 1];

  for (int t = o; t < 256*PH_/4; t += 256) {
    const int pt = t & (PH_-1);
    const int dq = t >> 4;
    const float4 v = *(const float4*)&f2[(size_t)(p0+pt)*W2_ + dq*4];
    s_in[dq*4+0][pt] = v.x; s_in[dq*4+1][pt] = v.y;
    s_in[dq*4+2][pt] = v.z; s_in[dq*4+3][pt] = v.w;
  }
  {
    const float gv = g2[b*W2_ + o];
    const float4 gv4 = make_float4(gv, gv, gv, gv);
    float4* row = (float4*)&s_in[256 + o][0];
    row[0] = gv4; row[1] = gv4; row[2] = gv4; row[3] = gv4;
  }
  __syncthreads();

  const int og = o >> 2;
  const int pg = o & 3;
  const int oo = og * 4;
  const float4 hb = *(const float4*)&h1b[oo];

  float acc[4][4];   // [oi][pi]
#pragma unroll
  for (int pi = 0; pi < 4; ++pi) {
    acc[0][pi] = hb.x; acc[1][pi] = hb.y; acc[2][pi] = hb.z; acc[3][pi] = hb.w;
  }
  for (int d = 0; d < 512; ++d) {
    const float4 pv = *(const float4*)&s_in[d][pg*4];
    const float4 wv = *(const float4*)&h1w[d*256 + oo];
    acc[0][0] += pv.x*wv.x; acc[0][1] += pv.y*wv.x; acc[0][2] += pv.z*wv.x; acc[0][3] += pv.w*wv.x;
    acc[1][0] += pv.x*wv.y; acc[1][1] += pv.y*wv.y; acc[1][2] += pv.z*wv.y; acc[1][3] += pv.w*wv.y;
    acc[2][0] += pv.x*wv.z; acc[2][1] += pv.y*wv.z; acc[2][2] += pv.z*wv.z; acc[2][3] += pv.w*wv.z;
    acc[3][0] += pv.x*wv.w; acc[3][1] += pv.y*wv.w; acc[3][2] += pv.z*wv.w; acc[3][3] += pv.w*wv.w;
  }
#pragma unroll
  for (int oi = 0; oi < 4; ++oi)
#pragma unroll
    for (int pi = 0; pi < 4; ++pi)
      s_h[pg*4+pi][oo+oi] = fmaxf(acc[oi][pi], 0.f);
  __syncthreads();

  if (o < PH_*3) {
    const int pp = o / 3, c = o % 3;
    float s = h2b[c];
    for (int d = 0; d < 256; ++d) s += s_h[pp][d]*h2w[d*3 + c];
    if (c == 0) {
      const float hag = x[(size_t)(p0+pp)*4 + 3];
      const float t = sharp[0]*(thresh[0] - hag);
      s += scale[0] / (1.f + expf(-t));
    }
    out[(size_t)(p0+pp)*3 + c] = s;
  }
}

// ---------------- launch ----------------
extern "C" void kernel_launch(void* const* d_in, const int* in_sizes, int n_in,
                              void* d_out, int out_size, void* d_ws, size_t ws_size,
                              hipStream_t stream) {
  const float* x       = (const float*)d_in[0];
  const float* hmix_a  = (const float*)d_in[1];
  const float* hmix_b  = (const float*)d_in[2];
  const float* hmix_c  = (const float*)d_in[3];
  const float* stem_w  = (const float*)d_in[4];
  const float* stem_b  = (const float*)d_in[5];
  const float* b1_w    = (const float*)d_in[6];
  const float* b1_b    = (const float*)d_in[7];
  const float* b2_w    = (const float*)d_in[8];
  const float* b2_b    = (const float*)d_in[9];
  const float* glob_w  = (const float*)d_in[10];
  const float* glob_b  = (const float*)d_in[11];
  const float* head1_w = (const float*)d_in[12];
  const float* head1_b = (const float*)d_in[13];
  const float* head2_w = (const float*)d_in[14];
  const float* head2_b = (const float*)d_in[15];
  const float* thresh  = (const float*)d_in[16];
  const float* sharp   = (const float*)d_in[17];
  const float* scale   = (const float*)d_in[18];
  float* out = (float*)d_out;

  char* base = (char*)d_ws;
  float* coords4 = (float*)(base + 0);          //  512KB
  float* f0      = (float*)(base + 524288);     //  8MB
  int*   idxb    = (int*)  (base + 8912896);    //  2MB
  float* f1      = (float*)(base + 11010048);   //  16MB
  float* f2      = (float*)(base + 27787264);   //  32MB
  float* part    = (float*)(base + 61341696);   //  128KB
  float* g2      = (float*)(base + 61472768);   //  4KB

  const int NP = B_ * N_;   // 32768 points

  prep_kernel<<<NP, 64, 0, stream>>>(x, stem_w, stem_b, hmix_a, hmix_b, hmix_c,
                                     coords4, f0);
  knn_kernel<<<NP / 2, 64, 0, stream>>>(coords4, idxb);
  agg_kernel<W0_, W1_><<<NP, W1_, 0, stream>>>(f0, coords4, idxb, b1_w, b1_b, f1);
  agg_kernel<W1_, W2_><<<NP, W2_, 0, stream>>>(f1, coords4, idxb, b2_w, b2_b, f2);
  gmax_kernel<<<B_*32, 256, 0, stream>>>(f2, part);
  gfc_kernel<<<B_, 256, 0, stream>>>(part, glob_w, glob_b, g2);
  head_kernel<<<NP / PH_, 256, 0, stream>>>(f2, g2, head1_w, head1_b, head2_w, head2_b,
                                            x, thresh, sharp, scale, out);
}

// Round 4
// 1085.074 us; speedup vs baseline: 2.1518x; 2.1518x over previous
//
#include <hip/hip_runtime.h>
#include <math.h>

typedef unsigned long long u64;
typedef unsigned int u32;
typedef unsigned short u16;
typedef short  s8v  __attribute__((ext_vector_type(8)));  // 8 bf16 (4 VGPRs)
typedef float  f4v  __attribute__((ext_vector_type(4)));  // MFMA acc

#define B_ 4
#define N_ 8192
#define K_ 16
#define W0_ 64
#define W1_ 128
#define W2_ 256
#define P_ 8     // points per block in head kernel
#define X0_ 96   // padded K-dim layer-1 inputs (64 feat + 3 coord + 29 zero)
#define X1_ 160  // padded K-dim layer-2 inputs (128 feat + 3 coord + 29 zero)

// ---- f32 -> bf16 hi/lo split: x ~= hi + lo, |x-hi-lo| <~ 2^-16|x| ----
__device__ __forceinline__ u32 bf16_rne(float x) {
  u32 u = __float_as_uint(x);
  return (u + 0x7FFFu + ((u >> 16) & 1u)) >> 16;
}
__device__ __forceinline__ void split_bf16(float x, u16& h, u16& l) {
  u32 hb = bf16_rne(x);
  float hf = __uint_as_float(hb << 16);
  h = (u16)hb;
  l = (u16)bf16_rne(x - hf);
}

// ---------------- prep: coords4 + stem MLP -> fx0 (bf16 hi/lo, padded) ----------------
__global__ __launch_bounds__(64) void prep_kernel(
    const float* __restrict__ x,
    const float* __restrict__ stem_w, const float* __restrict__ stem_b,
    const float* __restrict__ hmix_a, const float* __restrict__ hmix_b,
    const float* __restrict__ hmix_c,
    float* __restrict__ coords4, u16* __restrict__ fx0_h, u16* __restrict__ fx0_l) {
  const int p = blockIdx.x;
  const int o = threadIdx.x;
  const float x0 = x[p*4+0], x1 = x[p*4+1], x2 = x[p*4+2], x3 = x[p*4+3];
  const float z = hmix_a[0]*x2 + hmix_b[0]*x3 + hmix_c[0];
  float acc = stem_b[o] + x0*stem_w[0*W0_+o] + x1*stem_w[1*W0_+o]
            + x2*stem_w[2*W0_+o] + x3*stem_w[3*W0_+o];
  acc = fmaxf(acc, 0.f);
  u16 h, l; split_bf16(acc, h, l);
  fx0_h[p*X0_+o] = h; fx0_l[p*X0_+o] = l;
  if (o < 32) {   // tail: 3 coords + 29 zeros
    const float tv = (o==0) ? x0 : (o==1) ? x1 : (o==2) ? z : 0.f;
    u16 th, tl; split_bf16(tv, th, tl);
    fx0_h[p*X0_+W0_+o] = th; fx0_l[p*X0_+W0_+o] = tl;
  }
  if (o == 0) {
    const float xx = x0*x0 + x1*x1 + z*z;
    ((float4*)coords4)[p] = make_float4(x0, x1, z, xx);
  }
}

// ---------------- fx1 tail: coords + zero-pad (2 points per 64-thread block) ----------------
__global__ __launch_bounds__(64) void fx1tail_kernel(
    const float* __restrict__ coords4, u16* __restrict__ fx1_h, u16* __restrict__ fx1_l) {
  const int p = blockIdx.x*2 + (threadIdx.x >> 5);
  const int o = threadIdx.x & 31;
  const float4 c = ((const float4*)coords4)[p];
  const float tv = (o==0) ? c.x : (o==1) ? c.y : (o==2) ? c.z : 0.f;
  u16 h, l; split_bf16(tv, h, l);
  fx1_h[(size_t)p*X1_+W1_+o] = h; fx1_l[(size_t)p*X1_+W1_+o] = l;
}

// ---------------- weight conversion: transposed, extended, hi/lo ----------------
// midT[o][c] = { Wmid[c][o] (c<DIN), wp[c-DIN][o] (c<DIN+3), 0 }
// difT[o][c] = { Wself[c][o]-Wmid[c][o],      -wp[c-DIN][o], 0 }
template<int DIN, int DOUT, int XDIM>
__global__ void wconv_kernel(const float* __restrict__ w,
    u16* __restrict__ midT_h, u16* __restrict__ midT_l,
    u16* __restrict__ difT_h, u16* __restrict__ difT_l) {
  const int o = blockIdx.x;
  const int c = threadIdx.x;
  float mv = 0.f, dv = 0.f;
  if (c < DIN)          { const float wm = w[(DIN+c)*DOUT+o]; mv = wm; dv = w[c*DOUT+o] - wm; }
  else if (c < DIN+3)   { const float wp = w[(2*DIN+(c-DIN))*DOUT+o]; mv = wp; dv = -wp; }
  u16 h, l;
  split_bf16(mv, h, l); midT_h[o*XDIM+c] = h; midT_l[o*XDIM+c] = l;
  split_bf16(dv, h, l); difT_h[o*XDIM+c] = h; difT_l[o*XDIM+c] = l;
}

// ---------------- knn: one wave per 2 points (threshold-filtered exact top-16) ----------------
__global__ __launch_bounds__(64) void knn_kernel(
    const float* __restrict__ coords4, int* __restrict__ knn_idx) {
  const int p0 = blockIdx.x * 2;
  const int p1 = p0 + 1;
  const int b = p0 >> 13;
  const int lane = threadIdx.x;
  const float4* cb = ((const float4*)coords4) + (b << 13);
  const float4 c0 = ((const float4*)coords4)[p0];
  const float4 c1 = ((const float4*)coords4)[p1];

  u64 lk0 = ~0ull, lk1 = ~0ull;
  u64 k15_0 = ~0ull, k15_1 = ~0ull;
  float T0 = INFINITY, T1 = INFINITY;

  for (int it = 0; it < N_/64; ++it) {
    const int j = lane + it*64;
    const float4 cj = cb[j];
    float d0 = c0.w + cj.w - 2.f*(c0.x*cj.x + c0.y*cj.y + c0.z*cj.z);
    float d1 = c1.w + cj.w - 2.f*(c1.x*cj.x + c1.y*cj.y + c1.z*cj.z);
    d0 = fmaxf(d0, 0.f);
    d1 = fmaxf(d1, 0.f);

    u64 m0 = __ballot(d0 <= T0);
    while (m0) {
      const int s = (int)__ffsll((unsigned long long)m0) - 1;
      m0 &= m0 - 1;
      const float dc = __shfl(d0, s, 64);
      const u64 ck = ((u64)__float_as_uint(dc) << 32) | (u32)(s + it*64);
      if (ck < k15_0) {
        const bool cond = ck < lk0;
        const u64 pk = __shfl_up(lk0, 1, 64);
        const bool pc = (__shfl_up((int)cond, 1, 64) != 0) && (lane > 0);
        lk0 = cond ? (pc ? pk : ck) : lk0;
        k15_0 = __shfl(lk0, 15, 64);
        T0 = __uint_as_float((u32)(k15_0 >> 32));
      }
    }

    u64 m1 = __ballot(d1 <= T1);
    while (m1) {
      const int s = (int)__ffsll((unsigned long long)m1) - 1;
      m1 &= m1 - 1;
      const float dc = __shfl(d1, s, 64);
      const u64 ck = ((u64)__float_as_uint(dc) << 32) | (u32)(s + it*64);
      if (ck < k15_1) {
        const bool cond = ck < lk1;
        const u64 pk = __shfl_up(lk1, 1, 64);
        const bool pc = (__shfl_up((int)cond, 1, 64) != 0) && (lane > 0);
        lk1 = cond ? (pc ? pk : ck) : lk1;
        k15_1 = __shfl(lk1, 15, 64);
        T1 = __uint_as_float((u32)(k15_1 >> 32));
      }
    }
  }

  if (lane < K_) {
    knn_idx[p0*K_ + lane] = (int)(u32)(lk0 & 0xffffffffull);
    knn_idx[p1*K_ + lane] = (int)(u32)(lk1 & 0xffffffffull);
  }
}

// ---------------- MFMA local_agg ----------------
// Block = 16 points x 4 waves. Wave w owns outputs [w*NPASS*32, ...+NPASS*32).
// Per pass (32 outputs = 2 N-tiles): C-part via own-rows MFMA, then B-frags in
// registers, mt-loop over the 16 points: 16x16x32 bf16 MFMAs, 3-term hi/lo split.
// out[p][o] = max(0, max_k(D[k][o]) + C[p][o] + bias[o])
template<int KS, int DOUT, int NPASS, bool OUT16, int OSTR>
__global__ __launch_bounds__(256) void aggm_kernel(
    const u16* __restrict__ fx_h, const u16* __restrict__ fx_l,
    const int* __restrict__ knn_idx,
    const u16* __restrict__ midT_h, const u16* __restrict__ midT_l,
    const u16* __restrict__ difT_h, const u16* __restrict__ difT_l,
    const float* __restrict__ bw,
    float* __restrict__ fout, u16* __restrict__ fo_h, u16* __restrict__ fo_l) {
  const int XD = KS*32;
  const int p0 = blockIdx.x * 16;
  const int bb = (p0 >> 13) << 13;      // batch base row
  const int tid = threadIdx.x;
  const int w = tid >> 6;
  const int lane = tid & 63;
  const int col = lane & 15;
  const int quad = lane >> 4;
  const int koff = quad*8;              // ushort offset within 32-wide k-chunk

  __shared__ int s_idx[256];
  s_idx[tid] = knn_idx[p0*K_ + tid];
  __syncthreads();

  for (int ps = 0; ps < NPASS; ++ps) {
    const int o0 = w*(NPASS*32) + ps*32;

    // ---- C part: A rows = the block's own 16 points ----
    f4v cacc0 = {0.f,0.f,0.f,0.f}, cacc1 = {0.f,0.f,0.f,0.f};
    {
      const u16* ah_p = fx_h + (size_t)(p0+col)*XD + koff;
      const u16* al_p = fx_l + (size_t)(p0+col)*XD + koff;
      for (int kk = 0; kk < KS; ++kk) {
        const s8v ah = *(const s8v*)(ah_p + kk*32);
        const s8v al = *(const s8v*)(al_p + kk*32);
        {
          const int o = o0 + col;
          const s8v bh = *(const s8v*)(difT_h + (size_t)o*XD + kk*32 + koff);
          const s8v bl = *(const s8v*)(difT_l + (size_t)o*XD + kk*32 + koff);
          cacc0 = __builtin_amdgcn_mfma_f32_16x16x32_bf16(ah, bh, cacc0, 0,0,0);
          cacc0 = __builtin_amdgcn_mfma_f32_16x16x32_bf16(ah, bl, cacc0, 0,0,0);
          cacc0 = __builtin_amdgcn_mfma_f32_16x16x32_bf16(al, bh, cacc0, 0,0,0);
        }
        {
          const int o = o0 + 16 + col;
          const s8v bh = *(const s8v*)(difT_h + (size_t)o*XD + kk*32 + koff);
          const s8v bl = *(const s8v*)(difT_l + (size_t)o*XD + kk*32 + koff);
          cacc1 = __builtin_amdgcn_mfma_f32_16x16x32_bf16(ah, bh, cacc1, 0,0,0);
          cacc1 = __builtin_amdgcn_mfma_f32_16x16x32_bf16(ah, bl, cacc1, 0,0,0);
          cacc1 = __builtin_amdgcn_mfma_f32_16x16x32_bf16(al, bh, cacc1, 0,0,0);
        }
      }
    }

    // ---- preload main B fragments (weights) into registers ----
    s8v Bh0[KS], Bl0[KS], Bh1[KS], Bl1[KS];
#pragma unroll
    for (int kk = 0; kk < KS; ++kk) {
      const int oa = o0 + col, ob = o0 + 16 + col;
      Bh0[kk] = *(const s8v*)(midT_h + (size_t)oa*XD + kk*32 + koff);
      Bl0[kk] = *(const s8v*)(midT_l + (size_t)oa*XD + kk*32 + koff);
      Bh1[kk] = *(const s8v*)(midT_h + (size_t)ob*XD + kk*32 + koff);
      Bl1[kk] = *(const s8v*)(midT_l + (size_t)ob*XD + kk*32 + koff);
    }
    const float bias0 = bw[o0 + col];
    const float bias1 = bw[o0 + 16 + col];

    // ---- main loop over the 16 points ----
    for (int g = 0; g < 16; ++g) {
      const int nrow = bb + s_idx[g*16 + col];
      const u16* ah_p = fx_h + (size_t)nrow*XD + koff;
      const u16* al_p = fx_l + (size_t)nrow*XD + koff;
      f4v a0 = {0.f,0.f,0.f,0.f}, a1 = {0.f,0.f,0.f,0.f};
#pragma unroll
      for (int kk = 0; kk < KS; ++kk) {
        const s8v ah = *(const s8v*)(ah_p + kk*32);
        const s8v al = *(const s8v*)(al_p + kk*32);
        a0 = __builtin_amdgcn_mfma_f32_16x16x32_bf16(ah, Bh0[kk], a0, 0,0,0);
        a1 = __builtin_amdgcn_mfma_f32_16x16x32_bf16(ah, Bh1[kk], a1, 0,0,0);
        a0 = __builtin_amdgcn_mfma_f32_16x16x32_bf16(ah, Bl0[kk], a0, 0,0,0);
        a1 = __builtin_amdgcn_mfma_f32_16x16x32_bf16(ah, Bl1[kk], a1, 0,0,0);
        a0 = __builtin_amdgcn_mfma_f32_16x16x32_bf16(al, Bh0[kk], a0, 0,0,0);
        a1 = __builtin_amdgcn_mfma_f32_16x16x32_bf16(al, Bh1[kk], a1, 0,0,0);
      }
      // max over the 16 k-rows: 4 in-lane + cross-quad shuffles
      float m0 = fmaxf(fmaxf(a0[0], a0[1]), fmaxf(a0[2], a0[3]));
      float m1 = fmaxf(fmaxf(a1[0], a1[1]), fmaxf(a1[2], a1[3]));
      m0 = fmaxf(m0, __shfl_xor(m0, 16, 64)); m0 = fmaxf(m0, __shfl_xor(m0, 32, 64));
      m1 = fmaxf(m1, __shfl_xor(m1, 16, 64)); m1 = fmaxf(m1, __shfl_xor(m1, 32, 64));
      // C[g][col]: held in cacc reg (g&3) of quad (g>>2) lanes
      const int src = ((g >> 2) << 4) + col;
      const float c0 = __shfl(cacc0[g & 3], src, 64);
      const float c1 = __shfl(cacc1[g & 3], src, 64);
      const float v0 = fmaxf(m0 + c0 + bias0, 0.f);
      const float v1 = fmaxf(m1 + c1 + bias1, 0.f);
      if (lane < 16) {
        const size_t pr = (size_t)(p0 + g);
        if (OUT16) {
          u16 h, l;
          split_bf16(v0, h, l); fo_h[pr*OSTR + o0 + col] = h;       fo_l[pr*OSTR + o0 + col] = l;
          split_bf16(v1, h, l); fo_h[pr*OSTR + o0 + 16 + col] = h;  fo_l[pr*OSTR + o0 + 16 + col] = l;
        } else {
          fout[pr*DOUT + o0 + col] = v0;
          fout[pr*DOUT + o0 + 16 + col] = v1;
        }
      }
    }
  }
}

// ---------------- global max (stage 1) ----------------
__global__ __launch_bounds__(256) void gmax_kernel(
    const float* __restrict__ f2, float* __restrict__ part) {
  const int b = blockIdx.x >> 5;
  const int seg = blockIdx.x & 31;
  const int o = threadIdx.x;
  float m = -INFINITY;
  const int n0 = seg * 256;
  for (int n = n0; n < n0 + 256; ++n)
    m = fmaxf(m, f2[((size_t)(b<<13) + n)*W2_ + o]);
  part[(size_t)blockIdx.x*W2_ + o] = m;
}

// ---------------- global max reduce + glob FC ----------------
__global__ __launch_bounds__(256) void gfc_kernel(
    const float* __restrict__ part, const float* __restrict__ gw,
    const float* __restrict__ gb, float* __restrict__ g2) {
  const int b = blockIdx.x;
  const int o = threadIdx.x;
  __shared__ float s_g[W2_];
  float m = -INFINITY;
  for (int s = 0; s < 32; ++s) m = fmaxf(m, part[(size_t)(b*32+s)*W2_ + o]);
  s_g[o] = m;
  __syncthreads();
  float acc = gb[o];
  for (int d = 0; d < W2_; ++d) acc += s_g[d]*gw[d*W2_ + o];
  g2[b*W2_ + o] = fmaxf(acc, 0.f);
}

// ---------------- head (round-2 version) ----------------
__global__ __launch_bounds__(256) void head_kernel(
    const float* __restrict__ f2, const float* __restrict__ g2,
    const float* __restrict__ h1w, const float* __restrict__ h1b,
    const float* __restrict__ h2w, const float* __restrict__ h2b,
    const float* __restrict__ x,
    const float* __restrict__ thresh, const float* __restrict__ sharp,
    const float* __restrict__ scale,
    float* __restrict__ out) {
  const int p0 = blockIdx.x * P_;
  const int b = p0 >> 13;
  const int o = threadIdx.x;
  __shared__ float s_in[512][P_];
  __shared__ float s_h[P_][W2_ + 1];

  for (int t = o; t < 256*P_; t += 256) {
    const int pp = t & (P_-1);
    const int d  = t >> 3;
    s_in[d][pp] = f2[(size_t)(p0+pp)*W2_ + d];
  }
  {
    const float gv = g2[b*W2_ + o];
#pragma unroll
    for (int pp = 0; pp < P_; ++pp) s_in[256 + o][pp] = gv;
  }
  __syncthreads();

  float acc[P_];
#pragma unroll
  for (int pp = 0; pp < P_; ++pp) acc[pp] = h1b[o];
  for (int d = 0; d < 512; ++d) {
    const float wv = h1w[d*256 + o];
    const float4 a = *(const float4*)&s_in[d][0];
    const float4 c = *(const float4*)&s_in[d][4];
    acc[0] += a.x*wv; acc[1] += a.y*wv; acc[2] += a.z*wv; acc[3] += a.w*wv;
    acc[4] += c.x*wv; acc[5] += c.y*wv; acc[6] += c.z*wv; acc[7] += c.w*wv;
  }
#pragma unroll
  for (int pp = 0; pp < P_; ++pp) s_h[pp][o] = fmaxf(acc[pp], 0.f);
  __syncthreads();

  if (o < P_*3) {
    const int pp = o / 3, c = o % 3;
    float s = h2b[c];
    for (int d = 0; d < 256; ++d) s += s_h[pp][d]*h2w[d*3 + c];
    if (c == 0) {
      const float hag = x[(size_t)(p0+pp)*4 + 3];
      const float t = sharp[0]*(thresh[0] - hag);
      s += scale[0] / (1.f + expf(-t));
    }
    out[(size_t)(p0+pp)*3 + c] = s;
  }
}

// ---------------- launch ----------------
extern "C" void kernel_launch(void* const* d_in, const int* in_sizes, int n_in,
                              void* d_out, int out_size, void* d_ws, size_t ws_size,
                              hipStream_t stream) {
  const float* x       = (const float*)d_in[0];
  const float* hmix_a  = (const float*)d_in[1];
  const float* hmix_b  = (const float*)d_in[2];
  const float* hmix_c  = (const float*)d_in[3];
  const float* stem_w  = (const float*)d_in[4];
  const float* stem_b  = (const float*)d_in[5];
  const float* b1_w    = (const float*)d_in[6];
  const float* b1_b    = (const float*)d_in[7];
  const float* b2_w    = (const float*)d_in[8];
  const float* b2_b    = (const float*)d_in[9];
  const float* glob_w  = (const float*)d_in[10];
  const float* glob_b  = (const float*)d_in[11];
  const float* head1_w = (const float*)d_in[12];
  const float* head1_b = (const float*)d_in[13];
  const float* head2_w = (const float*)d_in[14];
  const float* head2_b = (const float*)d_in[15];
  const float* thresh  = (const float*)d_in[16];
  const float* sharp   = (const float*)d_in[17];
  const float* scale   = (const float*)d_in[18];
  float* out = (float*)d_out;

  char* base = (char*)d_ws;
  float* coords4 = (float*)(base + 0);              // 512 KB
  int*   idxb    = (int*)  (base + 524288);         // 2 MB
  u16*   fx1_h   = (u16*)  (base + 2621440);        // 10 MB (32768*160*2)
  u16*   fx1_l   = (u16*)  (base + 13107200);       // 10 MB
  u16*   w1m_h   = (u16*)  (base + 23592960);       // 24 KB each (128*96*2)
  u16*   w1m_l   = (u16*)  (base + 23617536);
  u16*   w1d_h   = (u16*)  (base + 23642112);
  u16*   w1d_l   = (u16*)  (base + 23666688);
  u16*   w2m_h   = (u16*)  (base + 23691264);       // 80 KB each (256*160*2)
  u16*   w2m_l   = (u16*)  (base + 23773184);
  u16*   w2d_h   = (u16*)  (base + 23855104);
  u16*   w2d_l   = (u16*)  (base + 23937024);
  float* part    = (float*)(base + 24018944);       // 128 KB
  float* g2      = (float*)(base + 24150016);       // 4 KB
  // fx0 (12 MB) and f2 (32 MB) share a region: fx0 is dead before agg2 writes f2
  u16*   fx0_h   = (u16*)  (base + 24154112);       // 6 MB (32768*96*2)
  u16*   fx0_l   = (u16*)  (base + 30445568);       // 6 MB
  float* f2      = (float*)(base + 24154112);       // 32 MB, overlaps fx0

  const int NP = B_ * N_;   // 32768 points

  wconv_kernel<W0_, W1_, X0_><<<W1_, X0_, 0, stream>>>(b1_w, w1m_h, w1m_l, w1d_h, w1d_l);
  wconv_kernel<W1_, W2_, X1_><<<W2_, X1_, 0, stream>>>(b2_w, w2m_h, w2m_l, w2d_h, w2d_l);
  prep_kernel<<<NP, 64, 0, stream>>>(x, stem_w, stem_b, hmix_a, hmix_b, hmix_c,
                                     coords4, fx0_h, fx0_l);
  fx1tail_kernel<<<NP/2, 64, 0, stream>>>(coords4, fx1_h, fx1_l);
  knn_kernel<<<NP/2, 64, 0, stream>>>(coords4, idxb);
  // agg1: K=96 (3 steps), DOUT=128, 1 pass, bf16 hi/lo out into fx1
  aggm_kernel<3, W1_, 1, true, X1_><<<NP/16, 256, 0, stream>>>(
      fx0_h, fx0_l, idxb, w1m_h, w1m_l, w1d_h, w1d_l, b1_b, (float*)0, fx1_h, fx1_l);
  // agg2: K=160 (5 steps), DOUT=256, 2 passes, f32 out
  aggm_kernel<5, W2_, 2, false, 0><<<NP/16, 256, 0, stream>>>(
      fx1_h, fx1_l, idxb, w2m_h, w2m_l, w2d_h, w2d_l, b2_b, f2, (u16*)0, (u16*)0);
  gmax_kernel<<<B_*32, 256, 0, stream>>>(f2, part);
  gfc_kernel<<<B_, 256, 0, stream>>>(part, glob_w, glob_b, g2);
  head_kernel<<<NP/P_, 256, 0, stream>>>(f2, g2, head1_w, head1_b, head2_w, head2_b,
                                         x, thresh, sharp, scale, out);
}

// Round 5
// 659.717 us; speedup vs baseline: 3.5392x; 1.6448x over previous
//
#include <hip/hip_runtime.h>
#include <math.h>

typedef unsigned long long u64;
typedef unsigned int u32;
typedef _Float16 h8v __attribute__((ext_vector_type(8)));  // 8 fp16 (4 VGPRs)
typedef float    f4v __attribute__((ext_vector_type(4)));  // MFMA acc

#define MFMA16(a,b,c) __builtin_amdgcn_mfma_f32_16x16x32_f16(a, b, c, 0, 0, 0)

#define B_ 4
#define N_ 8192
#define K_ 16
#define W0_ 64
#define W1_ 128
#define W2_ 256
#define X0_ 96   // padded K-dim layer-1 inputs (64 feat + 3 coord + 29 zero)
#define X1_ 160  // padded K-dim layer-2 inputs (128 feat + 3 coord + 29 zero)

// ---------------- prep: coords4 + stem MLP -> fx0 (fp16, padded) ----------------
__global__ __launch_bounds__(64) void prep_kernel(
    const float* __restrict__ x,
    const float* __restrict__ stem_w, const float* __restrict__ stem_b,
    const float* __restrict__ hmix_a, const float* __restrict__ hmix_b,
    const float* __restrict__ hmix_c,
    float* __restrict__ coords4, _Float16* __restrict__ fx0) {
  const int p = blockIdx.x;
  const int o = threadIdx.x;
  const float x0 = x[p*4+0], x1 = x[p*4+1], x2 = x[p*4+2], x3 = x[p*4+3];
  const float z = hmix_a[0]*x2 + hmix_b[0]*x3 + hmix_c[0];
  float acc = stem_b[o] + x0*stem_w[0*W0_+o] + x1*stem_w[1*W0_+o]
            + x2*stem_w[2*W0_+o] + x3*stem_w[3*W0_+o];
  fx0[p*X0_+o] = (_Float16)fmaxf(acc, 0.f);
  if (o < 32) {   // tail: 3 coords + 29 zeros
    const float tv = (o==0) ? x0 : (o==1) ? x1 : (o==2) ? z : 0.f;
    fx0[p*X0_+W0_+o] = (_Float16)tv;
  }
  if (o == 0) {
    const float xx = x0*x0 + x1*x1 + z*z;
    ((float4*)coords4)[p] = make_float4(x0, x1, z, xx);
  }
}

// ---------------- fx1 tail: coords + zero-pad ----------------
__global__ __launch_bounds__(64) void fx1tail_kernel(
    const float* __restrict__ coords4, _Float16* __restrict__ fx1) {
  const int p = blockIdx.x*2 + (threadIdx.x >> 5);
  const int o = threadIdx.x & 31;
  const float4 c = ((const float4*)coords4)[p];
  const float tv = (o==0) ? c.x : (o==1) ? c.y : (o==2) ? c.z : 0.f;
  fx1[(size_t)p*X1_ + W1_ + o] = (_Float16)tv;
}

// ---------------- weight conversion: transposed, extended, fp16 ----------------
// midT[o][c] = { Wmid[c][o] (c<DIN), wp[c-DIN][o] (c<DIN+3), 0 }
// difT[o][c] = { Wself[c][o]-Wmid[c][o],         -wp[c-DIN][o], 0 }
template<int DIN, int DOUT, int XDIM>
__global__ void wconv_kernel(const float* __restrict__ w,
    _Float16* __restrict__ midT, _Float16* __restrict__ difT) {
  const int o = blockIdx.x;
  const int c = threadIdx.x;
  float mv = 0.f, dv = 0.f;
  if (c < DIN)        { const float wm = w[(DIN+c)*DOUT+o]; mv = wm; dv = w[c*DOUT+o] - wm; }
  else if (c < DIN+3) { const float wp = w[(2*DIN+(c-DIN))*DOUT+o]; mv = wp; dv = -wp; }
  midT[o*XDIM+c] = (_Float16)mv;
  difT[o*XDIM+c] = (_Float16)dv;
}

// ---------------- head1 weight transpose -> fp16 ----------------
__global__ __launch_bounds__(256) void htrans_kernel(
    const float* __restrict__ h1w, _Float16* __restrict__ h1wT) {
  const int o = blockIdx.x;
  for (int c = threadIdx.x; c < 512; c += 256)
    h1wT[(size_t)o*512 + c] = (_Float16)h1w[(size_t)c*256 + o];
}

// ---------------- knn: one wave per 2 points (threshold-filtered exact top-16) ----------------
__global__ __launch_bounds__(64) void knn_kernel(
    const float* __restrict__ coords4, int* __restrict__ knn_idx) {
  const int p0 = blockIdx.x * 2;
  const int p1 = p0 + 1;
  const int b = p0 >> 13;
  const int lane = threadIdx.x;
  const float4* cb = ((const float4*)coords4) + (b << 13);
  const float4 c0 = ((const float4*)coords4)[p0];
  const float4 c1 = ((const float4*)coords4)[p1];

  u64 lk0 = ~0ull, lk1 = ~0ull;
  u64 k15_0 = ~0ull, k15_1 = ~0ull;
  float T0 = INFINITY, T1 = INFINITY;

  for (int it = 0; it < N_/64; ++it) {
    const int j = lane + it*64;
    const float4 cj = cb[j];
    float d0 = c0.w + cj.w - 2.f*(c0.x*cj.x + c0.y*cj.y + c0.z*cj.z);
    float d1 = c1.w + cj.w - 2.f*(c1.x*cj.x + c1.y*cj.y + c1.z*cj.z);
    d0 = fmaxf(d0, 0.f);
    d1 = fmaxf(d1, 0.f);

    u64 m0 = __ballot(d0 <= T0);
    while (m0) {
      const int s = (int)__ffsll((unsigned long long)m0) - 1;
      m0 &= m0 - 1;
      const float dc = __shfl(d0, s, 64);
      const u64 ck = ((u64)__float_as_uint(dc) << 32) | (u32)(s + it*64);
      if (ck < k15_0) {
        const bool cond = ck < lk0;
        const u64 pk = __shfl_up(lk0, 1, 64);
        const bool pc = (__shfl_up((int)cond, 1, 64) != 0) && (lane > 0);
        lk0 = cond ? (pc ? pk : ck) : lk0;
        k15_0 = __shfl(lk0, 15, 64);
        T0 = __uint_as_float((u32)(k15_0 >> 32));
      }
    }

    u64 m1 = __ballot(d1 <= T1);
    while (m1) {
      const int s = (int)__ffsll((unsigned long long)m1) - 1;
      m1 &= m1 - 1;
      const float dc = __shfl(d1, s, 64);
      const u64 ck = ((u64)__float_as_uint(dc) << 32) | (u32)(s + it*64);
      if (ck < k15_1) {
        const bool cond = ck < lk1;
        const u64 pk = __shfl_up(lk1, 1, 64);
        const bool pc = (__shfl_up((int)cond, 1, 64) != 0) && (lane > 0);
        lk1 = cond ? (pc ? pk : ck) : lk1;
        k15_1 = __shfl(lk1, 15, 64);
        T1 = __uint_as_float((u32)(k15_1 >> 32));
      }
    }
  }

  if (lane < K_) {
    knn_idx[p0*K_ + lane] = (int)(u32)(lk0 & 0xffffffffull);
    knn_idx[p1*K_ + lane] = (int)(u32)(lk1 & 0xffffffffull);
  }
}

// ---------------- MFMA local_agg (fp16, 2 tiles/wave, register g+1 prefetch) ----------------
// Block = 16 points x 4 waves; wave owns 32 outputs per pass.
// out[p][o] = max(0, max_k(D[k][o]) + C[p][o] + bias[o]), all via 16x16x32 f16 MFMA.
template<int KS, int NPASS>
__global__ __launch_bounds__(256) void aggm_kernel(
    const _Float16* __restrict__ fx, const int* __restrict__ knn_idx,
    const _Float16* __restrict__ midT, const _Float16* __restrict__ difT,
    const float* __restrict__ bw,
    _Float16* __restrict__ fo, const int ostr) {
  const int XD = KS*32;
  const int p0 = blockIdx.x * 16;
  const int bb = (p0 >> 13) << 13;
  const int tid = threadIdx.x;
  const int w = tid >> 6, lane = tid & 63, col = lane & 15, quad = lane >> 4;
  const int koff = quad * 8;

  __shared__ int s_idx[256];
  s_idx[tid] = knn_idx[p0*K_ + tid];
  __syncthreads();

  for (int ps = 0; ps < NPASS; ++ps) {
    const int o0 = ps*128 + w*32;
    const int oa = o0 + col, ob = oa + 16;

    // ---- C part: A rows = the block's own 16 points ----
    f4v cacc0 = {0.f,0.f,0.f,0.f}, cacc1 = {0.f,0.f,0.f,0.f};
    {
      const _Float16* ap = fx + (size_t)(p0+col)*XD + koff;
      const _Float16* b0 = difT + (size_t)oa*XD + koff;
      const _Float16* b1 = difT + (size_t)ob*XD + koff;
#pragma unroll
      for (int kk = 0; kk < KS; ++kk) {
        const h8v ah = *(const h8v*)(ap + kk*32);
        cacc0 = MFMA16(ah, *(const h8v*)(b0 + kk*32), cacc0);
        cacc1 = MFMA16(ah, *(const h8v*)(b1 + kk*32), cacc1);
      }
    }

    // ---- B fragments (weights) in registers ----
    h8v B0[KS], B1[KS];
#pragma unroll
    for (int kk = 0; kk < KS; ++kk) {
      B0[kk] = *(const h8v*)(midT + (size_t)oa*XD + kk*32 + koff);
      B1[kk] = *(const h8v*)(midT + (size_t)ob*XD + kk*32 + koff);
    }
    const float bias0 = bw[oa], bias1 = bw[ob];

    // ---- main loop over the 16 points, A prefetched one g ahead ----
    h8v Ac[KS];
    {
      const _Float16* ap = fx + (size_t)(bb + s_idx[col])*XD + koff;
#pragma unroll
      for (int kk = 0; kk < KS; ++kk) Ac[kk] = *(const h8v*)(ap + kk*32);
    }
    for (int g = 0; g < 16; ++g) {
      h8v An[KS];
      {
        const int gn = (g < 15) ? g + 1 : 15;
        const _Float16* ap = fx + (size_t)(bb + s_idx[gn*16 + col])*XD + koff;
#pragma unroll
        for (int kk = 0; kk < KS; ++kk) An[kk] = *(const h8v*)(ap + kk*32);
      }
      f4v a0 = {0.f,0.f,0.f,0.f}, a1 = {0.f,0.f,0.f,0.f};
#pragma unroll
      for (int kk = 0; kk < KS; ++kk) {
        a0 = MFMA16(Ac[kk], B0[kk], a0);
        a1 = MFMA16(Ac[kk], B1[kk], a1);
      }
      float m0 = fmaxf(fmaxf(a0[0],a0[1]), fmaxf(a0[2],a0[3]));
      float m1 = fmaxf(fmaxf(a1[0],a1[1]), fmaxf(a1[2],a1[3]));
      m0 = fmaxf(m0, __shfl_xor(m0,16,64)); m0 = fmaxf(m0, __shfl_xor(m0,32,64));
      m1 = fmaxf(m1, __shfl_xor(m1,16,64)); m1 = fmaxf(m1, __shfl_xor(m1,32,64));
      const int src = ((g >> 2) << 4) + col;   // C[g][col] lives in quad g>>2, reg g&3
      const float c0 = __shfl(cacc0[g & 3], src, 64);
      const float c1 = __shfl(cacc1[g & 3], src, 64);
      if (lane < 16) {
        fo[(size_t)(p0+g)*ostr + oa] = (_Float16)fmaxf(m0 + c0 + bias0, 0.f);
        fo[(size_t)(p0+g)*ostr + ob] = (_Float16)fmaxf(m1 + c1 + bias1, 0.f);
      }
#pragma unroll
      for (int kk = 0; kk < KS; ++kk) Ac[kk] = An[kk];
    }
  }
}

// ---------------- global max (stage 1, fp16 in, f32 partials) ----------------
__global__ __launch_bounds__(256) void gmax_kernel(
    const _Float16* __restrict__ f2h, float* __restrict__ part) {
  const int b = blockIdx.x >> 5;
  const int seg = blockIdx.x & 31;
  const int o = threadIdx.x;
  float m = -INFINITY;
  const int n0 = seg * 256;
  for (int n = n0; n < n0 + 256; ++n)
    m = fmaxf(m, (float)f2h[((size_t)(b<<13) + n)*W2_ + o]);
  part[(size_t)blockIdx.x*W2_ + o] = m;
}

// ---------------- global max reduce + glob FC -> g2h fp16 ----------------
__global__ __launch_bounds__(256) void gfc_kernel(
    const float* __restrict__ part, const float* __restrict__ gw,
    const float* __restrict__ gb, _Float16* __restrict__ g2h) {
  const int b = blockIdx.x;
  const int o = threadIdx.x;
  __shared__ float s_g[W2_];
  float m = -INFINITY;
  for (int s = 0; s < 32; ++s) m = fmaxf(m, part[(size_t)(b*32+s)*W2_ + o]);
  s_g[o] = m;
  __syncthreads();
  float acc = gb[o];
  for (int d = 0; d < W2_; ++d) acc += s_g[d]*gw[d*W2_ + o];
  g2h[b*W2_ + o] = (_Float16)fmaxf(acc, 0.f);
}

// ---------------- head: 32 points/block MFMA GEMM + tiny second layer ----------------
__global__ __launch_bounds__(256) void headm_kernel(
    const _Float16* __restrict__ f2h, const _Float16* __restrict__ g2h,
    const _Float16* __restrict__ h1wT, const float* __restrict__ h1b,
    const float* __restrict__ h2w, const float* __restrict__ h2b,
    const float* __restrict__ x,
    const float* __restrict__ thresh, const float* __restrict__ sharp,
    const float* __restrict__ scale,
    float* __restrict__ out) {
  const int p0 = blockIdx.x * 32;
  const int b = p0 >> 13;
  const int tid = threadIdx.x;
  const int w = tid >> 6, lane = tid & 63, col = lane & 15, quad = lane >> 4;

  __shared__ _Float16 sA[32*520];   // 32 points x 512 (padded to 520): 33.3 KB
  __shared__ float    sh[32*260];   // relu(h1) f32: 33.3 KB

  for (int t = tid; t < 32*32; t += 256) {       // f2h part (16B chunks)
    const int r = t >> 5, cc = (t & 31) * 8;
    *(uint4*)&sA[r*520 + cc] = *(const uint4*)&f2h[(size_t)(p0+r)*W2_ + cc];
  }
  for (int t = tid; t < 32*32; t += 256) {       // g2h broadcast part
    const int r = t >> 5, cc = (t & 31) * 8;
    *(uint4*)&sA[r*520 + 256 + cc] = *(const uint4*)&g2h[b*W2_ + cc];
  }
  __syncthreads();

  f4v acc[2][4];
#pragma unroll
  for (int r = 0; r < 2; ++r)
#pragma unroll
    for (int t = 0; t < 4; ++t) acc[r][t] = (f4v){0.f,0.f,0.f,0.f};

  for (int kk = 0; kk < 16; ++kk) {
    const h8v a0 = *(const h8v*)&sA[col*520 + kk*32 + quad*8];
    const h8v a1 = *(const h8v*)&sA[(16+col)*520 + kk*32 + quad*8];
#pragma unroll
    for (int t = 0; t < 4; ++t) {
      const h8v bt = *(const h8v*)&h1wT[(size_t)(w*64 + t*16 + col)*512 + kk*32 + quad*8];
      acc[0][t] = MFMA16(a0, bt, acc[0][t]);
      acc[1][t] = MFMA16(a1, bt, acc[1][t]);
    }
  }
#pragma unroll
  for (int r = 0; r < 2; ++r)
#pragma unroll
    for (int t = 0; t < 4; ++t) {
      const int o = w*64 + t*16 + col;
      const float bv = h1b[o];
#pragma unroll
      for (int reg = 0; reg < 4; ++reg)
        sh[(r*16 + quad*4 + reg)*260 + o] = fmaxf(acc[r][t][reg] + bv, 0.f);
    }
  __syncthreads();

  if (tid < 96) {
    const int pp = tid / 3, c = tid % 3;
    float s = h2b[c];
    for (int d = 0; d < 256; ++d) s += sh[pp*260 + d] * h2w[d*3 + c];
    if (c == 0) {
      const float hag = x[(size_t)(p0+pp)*4 + 3];
      s += scale[0] / (1.f + expf(-sharp[0]*(thresh[0] - hag)));
    }
    out[(size_t)(p0+pp)*3 + c] = s;
  }
}

// ---------------- launch ----------------
extern "C" void kernel_launch(void* const* d_in, const int* in_sizes, int n_in,
                              void* d_out, int out_size, void* d_ws, size_t ws_size,
                              hipStream_t stream) {
  const float* x       = (const float*)d_in[0];
  const float* hmix_a  = (const float*)d_in[1];
  const float* hmix_b  = (const float*)d_in[2];
  const float* hmix_c  = (const float*)d_in[3];
  const float* stem_w  = (const float*)d_in[4];
  const float* stem_b  = (const float*)d_in[5];
  const float* b1_w    = (const float*)d_in[6];
  const float* b1_b    = (const float*)d_in[7];
  const float* b2_w    = (const float*)d_in[8];
  const float* b2_b    = (const float*)d_in[9];
  const float* glob_w  = (const float*)d_in[10];
  const float* glob_b  = (const float*)d_in[11];
  const float* head1_w = (const float*)d_in[12];
  const float* head1_b = (const float*)d_in[13];
  const float* head2_w = (const float*)d_in[14];
  const float* head2_b = (const float*)d_in[15];
  const float* thresh  = (const float*)d_in[16];
  const float* sharp   = (const float*)d_in[17];
  const float* scale   = (const float*)d_in[18];
  float* out = (float*)d_out;

  char* base = (char*)d_ws;
  float*     coords4 = (float*)    (base + 0);          // 512 KB
  int*       idxb    = (int*)      (base + 524288);     // 2 MB
  _Float16*  fx0     = (_Float16*) (base + 2621440);    // 6 MB   (32768*96*2)
  _Float16*  fx1     = (_Float16*) (base + 8912896);    // 10 MB  (32768*160*2)
  _Float16*  f2h     = (_Float16*) (base + 19398656);   // 16 MB  (32768*256*2)
  _Float16*  w1m     = (_Float16*) (base + 36175872);   // 24 KB  (128*96*2)
  _Float16*  w1d     = (_Float16*) (base + 36200448);   // 24 KB
  _Float16*  w2m     = (_Float16*) (base + 36225024);   // 80 KB  (256*160*2)
  _Float16*  w2d     = (_Float16*) (base + 36306944);   // 80 KB
  _Float16*  h1wT    = (_Float16*) (base + 36388864);   // 256 KB (256*512*2)
  float*     part    = (float*)    (base + 36651008);   // 128 KB
  _Float16*  g2h     = (_Float16*) (base + 36782080);   // 2 KB

  const int NP = B_ * N_;   // 32768 points

  wconv_kernel<W0_, W1_, X0_><<<W1_, X0_, 0, stream>>>(b1_w, w1m, w1d);
  wconv_kernel<W1_, W2_, X1_><<<W2_, X1_, 0, stream>>>(b2_w, w2m, w2d);
  htrans_kernel<<<W2_, 256, 0, stream>>>(head1_w, h1wT);
  prep_kernel<<<NP, 64, 0, stream>>>(x, stem_w, stem_b, hmix_a, hmix_b, hmix_c,
                                     coords4, fx0);
  fx1tail_kernel<<<NP/2, 64, 0, stream>>>(coords4, fx1);
  knn_kernel<<<NP/2, 64, 0, stream>>>(coords4, idxb);
  aggm_kernel<3, 1><<<NP/16, 256, 0, stream>>>(fx0, idxb, w1m, w1d, b1_b, fx1, X1_);
  aggm_kernel<5, 2><<<NP/16, 256, 0, stream>>>(fx1, idxb, w2m, w2d, b2_b, f2h, W2_);
  gmax_kernel<<<B_*32, 256, 0, stream>>>(f2h, part);
  gfc_kernel<<<B_, 256, 0, stream>>>(part, glob_w, glob_b, g2h);
  headm_kernel<<<NP/32, 256, 0, stream>>>(f2h, g2h, h1wT, head1_b, head2_w, head2_b,
                                          x, thresh, sharp, scale, out);
}

// Round 6
// 583.862 us; speedup vs baseline: 3.9990x; 1.1299x over previous
//
#include <hip/hip_runtime.h>
#include <math.h>

typedef unsigned long long u64;
typedef unsigned int u32;
typedef _Float16 h8v __attribute__((ext_vector_type(8)));  // 8 fp16 (4 VGPRs)
typedef float    f4v __attribute__((ext_vector_type(4)));  // MFMA acc

#define MFMA16(a,b,c) __builtin_amdgcn_mfma_f32_16x16x32_f16(a, b, c, 0, 0, 0)

#define B_ 4
#define N_ 8192
#define K_ 16
#define W0_ 64
#define W1_ 128
#define W2_ 256
#define X0_ 96   // padded K-dim layer-1 inputs (64 feat + 3 coord + 29 zero)
#define X1_ 160  // padded K-dim layer-2 inputs (128 feat + 3 coord + 29 zero)

// ---------------- prep: coords4 + stem MLP -> fx0 (fp16, padded) ----------------
__global__ __launch_bounds__(64) void prep_kernel(
    const float* __restrict__ x,
    const float* __restrict__ stem_w, const float* __restrict__ stem_b,
    const float* __restrict__ hmix_a, const float* __restrict__ hmix_b,
    const float* __restrict__ hmix_c,
    float* __restrict__ coords4, _Float16* __restrict__ fx0) {
  const int p = blockIdx.x;
  const int o = threadIdx.x;
  const float x0 = x[p*4+0], x1 = x[p*4+1], x2 = x[p*4+2], x3 = x[p*4+3];
  const float z = hmix_a[0]*x2 + hmix_b[0]*x3 + hmix_c[0];
  float acc = stem_b[o] + x0*stem_w[0*W0_+o] + x1*stem_w[1*W0_+o]
            + x2*stem_w[2*W0_+o] + x3*stem_w[3*W0_+o];
  fx0[p*X0_+o] = (_Float16)fmaxf(acc, 0.f);
  if (o < 32) {   // tail: 3 coords + 29 zeros
    const float tv = (o==0) ? x0 : (o==1) ? x1 : (o==2) ? z : 0.f;
    fx0[p*X0_+W0_+o] = (_Float16)tv;
  }
  if (o == 0) {
    const float xx = x0*x0 + x1*x1 + z*z;
    ((float4*)coords4)[p] = make_float4(x0, x1, z, xx);
  }
}

// ---------------- fx1 tail: coords + zero-pad ----------------
__global__ __launch_bounds__(64) void fx1tail_kernel(
    const float* __restrict__ coords4, _Float16* __restrict__ fx1) {
  const int p = blockIdx.x*2 + (threadIdx.x >> 5);
  const int o = threadIdx.x & 31;
  const float4 c = ((const float4*)coords4)[p];
  const float tv = (o==0) ? c.x : (o==1) ? c.y : (o==2) ? c.z : 0.f;
  fx1[(size_t)p*X1_ + W1_ + o] = (_Float16)tv;
}

// ---------------- weight conversion: transposed, extended, fp16 ----------------
template<int DIN, int DOUT, int XDIM>
__global__ void wconv_kernel(const float* __restrict__ w,
    _Float16* __restrict__ midT, _Float16* __restrict__ difT) {
  const int o = blockIdx.x;
  const int c = threadIdx.x;
  float mv = 0.f, dv = 0.f;
  if (c < DIN)        { const float wm = w[(DIN+c)*DOUT+o]; mv = wm; dv = w[c*DOUT+o] - wm; }
  else if (c < DIN+3) { const float wp = w[(2*DIN+(c-DIN))*DOUT+o]; mv = wp; dv = -wp; }
  midT[o*XDIM+c] = (_Float16)mv;
  difT[o*XDIM+c] = (_Float16)dv;
}

// ---------------- head1 weight transpose -> fp16 ----------------
__global__ __launch_bounds__(256) void htrans_kernel(
    const float* __restrict__ h1w, _Float16* __restrict__ h1wT) {
  const int o = blockIdx.x;
  for (int c = threadIdx.x; c < 512; c += 256)
    h1wT[(size_t)o*512 + c] = (_Float16)h1w[(size_t)c*256 + o];
}

// ---------------- knn: one wave per 4 points ----------------
// Wave-distributed sorted top-16 with 32-bit dist/idx registers.
// Strict-< insertion in ascending-j arrival order reproduces top_k's
// lower-index-first tie-break exactly (equal dist lands after, falls off).
// Event path: readlane broadcast (no DS), ballot-shift carry, readlane T refresh.
#define KNN_PROC(d, dk, ik, T)                                                  \
  { u64 m = __ballot(d < T);                                                    \
    while (m) {                                                                 \
      const int s = (int)__ffsll((unsigned long long)m) - 1;  m &= m - 1;       \
      const float dc = __uint_as_float((u32)__builtin_amdgcn_readlane(          \
                         (int)__float_as_uint(d), s));                          \
      if (dc < T) {                  /* wave-uniform: skip stale hits */        \
        const bool cnd = dc < dk;                                               \
        const u64 cm = __ballot(cnd) << 1;                                      \
        const float pd = __shfl_up(dk, 1, 64);                                  \
        const int   pi = __shfl_up(ik, 1, 64);                                  \
        const bool pc = (cm >> lane) & 1;                                       \
        dk = cnd ? (pc ? pd : dc) : dk;                                         \
        ik = cnd ? (pc ? pi : (jbase + s)) : ik;                                \
        T = __uint_as_float((u32)__builtin_amdgcn_readlane(                     \
              (int)__float_as_uint(dk), 15));                                   \
      }                                                                         \
    }                                                                           \
  }

__global__ __launch_bounds__(64) void knn_kernel(
    const float* __restrict__ coords4, int* __restrict__ knn_idx) {
  const int p0 = blockIdx.x * 4;       // 4 points per wave, never straddles batch
  const int b = p0 >> 13;
  const int lane = threadIdx.x;
  const float4* cb = ((const float4*)coords4) + (b << 13);
  const float4 c0 = ((const float4*)coords4)[p0+0];
  const float4 c1 = ((const float4*)coords4)[p0+1];
  const float4 c2 = ((const float4*)coords4)[p0+2];
  const float4 c3 = ((const float4*)coords4)[p0+3];

  float dk0 = INFINITY, dk1 = INFINITY, dk2 = INFINITY, dk3 = INFINITY;
  int   ik0 = 0, ik1 = 0, ik2 = 0, ik3 = 0;
  float T0 = INFINITY, T1 = INFINITY, T2 = INFINITY, T3 = INFINITY;

  for (int it = 0; it < N_/64; ++it) {
    const int jbase = it*64;
    const float4 cj = cb[jbase + lane];
    const float d0 = fmaxf(c0.w + cj.w - 2.f*(c0.x*cj.x + c0.y*cj.y + c0.z*cj.z), 0.f);
    const float d1 = fmaxf(c1.w + cj.w - 2.f*(c1.x*cj.x + c1.y*cj.y + c1.z*cj.z), 0.f);
    const float d2 = fmaxf(c2.w + cj.w - 2.f*(c2.x*cj.x + c2.y*cj.y + c2.z*cj.z), 0.f);
    const float d3 = fmaxf(c3.w + cj.w - 2.f*(c3.x*cj.x + c3.y*cj.y + c3.z*cj.z), 0.f);
    KNN_PROC(d0, dk0, ik0, T0);
    KNN_PROC(d1, dk1, ik1, T1);
    KNN_PROC(d2, dk2, ik2, T2);
    KNN_PROC(d3, dk3, ik3, T3);
  }

  if (lane < K_) {
    knn_idx[(size_t)(p0+0)*K_ + lane] = ik0;
    knn_idx[(size_t)(p0+1)*K_ + lane] = ik1;
    knn_idx[(size_t)(p0+2)*K_ + lane] = ik2;
    knn_idx[(size_t)(p0+3)*K_ + lane] = ik3;
  }
}

// ---------------- MFMA local_agg (fp16, 2 tiles/wave, register g+1 prefetch) ----------------
template<int KS, int NPASS>
__global__ __launch_bounds__(256) void aggm_kernel(
    const _Float16* __restrict__ fx, const int* __restrict__ knn_idx,
    const _Float16* __restrict__ midT, const _Float16* __restrict__ difT,
    const float* __restrict__ bw,
    _Float16* __restrict__ fo, const int ostr) {
  const int XD = KS*32;
  const int p0 = blockIdx.x * 16;
  const int bb = (p0 >> 13) << 13;
  const int tid = threadIdx.x;
  const int w = tid >> 6, lane = tid & 63, col = lane & 15, quad = lane >> 4;
  const int koff = quad * 8;

  __shared__ int s_idx[256];
  s_idx[tid] = knn_idx[p0*K_ + tid];
  __syncthreads();

  for (int ps = 0; ps < NPASS; ++ps) {
    const int o0 = ps*128 + w*32;
    const int oa = o0 + col, ob = oa + 16;

    // ---- C part: A rows = the block's own 16 points ----
    f4v cacc0 = {0.f,0.f,0.f,0.f}, cacc1 = {0.f,0.f,0.f,0.f};
    {
      const _Float16* ap = fx + (size_t)(p0+col)*XD + koff;
      const _Float16* b0 = difT + (size_t)oa*XD + koff;
      const _Float16* b1 = difT + (size_t)ob*XD + koff;
#pragma unroll
      for (int kk = 0; kk < KS; ++kk) {
        const h8v ah = *(const h8v*)(ap + kk*32);
        cacc0 = MFMA16(ah, *(const h8v*)(b0 + kk*32), cacc0);
        cacc1 = MFMA16(ah, *(const h8v*)(b1 + kk*32), cacc1);
      }
    }

    // ---- B fragments (weights) in registers ----
    h8v B0[KS], B1[KS];
#pragma unroll
    for (int kk = 0; kk < KS; ++kk) {
      B0[kk] = *(const h8v*)(midT + (size_t)oa*XD + kk*32 + koff);
      B1[kk] = *(const h8v*)(midT + (size_t)ob*XD + kk*32 + koff);
    }
    const float bias0 = bw[oa], bias1 = bw[ob];

    // ---- main loop over the 16 points, A prefetched one g ahead ----
    h8v Ac[KS];
    {
      const _Float16* ap = fx + (size_t)(bb + s_idx[col])*XD + koff;
#pragma unroll
      for (int kk = 0; kk < KS; ++kk) Ac[kk] = *(const h8v*)(ap + kk*32);
    }
    for (int g = 0; g < 16; ++g) {
      h8v An[KS];
      {
        const int gn = (g < 15) ? g + 1 : 15;
        const _Float16* ap = fx + (size_t)(bb + s_idx[gn*16 + col])*XD + koff;
#pragma unroll
        for (int kk = 0; kk < KS; ++kk) An[kk] = *(const h8v*)(ap + kk*32);
      }
      f4v a0 = {0.f,0.f,0.f,0.f}, a1 = {0.f,0.f,0.f,0.f};
#pragma unroll
      for (int kk = 0; kk < KS; ++kk) {
        a0 = MFMA16(Ac[kk], B0[kk], a0);
        a1 = MFMA16(Ac[kk], B1[kk], a1);
      }
      float m0 = fmaxf(fmaxf(a0[0],a0[1]), fmaxf(a0[2],a0[3]));
      float m1 = fmaxf(fmaxf(a1[0],a1[1]), fmaxf(a1[2],a1[3]));
      m0 = fmaxf(m0, __shfl_xor(m0,16,64)); m0 = fmaxf(m0, __shfl_xor(m0,32,64));
      m1 = fmaxf(m1, __shfl_xor(m1,16,64)); m1 = fmaxf(m1, __shfl_xor(m1,32,64));
      const int src = ((g >> 2) << 4) + col;   // C[g][col] lives in quad g>>2, reg g&3
      const float c0 = __shfl(cacc0[g & 3], src, 64);
      const float c1 = __shfl(cacc1[g & 3], src, 64);
      if (lane < 16) {
        fo[(size_t)(p0+g)*ostr + oa] = (_Float16)fmaxf(m0 + c0 + bias0, 0.f);
        fo[(size_t)(p0+g)*ostr + ob] = (_Float16)fmaxf(m1 + c1 + bias1, 0.f);
      }
#pragma unroll
      for (int kk = 0; kk < KS; ++kk) Ac[kk] = An[kk];
    }
  }
}

// ---------------- global max (stage 1, fp16 in, f32 partials) ----------------
__global__ __launch_bounds__(256) void gmax_kernel(
    const _Float16* __restrict__ f2h, float* __restrict__ part) {
  const int b = blockIdx.x >> 5;
  const int seg = blockIdx.x & 31;
  const int o = threadIdx.x;
  float m = -INFINITY;
  const int n0 = seg * 256;
  for (int n = n0; n < n0 + 256; ++n)
    m = fmaxf(m, (float)f2h[((size_t)(b<<13) + n)*W2_ + o]);
  part[(size_t)blockIdx.x*W2_ + o] = m;
}

// ---------------- global max reduce + glob FC -> g2h fp16 ----------------
__global__ __launch_bounds__(256) void gfc_kernel(
    const float* __restrict__ part, const float* __restrict__ gw,
    const float* __restrict__ gb, _Float16* __restrict__ g2h) {
  const int b = blockIdx.x;
  const int o = threadIdx.x;
  __shared__ float s_g[W2_];
  float m = -INFINITY;
  for (int s = 0; s < 32; ++s) m = fmaxf(m, part[(size_t)(b*32+s)*W2_ + o]);
  s_g[o] = m;
  __syncthreads();
  float acc = gb[o];
  for (int d = 0; d < W2_; ++d) acc += s_g[d]*gw[d*W2_ + o];
  g2h[b*W2_ + o] = (_Float16)fmaxf(acc, 0.f);
}

// ---------------- head: 32 points/block MFMA GEMM + tiny second layer ----------------
__global__ __launch_bounds__(256) void headm_kernel(
    const _Float16* __restrict__ f2h, const _Float16* __restrict__ g2h,
    const _Float16* __restrict__ h1wT, const float* __restrict__ h1b,
    const float* __restrict__ h2w, const float* __restrict__ h2b,
    const float* __restrict__ x,
    const float* __restrict__ thresh, const float* __restrict__ sharp,
    const float* __restrict__ scale,
    float* __restrict__ out) {
  const int p0 = blockIdx.x * 32;
  const int b = p0 >> 13;
  const int tid = threadIdx.x;
  const int w = tid >> 6, lane = tid & 63, col = lane & 15, quad = lane >> 4;

  __shared__ _Float16 sA[32*520];   // 32 points x 512 (padded to 520)
  __shared__ float    sh[32*260];   // relu(h1) f32

  for (int t = tid; t < 32*32; t += 256) {       // f2h part (16B chunks)
    const int r = t >> 5, cc = (t & 31) * 8;
    *(uint4*)&sA[r*520 + cc] = *(const uint4*)&f2h[(size_t)(p0+r)*W2_ + cc];
  }
  for (int t = tid; t < 32*32; t += 256) {       // g2h broadcast part
    const int r = t >> 5, cc = (t & 31) * 8;
    *(uint4*)&sA[r*520 + 256 + cc] = *(const uint4*)&g2h[b*W2_ + cc];
  }
  __syncthreads();

  f4v acc[2][4];
#pragma unroll
  for (int r = 0; r < 2; ++r)
#pragma unroll
    for (int t = 0; t < 4; ++t) acc[r][t] = (f4v){0.f,0.f,0.f,0.f};

  for (int kk = 0; kk < 16; ++kk) {
    const h8v a0 = *(const h8v*)&sA[col*520 + kk*32 + quad*8];
    const h8v a1 = *(const h8v*)&sA[(16+col)*520 + kk*32 + quad*8];
#pragma unroll
    for (int t = 0; t < 4; ++t) {
      const h8v bt = *(const h8v*)&h1wT[(size_t)(w*64 + t*16 + col)*512 + kk*32 + quad*8];
      acc[0][t] = MFMA16(a0, bt, acc[0][t]);
      acc[1][t] = MFMA16(a1, bt, acc[1][t]);
    }
  }
#pragma unroll
  for (int r = 0; r < 2; ++r)
#pragma unroll
    for (int t = 0; t < 4; ++t) {
      const int o = w*64 + t*16 + col;
      const float bv = h1b[o];
#pragma unroll
      for (int reg = 0; reg < 4; ++reg)
        sh[(r*16 + quad*4 + reg)*260 + o] = fmaxf(acc[r][t][reg] + bv, 0.f);
    }
  __syncthreads();

  if (tid < 96) {
    const int pp = tid / 3, c = tid % 3;
    float s = h2b[c];
    for (int d = 0; d < 256; ++d) s += sh[pp*260 + d] * h2w[d*3 + c];
    if (c == 0) {
      const float hag = x[(size_t)(p0+pp)*4 + 3];
      s += scale[0] / (1.f + expf(-sharp[0]*(thresh[0] - hag)));
    }
    out[(size_t)(p0+pp)*3 + c] = s;
  }
}

// ---------------- launch ----------------
extern "C" void kernel_launch(void* const* d_in, const int* in_sizes, int n_in,
                              void* d_out, int out_size, void* d_ws, size_t ws_size,
                              hipStream_t stream) {
  const float* x       = (const float*)d_in[0];
  const float* hmix_a  = (const float*)d_in[1];
  const float* hmix_b  = (const float*)d_in[2];
  const float* hmix_c  = (const float*)d_in[3];
  const float* stem_w  = (const float*)d_in[4];
  const float* stem_b  = (const float*)d_in[5];
  const float* b1_w    = (const float*)d_in[6];
  const float* b1_b    = (const float*)d_in[7];
  const float* b2_w    = (const float*)d_in[8];
  const float* b2_b    = (const float*)d_in[9];
  const float* glob_w  = (const float*)d_in[10];
  const float* glob_b  = (const float*)d_in[11];
  const float* head1_w = (const float*)d_in[12];
  const float* head1_b = (const float*)d_in[13];
  const float* head2_w = (const float*)d_in[14];
  const float* head2_b = (const float*)d_in[15];
  const float* thresh  = (const float*)d_in[16];
  const float* sharp   = (const float*)d_in[17];
  const float* scale   = (const float*)d_in[18];
  float* out = (float*)d_out;

  char* base = (char*)d_ws;
  float*     coords4 = (float*)    (base + 0);          // 512 KB
  int*       idxb    = (int*)      (base + 524288);     // 2 MB
  _Float16*  fx0     = (_Float16*) (base + 2621440);    // 6 MB   (32768*96*2)
  _Float16*  fx1     = (_Float16*) (base + 8912896);    // 10 MB  (32768*160*2)
  _Float16*  f2h     = (_Float16*) (base + 19398656);   // 16 MB  (32768*256*2)
  _Float16*  w1m     = (_Float16*) (base + 36175872);   // 24 KB  (128*96*2)
  _Float16*  w1d     = (_Float16*) (base + 36200448);   // 24 KB
  _Float16*  w2m     = (_Float16*) (base + 36225024);   // 80 KB  (256*160*2)
  _Float16*  w2d     = (_Float16*) (base + 36306944);   // 80 KB
  _Float16*  h1wT    = (_Float16*) (base + 36388864);   // 256 KB (256*512*2)
  float*     part    = (float*)    (base + 36651008);   // 128 KB
  _Float16*  g2h     = (_Float16*) (base + 36782080);   // 2 KB

  const int NP = B_ * N_;   // 32768 points

  wconv_kernel<W0_, W1_, X0_><<<W1_, X0_, 0, stream>>>(b1_w, w1m, w1d);
  wconv_kernel<W1_, W2_, X1_><<<W2_, X1_, 0, stream>>>(b2_w, w2m, w2d);
  htrans_kernel<<<W2_, 256, 0, stream>>>(head1_w, h1wT);
  prep_kernel<<<NP, 64, 0, stream>>>(x, stem_w, stem_b, hmix_a, hmix_b, hmix_c,
                                     coords4, fx0);
  fx1tail_kernel<<<NP/2, 64, 0, stream>>>(coords4, fx1);
  knn_kernel<<<NP/4, 64, 0, stream>>>(coords4, idxb);
  aggm_kernel<3, 1><<<NP/16, 256, 0, stream>>>(fx0, idxb, w1m, w1d, b1_b, fx1, X1_);
  aggm_kernel<5, 2><<<NP/16, 256, 0, stream>>>(fx1, idxb, w2m, w2d, b2_b, f2h, W2_);
  gmax_kernel<<<B_*32, 256, 0, stream>>>(f2h, part);
  gfc_kernel<<<B_, 256, 0, stream>>>(part, glob_w, glob_b, g2h);
  headm_kernel<<<NP/32, 256, 0, stream>>>(f2h, g2h, h1wT, head1_b, head2_w, head2_b,
                                          x, thresh, sharp, scale, out);
}

// Round 7
// 561.325 us; speedup vs baseline: 4.1595x; 1.0402x over previous
//
#include <hip/hip_runtime.h>
#include <math.h>

typedef unsigned long long u64;
typedef unsigned int u32;
typedef _Float16 h8v __attribute__((ext_vector_type(8)));  // 8 fp16 (4 VGPRs)
typedef float    f4v __attribute__((ext_vector_type(4)));  // MFMA acc

#define MFMA16(a,b,c) __builtin_amdgcn_mfma_f32_16x16x32_f16(a, b, c, 0, 0, 0)

#define B_ 4
#define N_ 8192
#define K_ 16
#define W0_ 64
#define W1_ 128
#define W2_ 256
#define X0_ 96   // padded K-dim layer-1 inputs (64 feat + 3 coord + 29 zero)
#define X1_ 160  // padded K-dim layer-2 inputs (128 feat + 3 coord + 29 zero)

// ---------------- prep: coords4 + stem MLP -> fx0 (fp16, padded) ----------------
__global__ __launch_bounds__(64) void prep_kernel(
    const float* __restrict__ x,
    const float* __restrict__ stem_w, const float* __restrict__ stem_b,
    const float* __restrict__ hmix_a, const float* __restrict__ hmix_b,
    const float* __restrict__ hmix_c,
    float* __restrict__ coords4, _Float16* __restrict__ fx0) {
  const int p = blockIdx.x;
  const int o = threadIdx.x;
  const float x0 = x[p*4+0], x1 = x[p*4+1], x2 = x[p*4+2], x3 = x[p*4+3];
  const float z = hmix_a[0]*x2 + hmix_b[0]*x3 + hmix_c[0];
  float acc = stem_b[o] + x0*stem_w[0*W0_+o] + x1*stem_w[1*W0_+o]
            + x2*stem_w[2*W0_+o] + x3*stem_w[3*W0_+o];
  fx0[p*X0_+o] = (_Float16)fmaxf(acc, 0.f);
  if (o < 32) {   // tail: 3 coords + 29 zeros
    const float tv = (o==0) ? x0 : (o==1) ? x1 : (o==2) ? z : 0.f;
    fx0[p*X0_+W0_+o] = (_Float16)tv;
  }
  if (o == 0) {
    const float xx = x0*x0 + x1*x1 + z*z;
    ((float4*)coords4)[p] = make_float4(x0, x1, z, xx);
  }
}

// ---------------- fx1 tail: coords + zero-pad ----------------
__global__ __launch_bounds__(64) void fx1tail_kernel(
    const float* __restrict__ coords4, _Float16* __restrict__ fx1) {
  const int p = blockIdx.x*2 + (threadIdx.x >> 5);
  const int o = threadIdx.x & 31;
  const float4 c = ((const float4*)coords4)[p];
  const float tv = (o==0) ? c.x : (o==1) ? c.y : (o==2) ? c.z : 0.f;
  fx1[(size_t)p*X1_ + W1_ + o] = (_Float16)tv;
}

// ---------------- weight conversion: transposed, extended, fp16 ----------------
template<int DIN, int DOUT, int XDIM>
__global__ void wconv_kernel(const float* __restrict__ w,
    _Float16* __restrict__ midT, _Float16* __restrict__ difT) {
  const int o = blockIdx.x;
  const int c = threadIdx.x;
  float mv = 0.f, dv = 0.f;
  if (c < DIN)        { const float wm = w[(DIN+c)*DOUT+o]; mv = wm; dv = w[c*DOUT+o] - wm; }
  else if (c < DIN+3) { const float wp = w[(2*DIN+(c-DIN))*DOUT+o]; mv = wp; dv = -wp; }
  midT[o*XDIM+c] = (_Float16)mv;
  difT[o*XDIM+c] = (_Float16)dv;
}

// ---------------- head1 weight transpose -> fp16 ----------------
__global__ __launch_bounds__(256) void htrans_kernel(
    const float* __restrict__ h1w, _Float16* __restrict__ h1wT) {
  const int o = blockIdx.x;
  for (int c = threadIdx.x; c < 512; c += 256)
    h1wT[(size_t)o*512 + c] = (_Float16)h1w[(size_t)c*256 + o];
}

// ---------------- knn: one wave per 4 points ----------------
// Wave-distributed 64-lane globally-sorted list (lanes 0..15 = top-16).
// Strict-< insertion in ascending-j order reproduces top_k tie-break exactly.
// Insertion is self-correcting (stale candidate lands at pos>=16), so T is a
// pure perf filter: refreshed per chunk (per event only in warmup chunk 0).
// Shuffles via raw ds_bpermute with precomputed (lane-1)*4 address.
#define KNN_EVT(d, dk, ik, refresh, T)                                          \
  {                                                                             \
    const int s = (int)__ffsll((unsigned long long)m) - 1;  m &= m - 1;         \
    const float dc = __uint_as_float((u32)__builtin_amdgcn_readlane(            \
                       (int)__float_as_uint(d), s));                            \
    if (!refresh || dc < T) {                                                   \
      const bool cnd = dc < dk;                                                 \
      const u64 cm = __ballot(cnd) << 1;                                        \
      const float pd = __uint_as_float((u32)__builtin_amdgcn_ds_bpermute(       \
                         bpa, (int)__float_as_uint(dk)));                       \
      const int   pi = __builtin_amdgcn_ds_bpermute(bpa, ik);                   \
      const bool pc = (cm >> lane) & 1;                                         \
      dk = cnd ? (pc ? pd : dc) : dk;                                           \
      ik = cnd ? (pc ? pi : (jbase + s)) : ik;                                  \
      if (refresh)                                                              \
        T = __uint_as_float((u32)__builtin_amdgcn_readlane(                     \
              (int)__float_as_uint(dk), 15));                                   \
    }                                                                           \
  }

#define KNN_CHUNK(d, dk, ik, T)                                                 \
  { u64 m = __ballot(d < T);                                                    \
    if (m) {                                                                    \
      do { KNN_EVT(d, dk, ik, false, T) } while (m);                            \
      T = __uint_as_float((u32)__builtin_amdgcn_readlane(                       \
            (int)__float_as_uint(dk), 15));                                     \
    }                                                                           \
  }

__global__ __launch_bounds__(64) void knn_kernel(
    const float* __restrict__ coords4, int* __restrict__ knn_idx) {
  const int p0 = blockIdx.x * 4;       // 4 points per wave, never straddles batch
  const int b = p0 >> 13;
  const int lane = threadIdx.x;
  const int bpa = (lane - 1) * 4;      // ds_bpermute shift-up address (lane0: don't-care)
  const float4* cb = ((const float4*)coords4) + (b << 13);
  const float4 c0 = ((const float4*)coords4)[p0+0];
  const float4 c1 = ((const float4*)coords4)[p0+1];
  const float4 c2 = ((const float4*)coords4)[p0+2];
  const float4 c3 = ((const float4*)coords4)[p0+3];

  float dk0 = INFINITY, dk1 = INFINITY, dk2 = INFINITY, dk3 = INFINITY;
  int   ik0 = 0, ik1 = 0, ik2 = 0, ik3 = 0;
  float T0 = INFINITY, T1 = INFINITY, T2 = INFINITY, T3 = INFINITY;

  { // warmup chunk 0: per-event T refresh prunes the 64 initial hits
    const int jbase = 0;
    const float4 cj = cb[lane];
    const float d0 = fmaxf(c0.w + cj.w - 2.f*(c0.x*cj.x + c0.y*cj.y + c0.z*cj.z), 0.f);
    const float d1 = fmaxf(c1.w + cj.w - 2.f*(c1.x*cj.x + c1.y*cj.y + c1.z*cj.z), 0.f);
    const float d2 = fmaxf(c2.w + cj.w - 2.f*(c2.x*cj.x + c2.y*cj.y + c2.z*cj.z), 0.f);
    const float d3 = fmaxf(c3.w + cj.w - 2.f*(c3.x*cj.x + c3.y*cj.y + c3.z*cj.z), 0.f);
    { u64 m = __ballot(d0 < T0); while (m) KNN_EVT(d0, dk0, ik0, true, T0) }
    { u64 m = __ballot(d1 < T1); while (m) KNN_EVT(d1, dk1, ik1, true, T1) }
    { u64 m = __ballot(d2 < T2); while (m) KNN_EVT(d2, dk2, ik2, true, T2) }
    { u64 m = __ballot(d3 < T3); while (m) KNN_EVT(d3, dk3, ik3, true, T3) }
  }

  for (int it = 1; it < N_/64; ++it) {
    const int jbase = it*64;
    const float4 cj = cb[jbase + lane];
    const float d0 = fmaxf(c0.w + cj.w - 2.f*(c0.x*cj.x + c0.y*cj.y + c0.z*cj.z), 0.f);
    const float d1 = fmaxf(c1.w + cj.w - 2.f*(c1.x*cj.x + c1.y*cj.y + c1.z*cj.z), 0.f);
    const float d2 = fmaxf(c2.w + cj.w - 2.f*(c2.x*cj.x + c2.y*cj.y + c2.z*cj.z), 0.f);
    const float d3 = fmaxf(c3.w + cj.w - 2.f*(c3.x*cj.x + c3.y*cj.y + c3.z*cj.z), 0.f);
    KNN_CHUNK(d0, dk0, ik0, T0);
    KNN_CHUNK(d1, dk1, ik1, T1);
    KNN_CHUNK(d2, dk2, ik2, T2);
    KNN_CHUNK(d3, dk3, ik3, T3);
  }

  if (lane < K_) {
    knn_idx[(size_t)(p0+0)*K_ + lane] = ik0;
    knn_idx[(size_t)(p0+1)*K_ + lane] = ik1;
    knn_idx[(size_t)(p0+2)*K_ + lane] = ik2;
    knn_idx[(size_t)(p0+3)*K_ + lane] = ik3;
  }
}

// ---------------- MFMA local_agg with LDS-staged neighbor rows ----------------
// Block = 16 points x 4 waves. Neighbor rows (256 per block) staged into LDS in
// two 128-row halves (pad +8 fp16/row: conflict-free b128 reads); all waves and
// both passes read A-fragments from LDS instead of re-gathering from global.
template<int KS, int NPASS>
__global__ __launch_bounds__(256) void aggm_kernel(
    const _Float16* __restrict__ fx, const int* __restrict__ knn_idx,
    const _Float16* __restrict__ midT, const _Float16* __restrict__ difT,
    const float* __restrict__ bw,
    _Float16* __restrict__ fo, const int ostr) {
  const int XD  = KS*32;
  const int XDP = XD + 8;
  const int CH  = KS*4;                 // uint4 chunks per row
  const int p0 = blockIdx.x * 16;
  const int bb = (p0 >> 13) << 13;
  const int tid = threadIdx.x;
  const int w = tid >> 6, lane = tid & 63, col = lane & 15, quad = lane >> 4;
  const int koff = quad * 8;

  __shared__ int s_idx[256];
  __shared__ _Float16 sA[128*(KS*32+8)];

  s_idx[tid] = knn_idx[p0*K_ + tid];

  // ---- C part (k-independent): own 16 rows x difT, for all passes ----
  f4v cacc[NPASS][2];
  {
    h8v Ao[KS];
    const _Float16* ap = fx + (size_t)(p0+col)*XD + koff;
#pragma unroll
    for (int kk = 0; kk < KS; ++kk) Ao[kk] = *(const h8v*)(ap + kk*32);
#pragma unroll
    for (int ps = 0; ps < NPASS; ++ps) {
      const int o0 = ps*128 + w*32;
      const _Float16* b0 = difT + (size_t)(o0 + col)*XD + koff;
      const _Float16* b1 = difT + (size_t)(o0 + 16 + col)*XD + koff;
      f4v c0 = {0.f,0.f,0.f,0.f}, c1 = {0.f,0.f,0.f,0.f};
#pragma unroll
      for (int kk = 0; kk < KS; ++kk) {
        c0 = MFMA16(Ao[kk], *(const h8v*)(b0 + kk*32), c0);
        c1 = MFMA16(Ao[kk], *(const h8v*)(b1 + kk*32), c1);
      }
      cacc[ps][0] = c0; cacc[ps][1] = c1;
    }
  }
  __syncthreads();   // s_idx ready

  for (int half = 0; half < 2; ++half) {
    // ---- stage 128 neighbor rows into LDS ----
    for (int c = tid; c < 128*CH; c += 256) {
      const int r = c / CH, o = c - r*CH;
      const _Float16* src = fx + (size_t)(bb + s_idx[half*128 + r])*XD + o*8;
      *(uint4*)&sA[r*XDP + o*8] = *(const uint4*)src;
    }
    __syncthreads();

#pragma unroll
    for (int ps = 0; ps < NPASS; ++ps) {
      const int o0 = ps*128 + w*32;
      const int oa = o0 + col, ob = oa + 16;
      h8v B0[KS], B1[KS];
#pragma unroll
      for (int kk = 0; kk < KS; ++kk) {
        B0[kk] = *(const h8v*)(midT + (size_t)oa*XD + kk*32 + koff);
        B1[kk] = *(const h8v*)(midT + (size_t)ob*XD + kk*32 + koff);
      }
      const float bias0 = bw[oa], bias1 = bw[ob];

      for (int g8 = 0; g8 < 8; ++g8) {
        const int g = half*8 + g8;
        const _Float16* ap = &sA[(g8*16 + col)*XDP + koff];
        f4v a0 = {0.f,0.f,0.f,0.f}, a1 = {0.f,0.f,0.f,0.f};
#pragma unroll
        for (int kk = 0; kk < KS; ++kk) {
          const h8v av = *(const h8v*)(ap + kk*32);
          a0 = MFMA16(av, B0[kk], a0);
          a1 = MFMA16(av, B1[kk], a1);
        }
        float m0 = fmaxf(fmaxf(a0[0],a0[1]), fmaxf(a0[2],a0[3]));
        float m1 = fmaxf(fmaxf(a1[0],a1[1]), fmaxf(a1[2],a1[3]));
        m0 = fmaxf(m0, __shfl_xor(m0,16,64)); m0 = fmaxf(m0, __shfl_xor(m0,32,64));
        m1 = fmaxf(m1, __shfl_xor(m1,16,64)); m1 = fmaxf(m1, __shfl_xor(m1,32,64));
        const int src = ((g >> 2) << 4) + col;   // C[g][col]: quad g>>2, reg g&3
        const float c0 = __shfl(cacc[ps][0][g & 3], src, 64);
        const float c1 = __shfl(cacc[ps][1][g & 3], src, 64);
        if (lane < 16) {
          fo[(size_t)(p0+g)*ostr + oa] = (_Float16)fmaxf(m0 + c0 + bias0, 0.f);
          fo[(size_t)(p0+g)*ostr + ob] = (_Float16)fmaxf(m1 + c1 + bias1, 0.f);
        }
      }
    }
    if (half == 0) __syncthreads();   // drain reads before restaging
  }
}

// ---------------- global max (stage 1, fp16 in, f32 partials) ----------------
__global__ __launch_bounds__(256) void gmax_kernel(
    const _Float16* __restrict__ f2h, float* __restrict__ part) {
  const int b = blockIdx.x >> 5;
  const int seg = blockIdx.x & 31;
  const int o = threadIdx.x;
  float m = -INFINITY;
  const int n0 = seg * 256;
  for (int n = n0; n < n0 + 256; ++n)
    m = fmaxf(m, (float)f2h[((size_t)(b<<13) + n)*W2_ + o]);
  part[(size_t)blockIdx.x*W2_ + o] = m;
}

// ---------------- global max reduce + glob FC -> g2h fp16 ----------------
__global__ __launch_bounds__(256) void gfc_kernel(
    const float* __restrict__ part, const float* __restrict__ gw,
    const float* __restrict__ gb, _Float16* __restrict__ g2h) {
  const int b = blockIdx.x;
  const int o = threadIdx.x;
  __shared__ float s_g[W2_];
  float m = -INFINITY;
  for (int s = 0; s < 32; ++s) m = fmaxf(m, part[(size_t)(b*32+s)*W2_ + o]);
  s_g[o] = m;
  __syncthreads();
  float acc = gb[o];
  for (int d = 0; d < W2_; ++d) acc += s_g[d]*gw[d*W2_ + o];
  g2h[b*W2_ + o] = (_Float16)fmaxf(acc, 0.f);
}

// ---------------- head: 32 points/block MFMA GEMM + tiny second layer ----------------
__global__ __launch_bounds__(256) void headm_kernel(
    const _Float16* __restrict__ f2h, const _Float16* __restrict__ g2h,
    const _Float16* __restrict__ h1wT, const float* __restrict__ h1b,
    const float* __restrict__ h2w, const float* __restrict__ h2b,
    const float* __restrict__ x,
    const float* __restrict__ thresh, const float* __restrict__ sharp,
    const float* __restrict__ scale,
    float* __restrict__ out) {
  const int p0 = blockIdx.x * 32;
  const int b = p0 >> 13;
  const int tid = threadIdx.x;
  const int w = tid >> 6, lane = tid & 63, col = lane & 15, quad = lane >> 4;

  __shared__ _Float16 sA[32*520];   // 32 points x 512 (padded to 520)
  __shared__ float    sh[32*260];   // relu(h1) f32

  for (int t = tid; t < 32*32; t += 256) {       // f2h part (16B chunks)
    const int r = t >> 5, cc = (t & 31) * 8;
    *(uint4*)&sA[r*520 + cc] = *(const uint4*)&f2h[(size_t)(p0+r)*W2_ + cc];
  }
  for (int t = tid; t < 32*32; t += 256) {       // g2h broadcast part
    const int r = t >> 5, cc = (t & 31) * 8;
    *(uint4*)&sA[r*520 + 256 + cc] = *(const uint4*)&g2h[b*W2_ + cc];
  }
  __syncthreads();

  f4v acc[2][4];
#pragma unroll
  for (int r = 0; r < 2; ++r)
#pragma unroll
    for (int t = 0; t < 4; ++t) acc[r][t] = (f4v){0.f,0.f,0.f,0.f};

  for (int kk = 0; kk < 16; ++kk) {
    const h8v a0 = *(const h8v*)&sA[col*520 + kk*32 + quad*8];
    const h8v a1 = *(const h8v*)&sA[(16+col)*520 + kk*32 + quad*8];
#pragma unroll
    for (int t = 0; t < 4; ++t) {
      const h8v bt = *(const h8v*)&h1wT[(size_t)(w*64 + t*16 + col)*512 + kk*32 + quad*8];
      acc[0][t] = MFMA16(a0, bt, acc[0][t]);
      acc[1][t] = MFMA16(a1, bt, acc[1][t]);
    }
  }
#pragma unroll
  for (int r = 0; r < 2; ++r)
#pragma unroll
    for (int t = 0; t < 4; ++t) {
      const int o = w*64 + t*16 + col;
      const float bv = h1b[o];
#pragma unroll
      for (int reg = 0; reg < 4; ++reg)
        sh[(r*16 + quad*4 + reg)*260 + o] = fmaxf(acc[r][t][reg] + bv, 0.f);
    }
  __syncthreads();

  if (tid < 96) {
    const int pp = tid / 3, c = tid % 3;
    float s = h2b[c];
    for (int d = 0; d < 256; ++d) s += sh[pp*260 + d] * h2w[d*3 + c];
    if (c == 0) {
      const float hag = x[(size_t)(p0+pp)*4 + 3];
      s += scale[0] / (1.f + expf(-sharp[0]*(thresh[0] - hag)));
    }
    out[(size_t)(p0+pp)*3 + c] = s;
  }
}

// ---------------- launch ----------------
extern "C" void kernel_launch(void* const* d_in, const int* in_sizes, int n_in,
                              void* d_out, int out_size, void* d_ws, size_t ws_size,
                              hipStream_t stream) {
  const float* x       = (const float*)d_in[0];
  const float* hmix_a  = (const float*)d_in[1];
  const float* hmix_b  = (const float*)d_in[2];
  const float* hmix_c  = (const float*)d_in[3];
  const float* stem_w  = (const float*)d_in[4];
  const float* stem_b  = (const float*)d_in[5];
  const float* b1_w    = (const float*)d_in[6];
  const float* b1_b    = (const float*)d_in[7];
  const float* b2_w    = (const float*)d_in[8];
  const float* b2_b    = (const float*)d_in[9];
  const float* glob_w  = (const float*)d_in[10];
  const float* glob_b  = (const float*)d_in[11];
  const float* head1_w = (const float*)d_in[12];
  const float* head1_b = (const float*)d_in[13];
  const float* head2_w = (const float*)d_in[14];
  const float* head2_b = (const float*)d_in[15];
  const float* thresh  = (const float*)d_in[16];
  const float* sharp   = (const float*)d_in[17];
  const float* scale   = (const float*)d_in[18];
  float* out = (float*)d_out;

  char* base = (char*)d_ws;
  float*     coords4 = (float*)    (base + 0);          // 512 KB
  int*       idxb    = (int*)      (base + 524288);     // 2 MB
  _Float16*  fx0     = (_Float16*) (base + 2621440);    // 6 MB   (32768*96*2)
  _Float16*  fx1     = (_Float16*) (base + 8912896);    // 10 MB  (32768*160*2)
  _Float16*  f2h     = (_Float16*) (base + 19398656);   // 16 MB  (32768*256*2)
  _Float16*  w1m     = (_Float16*) (base + 36175872);   // 24 KB  (128*96*2)
  _Float16*  w1d     = (_Float16*) (base + 36200448);   // 24 KB
  _Float16*  w2m     = (_Float16*) (base + 36225024);   // 80 KB  (256*160*2)
  _Float16*  w2d     = (_Float16*) (base + 36306944);   // 80 KB
  _Float16*  h1wT    = (_Float16*) (base + 36388864);   // 256 KB (256*512*2)
  float*     part    = (float*)    (base + 36651008);   // 128 KB
  _Float16*  g2h     = (_Float16*) (base + 36782080);   // 2 KB

  const int NP = B_ * N_;   // 32768 points

  wconv_kernel<W0_, W1_, X0_><<<W1_, X0_, 0, stream>>>(b1_w, w1m, w1d);
  wconv_kernel<W1_, W2_, X1_><<<W2_, X1_, 0, stream>>>(b2_w, w2m, w2d);
  htrans_kernel<<<W2_, 256, 0, stream>>>(head1_w, h1wT);
  prep_kernel<<<NP, 64, 0, stream>>>(x, stem_w, stem_b, hmix_a, hmix_b, hmix_c,
                                     coords4, fx0);
  fx1tail_kernel<<<NP/2, 64, 0, stream>>>(coords4, fx1);
  knn_kernel<<<NP/4, 64, 0, stream>>>(coords4, idxb);
  aggm_kernel<3, 1><<<NP/16, 256, 0, stream>>>(fx0, idxb, w1m, w1d, b1_b, fx1, X1_);
  aggm_kernel<5, 2><<<NP/16, 256, 0, stream>>>(fx1, idxb, w2m, w2d, b2_b, f2h, W2_);
  gmax_kernel<<<B_*32, 256, 0, stream>>>(f2h, part);
  gfc_kernel<<<B_, 256, 0, stream>>>(part, glob_w, glob_b, g2h);
  headm_kernel<<<NP/32, 256, 0, stream>>>(f2h, g2h, h1wT, head1_b, head2_w, head2_b,
                                          x, thresh, sharp, scale, out);
}

// Round 8
// 541.682 us; speedup vs baseline: 4.3104x; 1.0363x over previous
//
#include <hip/hip_runtime.h>
#include <math.h>

typedef unsigned long long u64;
typedef unsigned int u32;
typedef _Float16 h8v __attribute__((ext_vector_type(8)));  // 8 fp16 (4 VGPRs)
typedef float    f4v __attribute__((ext_vector_type(4)));  // MFMA acc

#define MFMA16(a,b,c) __builtin_amdgcn_mfma_f32_16x16x32_f16(a, b, c, 0, 0, 0)

#define B_ 4
#define N_ 8192
#define K_ 16
#define W0_ 64
#define W1_ 128
#define W2_ 256
#define X0_ 96   // padded K-dim layer-1 inputs (64 feat + 3 coord + 29 zero)
#define X1_ 160  // padded K-dim layer-2 inputs (128 feat + 3 coord + 29 zero)

// ---------------- prep: coords4 + stem MLP -> fx0 (fp16, padded) ----------------
__global__ __launch_bounds__(64) void prep_kernel(
    const float* __restrict__ x,
    const float* __restrict__ stem_w, const float* __restrict__ stem_b,
    const float* __restrict__ hmix_a, const float* __restrict__ hmix_b,
    const float* __restrict__ hmix_c,
    float* __restrict__ coords4, _Float16* __restrict__ fx0) {
  const int p = blockIdx.x;
  const int o = threadIdx.x;
  const float x0 = x[p*4+0], x1 = x[p*4+1], x2 = x[p*4+2], x3 = x[p*4+3];
  const float z = hmix_a[0]*x2 + hmix_b[0]*x3 + hmix_c[0];
  float acc = stem_b[o] + x0*stem_w[0*W0_+o] + x1*stem_w[1*W0_+o]
            + x2*stem_w[2*W0_+o] + x3*stem_w[3*W0_+o];
  fx0[p*X0_+o] = (_Float16)fmaxf(acc, 0.f);
  if (o < 32) {   // tail: 3 coords + 29 zeros
    const float tv = (o==0) ? x0 : (o==1) ? x1 : (o==2) ? z : 0.f;
    fx0[p*X0_+W0_+o] = (_Float16)tv;
  }
  if (o == 0) {
    const float xx = x0*x0 + x1*x1 + z*z;
    ((float4*)coords4)[p] = make_float4(x0, x1, z, xx);
  }
}

// ---------------- fx1 tail: coords + zero-pad ----------------
__global__ __launch_bounds__(64) void fx1tail_kernel(
    const float* __restrict__ coords4, _Float16* __restrict__ fx1) {
  const int p = blockIdx.x*2 + (threadIdx.x >> 5);
  const int o = threadIdx.x & 31;
  const float4 c = ((const float4*)coords4)[p];
  const float tv = (o==0) ? c.x : (o==1) ? c.y : (o==2) ? c.z : 0.f;
  fx1[(size_t)p*X1_ + W1_ + o] = (_Float16)tv;
}

// ---------------- weight conversion: transposed, extended, fp16 ----------------
template<int DIN, int DOUT, int XDIM>
__global__ void wconv_kernel(const float* __restrict__ w,
    _Float16* __restrict__ midT, _Float16* __restrict__ difT) {
  const int o = blockIdx.x;
  const int c = threadIdx.x;
  float mv = 0.f, dv = 0.f;
  if (c < DIN)        { const float wm = w[(DIN+c)*DOUT+o]; mv = wm; dv = w[c*DOUT+o] - wm; }
  else if (c < DIN+3) { const float wp = w[(2*DIN+(c-DIN))*DOUT+o]; mv = wp; dv = -wp; }
  midT[o*XDIM+c] = (_Float16)mv;
  difT[o*XDIM+c] = (_Float16)dv;
}

// ---------------- head1 weight transpose -> fp16 ----------------
__global__ __launch_bounds__(256) void htrans_kernel(
    const float* __restrict__ h1w, _Float16* __restrict__ h1wT) {
  const int o = blockIdx.x;
  for (int c = threadIdx.x; c < 512; c += 256)
    h1wT[(size_t)o*512 + c] = (_Float16)h1w[(size_t)c*256 + o];
}

// ---------------- knn: one wave per 4 points ----------------
// Wave-distributed 64-lane globally-sorted list (lanes 0..15 = top-16).
// Strict-< insertion in ascending-j order reproduces top_k tie-break exactly.
// Shift-up-by-1 via DPP wave_shr1 (0x138): 1 VALU inst, no LDS round-trip
// (replaces ds_bpermute's ~30-cyc latency in the serial event chain).
#define DPP_SHR1(v) __builtin_amdgcn_update_dpp(0, (v), 0x138, 0xF, 0xF, false)

#define KNN_EVT(d, dk, ik, refresh, T)                                          \
  {                                                                             \
    const int s = (int)__ffsll((unsigned long long)m) - 1;  m &= m - 1;         \
    const float dc = __uint_as_float((u32)__builtin_amdgcn_readlane(            \
                       (int)__float_as_uint(d), s));                            \
    if (!refresh || dc < T) {                                                   \
      const bool cnd = dc < dk;                                                 \
      const u64 cm = __ballot(cnd) << 1;                                        \
      const float pd = __uint_as_float((u32)DPP_SHR1((int)__float_as_uint(dk)));\
      const int   pi = DPP_SHR1(ik);                                            \
      const bool pc = (cm >> lane) & 1;                                         \
      dk = cnd ? (pc ? pd : dc) : dk;                                           \
      ik = cnd ? (pc ? pi : (jbase + s)) : ik;                                  \
      if (refresh)                                                              \
        T = __uint_as_float((u32)__builtin_amdgcn_readlane(                     \
              (int)__float_as_uint(dk), 15));                                   \
    }                                                                           \
  }

#define KNN_CHUNK(d, dk, ik, T)                                                 \
  { u64 m = __ballot(d < T);                                                    \
    if (m) {                                                                    \
      do { KNN_EVT(d, dk, ik, false, T) } while (m);                            \
      T = __uint_as_float((u32)__builtin_amdgcn_readlane(                       \
            (int)__float_as_uint(dk), 15));                                     \
    }                                                                           \
  }

__global__ __launch_bounds__(64) void knn_kernel(
    const float* __restrict__ coords4, int* __restrict__ knn_idx) {
  const int p0 = blockIdx.x * 4;       // 4 points per wave, never straddles batch
  const int b = p0 >> 13;
  const int lane = threadIdx.x;
  const float4* cb = ((const float4*)coords4) + (b << 13);
  const float4 c0 = ((const float4*)coords4)[p0+0];
  const float4 c1 = ((const float4*)coords4)[p0+1];
  const float4 c2 = ((const float4*)coords4)[p0+2];
  const float4 c3 = ((const float4*)coords4)[p0+3];

  float dk0 = INFINITY, dk1 = INFINITY, dk2 = INFINITY, dk3 = INFINITY;
  int   ik0 = 0, ik1 = 0, ik2 = 0, ik3 = 0;
  float T0 = INFINITY, T1 = INFINITY, T2 = INFINITY, T3 = INFINITY;

  { // warmup chunk 0: per-event T refresh prunes the 64 initial hits
    const int jbase = 0;
    const float4 cj = cb[lane];
    const float d0 = fmaxf(c0.w + cj.w - 2.f*(c0.x*cj.x + c0.y*cj.y + c0.z*cj.z), 0.f);
    const float d1 = fmaxf(c1.w + cj.w - 2.f*(c1.x*cj.x + c1.y*cj.y + c1.z*cj.z), 0.f);
    const float d2 = fmaxf(c2.w + cj.w - 2.f*(c2.x*cj.x + c2.y*cj.y + c2.z*cj.z), 0.f);
    const float d3 = fmaxf(c3.w + cj.w - 2.f*(c3.x*cj.x + c3.y*cj.y + c3.z*cj.z), 0.f);
    { u64 m = __ballot(d0 < T0); while (m) KNN_EVT(d0, dk0, ik0, true, T0) }
    { u64 m = __ballot(d1 < T1); while (m) KNN_EVT(d1, dk1, ik1, true, T1) }
    { u64 m = __ballot(d2 < T2); while (m) KNN_EVT(d2, dk2, ik2, true, T2) }
    { u64 m = __ballot(d3 < T3); while (m) KNN_EVT(d3, dk3, ik3, true, T3) }
  }

  for (int it = 1; it < N_/64; ++it) {
    const int jbase = it*64;
    const float4 cj = cb[jbase + lane];
    const float d0 = fmaxf(c0.w + cj.w - 2.f*(c0.x*cj.x + c0.y*cj.y + c0.z*cj.z), 0.f);
    const float d1 = fmaxf(c1.w + cj.w - 2.f*(c1.x*cj.x + c1.y*cj.y + c1.z*cj.z), 0.f);
    const float d2 = fmaxf(c2.w + cj.w - 2.f*(c2.x*cj.x + c2.y*cj.y + c2.z*cj.z), 0.f);
    const float d3 = fmaxf(c3.w + cj.w - 2.f*(c3.x*cj.x + c3.y*cj.y + c3.z*cj.z), 0.f);
    KNN_CHUNK(d0, dk0, ik0, T0);
    KNN_CHUNK(d1, dk1, ik1, T1);
    KNN_CHUNK(d2, dk2, ik2, T2);
    KNN_CHUNK(d3, dk3, ik3, T3);
  }

  if (lane < K_) {
    knn_idx[(size_t)(p0+0)*K_ + lane] = ik0;
    knn_idx[(size_t)(p0+1)*K_ + lane] = ik1;
    knn_idx[(size_t)(p0+2)*K_ + lane] = ik2;
    knn_idx[(size_t)(p0+3)*K_ + lane] = ik3;
  }
}

// ---------------- MFMA local_agg with LDS-staged neighbor rows ----------------
template<int KS, int NPASS>
__global__ __launch_bounds__(256) void aggm_kernel(
    const _Float16* __restrict__ fx, const int* __restrict__ knn_idx,
    const _Float16* __restrict__ midT, const _Float16* __restrict__ difT,
    const float* __restrict__ bw,
    _Float16* __restrict__ fo, const int ostr) {
  const int XD  = KS*32;
  const int XDP = XD + 8;
  const int CH  = KS*4;                 // uint4 chunks per row
  const int p0 = blockIdx.x * 16;
  const int bb = (p0 >> 13) << 13;
  const int tid = threadIdx.x;
  const int w = tid >> 6, lane = tid & 63, col = lane & 15, quad = lane >> 4;
  const int koff = quad * 8;

  __shared__ int s_idx[256];
  __shared__ _Float16 sA[128*(KS*32+8)];

  s_idx[tid] = knn_idx[p0*K_ + tid];

  // ---- C part (k-independent): own 16 rows x difT, for all passes ----
  f4v cacc[NPASS][2];
  {
    h8v Ao[KS];
    const _Float16* ap = fx + (size_t)(p0+col)*XD + koff;
#pragma unroll
    for (int kk = 0; kk < KS; ++kk) Ao[kk] = *(const h8v*)(ap + kk*32);
#pragma unroll
    for (int ps = 0; ps < NPASS; ++ps) {
      const int o0 = ps*128 + w*32;
      const _Float16* b0 = difT + (size_t)(o0 + col)*XD + koff;
      const _Float16* b1 = difT + (size_t)(o0 + 16 + col)*XD + koff;
      f4v c0 = {0.f,0.f,0.f,0.f}, c1 = {0.f,0.f,0.f,0.f};
#pragma unroll
      for (int kk = 0; kk < KS; ++kk) {
        c0 = MFMA16(Ao[kk], *(const h8v*)(b0 + kk*32), c0);
        c1 = MFMA16(Ao[kk], *(const h8v*)(b1 + kk*32), c1);
      }
      cacc[ps][0] = c0; cacc[ps][1] = c1;
    }
  }
  __syncthreads();   // s_idx ready

  for (int half = 0; half < 2; ++half) {
    // ---- stage 128 neighbor rows into LDS ----
    for (int c = tid; c < 128*CH; c += 256) {
      const int r = c / CH, o = c - r*CH;
      const _Float16* src = fx + (size_t)(bb + s_idx[half*128 + r])*XD + o*8;
      *(uint4*)&sA[r*XDP + o*8] = *(const uint4*)src;
    }
    __syncthreads();

#pragma unroll
    for (int ps = 0; ps < NPASS; ++ps) {
      const int o0 = ps*128 + w*32;
      const int oa = o0 + col, ob = oa + 16;
      h8v B0[KS], B1[KS];
#pragma unroll
      for (int kk = 0; kk < KS; ++kk) {
        B0[kk] = *(const h8v*)(midT + (size_t)oa*XD + kk*32 + koff);
        B1[kk] = *(const h8v*)(midT + (size_t)ob*XD + kk*32 + koff);
      }
      const float bias0 = bw[oa], bias1 = bw[ob];

      for (int g8 = 0; g8 < 8; ++g8) {
        const int g = half*8 + g8;
        const _Float16* ap = &sA[(g8*16 + col)*XDP + koff];
        f4v a0 = {0.f,0.f,0.f,0.f}, a1 = {0.f,0.f,0.f,0.f};
#pragma unroll
        for (int kk = 0; kk < KS; ++kk) {
          const h8v av = *(const h8v*)(ap + kk*32);
          a0 = MFMA16(av, B0[kk], a0);
          a1 = MFMA16(av, B1[kk], a1);
        }
        float m0 = fmaxf(fmaxf(a0[0],a0[1]), fmaxf(a0[2],a0[3]));
        float m1 = fmaxf(fmaxf(a1[0],a1[1]), fmaxf(a1[2],a1[3]));
        m0 = fmaxf(m0, __shfl_xor(m0,16,64)); m0 = fmaxf(m0, __shfl_xor(m0,32,64));
        m1 = fmaxf(m1, __shfl_xor(m1,16,64)); m1 = fmaxf(m1, __shfl_xor(m1,32,64));
        const int src = ((g >> 2) << 4) + col;   // C[g][col]: quad g>>2, reg g&3
        const float c0 = __shfl(cacc[ps][0][g & 3], src, 64);
        const float c1 = __shfl(cacc[ps][1][g & 3], src, 64);
        if (lane < 16) {
          fo[(size_t)(p0+g)*ostr + oa] = (_Float16)fmaxf(m0 + c0 + bias0, 0.f);
          fo[(size_t)(p0+g)*ostr + ob] = (_Float16)fmaxf(m1 + c1 + bias1, 0.f);
        }
      }
    }
    if (half == 0) __syncthreads();   // drain reads before restaging
  }
}

// ---------------- global max (stage 1): coalesced uint4 loads ----------------
// Block = 8 row-groups x 32 col-chunks; each half-wave load is 512B contiguous.
__global__ __launch_bounds__(256) void gmax_kernel(
    const _Float16* __restrict__ f2h, float* __restrict__ part) {
  const int b = blockIdx.x >> 5;
  const int seg = blockIdx.x & 31;
  const int tid = threadIdx.x;
  const int rg = tid >> 5;            // 0..7
  const int cc = (tid & 31) * 8;      // col chunk base
  __shared__ float smax[8][256];
  const size_t rbase = (size_t)(b << 13) + seg*256;
  _Float16 mh[8];
#pragma unroll
  for (int j = 0; j < 8; ++j) mh[j] = (_Float16)0.f;   // relu outputs >= 0
  for (int n = rg; n < 256; n += 8) {
    const h8v v = *(const h8v*)&f2h[(rbase + n)*W2_ + cc];
#pragma unroll
    for (int j = 0; j < 8; ++j) mh[j] = (v[j] > mh[j]) ? v[j] : mh[j];
  }
#pragma unroll
  for (int j = 0; j < 8; ++j) smax[rg][cc + j] = (float)mh[j];
  __syncthreads();
  float m = smax[0][tid];
#pragma unroll
  for (int g = 1; g < 8; ++g) m = fmaxf(m, smax[g][tid]);
  part[(size_t)blockIdx.x*W2_ + tid] = m;
}

// ---------------- global max reduce + glob FC -> g2h fp16 ----------------
__global__ __launch_bounds__(256) void gfc_kernel(
    const float* __restrict__ part, const float* __restrict__ gw,
    const float* __restrict__ gb, _Float16* __restrict__ g2h) {
  const int b = blockIdx.x;
  const int o = threadIdx.x;
  __shared__ float s_g[W2_];
  float m = -INFINITY;
  for (int s = 0; s < 32; ++s) m = fmaxf(m, part[(size_t)(b*32+s)*W2_ + o]);
  s_g[o] = m;
  __syncthreads();
  float acc = gb[o];
  for (int d = 0; d < W2_; ++d) acc += s_g[d]*gw[d*W2_ + o];
  g2h[b*W2_ + o] = (_Float16)fmaxf(acc, 0.f);
}

// ---------------- head: 32 points/block MFMA GEMM + tiny second layer ----------------
__global__ __launch_bounds__(256) void headm_kernel(
    const _Float16* __restrict__ f2h, const _Float16* __restrict__ g2h,
    const _Float16* __restrict__ h1wT, const float* __restrict__ h1b,
    const float* __restrict__ h2w, const float* __restrict__ h2b,
    const float* __restrict__ x,
    const float* __restrict__ thresh, const float* __restrict__ sharp,
    const float* __restrict__ scale,
    float* __restrict__ out) {
  const int p0 = blockIdx.x * 32;
  const int b = p0 >> 13;
  const int tid = threadIdx.x;
  const int w = tid >> 6, lane = tid & 63, col = lane & 15, quad = lane >> 4;

  __shared__ _Float16 sA[32*520];   // 32 points x 512 (padded to 520)
  __shared__ float    sh[32*260];   // relu(h1) f32

  for (int t = tid; t < 32*32; t += 256) {       // f2h part (16B chunks)
    const int r = t >> 5, cc = (t & 31) * 8;
    *(uint4*)&sA[r*520 + cc] = *(const uint4*)&f2h[(size_t)(p0+r)*W2_ + cc];
  }
  for (int t = tid; t < 32*32; t += 256) {       // g2h broadcast part
    const int r = t >> 5, cc = (t & 31) * 8;
    *(uint4*)&sA[r*520 + 256 + cc] = *(const uint4*)&g2h[b*W2_ + cc];
  }
  __syncthreads();

  f4v acc[2][4];
#pragma unroll
  for (int r = 0; r < 2; ++r)
#pragma unroll
    for (int t = 0; t < 4; ++t) acc[r][t] = (f4v){0.f,0.f,0.f,0.f};

  for (int kk = 0; kk < 16; ++kk) {
    const h8v a0 = *(const h8v*)&sA[col*520 + kk*32 + quad*8];
    const h8v a1 = *(const h8v*)&sA[(16+col)*520 + kk*32 + quad*8];
#pragma unroll
    for (int t = 0; t < 4; ++t) {
      const h8v bt = *(const h8v*)&h1wT[(size_t)(w*64 + t*16 + col)*512 + kk*32 + quad*8];
      acc[0][t] = MFMA16(a0, bt, acc[0][t]);
      acc[1][t] = MFMA16(a1, bt, acc[1][t]);
    }
  }
#pragma unroll
  for (int r = 0; r < 2; ++r)
#pragma unroll
    for (int t = 0; t < 4; ++t) {
      const int o = w*64 + t*16 + col;
      const float bv = h1b[o];
#pragma unroll
      for (int reg = 0; reg < 4; ++reg)
        sh[(r*16 + quad*4 + reg)*260 + o] = fmaxf(acc[r][t][reg] + bv, 0.f);
    }
  __syncthreads();

  if (tid < 96) {
    const int pp = tid / 3, c = tid % 3;
    float s = h2b[c];
    for (int d = 0; d < 256; ++d) s += sh[pp*260 + d] * h2w[d*3 + c];
    if (c == 0) {
      const float hag = x[(size_t)(p0+pp)*4 + 3];
      s += scale[0] / (1.f + expf(-sharp[0]*(thresh[0] - hag)));
    }
    out[(size_t)(p0+pp)*3 + c] = s;
  }
}

// ---------------- launch ----------------
extern "C" void kernel_launch(void* const* d_in, const int* in_sizes, int n_in,
                              void* d_out, int out_size, void* d_ws, size_t ws_size,
                              hipStream_t stream) {
  const float* x       = (const float*)d_in[0];
  const float* hmix_a  = (const float*)d_in[1];
  const float* hmix_b  = (const float*)d_in[2];
  const float* hmix_c  = (const float*)d_in[3];
  const float* stem_w  = (const float*)d_in[4];
  const float* stem_b  = (const float*)d_in[5];
  const float* b1_w    = (const float*)d_in[6];
  const float* b1_b    = (const float*)d_in[7];
  const float* b2_w    = (const float*)d_in[8];
  const float* b2_b    = (const float*)d_in[9];
  const float* glob_w  = (const float*)d_in[10];
  const float* glob_b  = (const float*)d_in[11];
  const float* head1_w = (const float*)d_in[12];
  const float* head1_b = (const float*)d_in[13];
  const float* head2_w = (const float*)d_in[14];
  const float* head2_b = (const float*)d_in[15];
  const float* thresh  = (const float*)d_in[16];
  const float* sharp   = (const float*)d_in[17];
  const float* scale   = (const float*)d_in[18];
  float* out = (float*)d_out;

  char* base = (char*)d_ws;
  float*     coords4 = (float*)    (base + 0);          // 512 KB
  int*       idxb    = (int*)      (base + 524288);     // 2 MB
  _Float16*  fx0     = (_Float16*) (base + 2621440);    // 6 MB   (32768*96*2)
  _Float16*  fx1     = (_Float16*) (base + 8912896);    // 10 MB  (32768*160*2)
  _Float16*  f2h     = (_Float16*) (base + 19398656);   // 16 MB  (32768*256*2)
  _Float16*  w1m     = (_Float16*) (base + 36175872);   // 24 KB  (128*96*2)
  _Float16*  w1d     = (_Float16*) (base + 36200448);   // 24 KB
  _Float16*  w2m     = (_Float16*) (base + 36225024);   // 80 KB  (256*160*2)
  _Float16*  w2d     = (_Float16*) (base + 36306944);   // 80 KB
  _Float16*  h1wT    = (_Float16*) (base + 36388864);   // 256 KB (256*512*2)
  float*     part    = (float*)    (base + 36651008);   // 128 KB
  _Float16*  g2h     = (_Float16*) (base + 36782080);   // 2 KB

  const int NP = B_ * N_;   // 32768 points

  wconv_kernel<W0_, W1_, X0_><<<W1_, X0_, 0, stream>>>(b1_w, w1m, w1d);
  wconv_kernel<W1_, W2_, X1_><<<W2_, X1_, 0, stream>>>(b2_w, w2m, w2d);
  htrans_kernel<<<W2_, 256, 0, stream>>>(head1_w, h1wT);
  prep_kernel<<<NP, 64, 0, stream>>>(x, stem_w, stem_b, hmix_a, hmix_b, hmix_c,
                                     coords4, fx0);
  fx1tail_kernel<<<NP/2, 64, 0, stream>>>(coords4, fx1);
  knn_kernel<<<NP/4, 64, 0, stream>>>(coords4, idxb);
  aggm_kernel<3, 1><<<NP/16, 256, 0, stream>>>(fx0, idxb, w1m, w1d, b1_b, fx1, X1_);
  aggm_kernel<5, 2><<<NP/16, 256, 0, stream>>>(fx1, idxb, w2m, w2d, b2_b, f2h, W2_);
  gmax_kernel<<<B_*32, 256, 0, stream>>>(f2h, part);
  gfc_kernel<<<B_, 256, 0, stream>>>(part, glob_w, glob_b, g2h);
  headm_kernel<<<NP/32, 256, 0, stream>>>(f2h, g2h, h1wT, head1_b, head2_w, head2_b,
                                          x, thresh, sharp, scale, out);
}

// Round 9
// 489.161 us; speedup vs baseline: 4.7732x; 1.1074x over previous
//
#include <hip/hip_runtime.h>
#include <math.h>

typedef unsigned long long u64;
typedef unsigned int u32;
typedef _Float16 h8v __attribute__((ext_vector_type(8)));  // 8 fp16 (4 VGPRs)
typedef float    f4v __attribute__((ext_vector_type(4)));  // MFMA acc

#define MFMA16(a,b,c) __builtin_amdgcn_mfma_f32_16x16x32_f16(a, b, c, 0, 0, 0)

#define B_ 4
#define N_ 8192
#define K_ 16
#define W0_ 64
#define W1_ 128
#define W2_ 256
#define X0_ 96   // padded K-dim layer-1 inputs (64 feat + 3 coord + 29 zero)
#define X1_ 160  // padded K-dim layer-2 inputs (128 feat + 3 coord + 29 zero)

// ---------------- prep: coords4 + stem MLP -> fx0 (+ fx1 tail, fused) ----------------
__global__ __launch_bounds__(64) void prep_kernel(
    const float* __restrict__ x,
    const float* __restrict__ stem_w, const float* __restrict__ stem_b,
    const float* __restrict__ hmix_a, const float* __restrict__ hmix_b,
    const float* __restrict__ hmix_c,
    float* __restrict__ coords4, _Float16* __restrict__ fx0,
    _Float16* __restrict__ fx1) {
  const int p = blockIdx.x;
  const int o = threadIdx.x;
  const float x0 = x[p*4+0], x1 = x[p*4+1], x2 = x[p*4+2], x3 = x[p*4+3];
  const float z = hmix_a[0]*x2 + hmix_b[0]*x3 + hmix_c[0];
  float acc = stem_b[o] + x0*stem_w[0*W0_+o] + x1*stem_w[1*W0_+o]
            + x2*stem_w[2*W0_+o] + x3*stem_w[3*W0_+o];
  fx0[p*X0_+o] = (_Float16)fmaxf(acc, 0.f);
  if (o < 32) {   // tail: 3 coords + 29 zeros (both layers' inputs)
    const float tv = (o==0) ? x0 : (o==1) ? x1 : (o==2) ? z : 0.f;
    fx0[p*X0_+W0_+o] = (_Float16)tv;
    fx1[(size_t)p*X1_+W1_+o] = (_Float16)tv;
  }
  if (o == 0) {
    const float xx = x0*x0 + x1*x1 + z*z;
    ((float4*)coords4)[p] = make_float4(x0, x1, z, xx);
  }
}

// ---------------- weight conversion: transposed, extended, fp16 ----------------
template<int DIN, int DOUT, int XDIM>
__global__ void wconv_kernel(const float* __restrict__ w,
    _Float16* __restrict__ midT, _Float16* __restrict__ difT) {
  const int o = blockIdx.x;
  const int c = threadIdx.x;
  float mv = 0.f, dv = 0.f;
  if (c < DIN)        { const float wm = w[(DIN+c)*DOUT+o]; mv = wm; dv = w[c*DOUT+o] - wm; }
  else if (c < DIN+3) { const float wp = w[(2*DIN+(c-DIN))*DOUT+o]; mv = wp; dv = -wp; }
  midT[o*XDIM+c] = (_Float16)mv;
  difT[o*XDIM+c] = (_Float16)dv;
}

// ---------------- head1 weight transpose -> fp16 ----------------
__global__ __launch_bounds__(256) void htrans_kernel(
    const float* __restrict__ h1w, _Float16* __restrict__ h1wT) {
  const int o = blockIdx.x;
  for (int c = threadIdx.x; c < 512; c += 256)
    h1wT[(size_t)o*512 + c] = (_Float16)h1w[(size_t)c*256 + o];
}

// ---------------- knn: one wave per 4 points, threshold pre-pass ----------------
// Exactness: the 16th smallest of the 64 per-lane minima over ANY candidate
// subset is >= d16 of that subset >= d16 of the full set (if 16 minima were
// < d16 they'd be 16 distinct candidates below the 16th smallest). So T-hat
// from pass A is a valid upper bound; main-pass ballot uses d <= T to keep
// boundary ties; strict-< insertion in ascending-j order reproduces top_k's
// lower-index tie-break exactly (unchanged since r6).
#define DPP_SHR1(v) __builtin_amdgcn_update_dpp(0, (v), 0x138, 0xF, 0xF, false)

#define DPP_MIN(v, ctrl)                                                        \
  { const int _t = __builtin_amdgcn_update_dpp(__float_as_int(v),               \
      __float_as_int(v), ctrl, 0xF, 0xF, false);                                \
    v = fminf(v, __int_as_float(_t)); }

// 16th smallest (distinct) of the 64 lane values; still an upper bound on d16.
__device__ __forceinline__ float sixteenth_of_minima(float v) {
  float th = 0.f;
#pragma unroll
  for (int r = 0; r < 16; ++r) {
    float w = v;
    DPP_MIN(w, 0x111); DPP_MIN(w, 0x112); DPP_MIN(w, 0x114); DPP_MIN(w, 0x118);
    DPP_MIN(w, 0x142); DPP_MIN(w, 0x143);   // row_bcast15 / row_bcast31
    const float mv = __int_as_float(
        __builtin_amdgcn_readlane(__float_as_int(w), 63));
    th = mv;
    v = (v == mv) ? INFINITY : v;
  }
  return th;
}

#define KNN_EVT(d, dk, ik)                                                      \
  {                                                                             \
    const int s = (int)__ffsll((unsigned long long)m) - 1;  m &= m - 1;         \
    const float dc = __int_as_float(__builtin_amdgcn_readlane(                  \
                       __float_as_int(d), s));                                  \
    const bool cnd = dc < dk;                                                   \
    const u64 cm = __ballot(cnd) << 1;                                          \
    const float pd = __int_as_float(DPP_SHR1(__float_as_int(dk)));              \
    const int   pi = DPP_SHR1(ik);                                              \
    const bool pc = (cm >> lane) & 1;                                           \
    dk = cnd ? (pc ? pd : dc) : dk;                                             \
    ik = cnd ? (pc ? pi : (jbase + s)) : ik;                                    \
  }

#define KNN_CHUNK(d, dk, ik, T, Th)                                             \
  { u64 m = __ballot(d <= T);                                                   \
    if (m) {                                                                    \
      do { KNN_EVT(d, dk, ik) } while (m);                                      \
      T = fminf(Th, __int_as_float(__builtin_amdgcn_readlane(                   \
            __float_as_int(dk), 15)));                                          \
    }                                                                           \
  }

__global__ __launch_bounds__(64) void knn_kernel(
    const float* __restrict__ coords4, int* __restrict__ knn_idx) {
  const int p0 = blockIdx.x * 4;       // 4 points per wave, never straddles batch
  const int b = p0 >> 13;
  const int lane = threadIdx.x;
  const float4* cb = ((const float4*)coords4) + (b << 13);
  const float4 c0 = ((const float4*)coords4)[p0+0];
  const float4 c1 = ((const float4*)coords4)[p0+1];
  const float4 c2 = ((const float4*)coords4)[p0+2];
  const float4 c3 = ((const float4*)coords4)[p0+3];

  // ---- pass A: per-lane minima over the first half (straight-line, no events)
  float lm0 = INFINITY, lm1 = INFINITY, lm2 = INFINITY, lm3 = INFINITY;
  for (int it = 0; it < 64; ++it) {
    const float4 cj = cb[it*64 + lane];
    lm0 = fminf(lm0, fmaxf(c0.w + cj.w - 2.f*(c0.x*cj.x + c0.y*cj.y + c0.z*cj.z), 0.f));
    lm1 = fminf(lm1, fmaxf(c1.w + cj.w - 2.f*(c1.x*cj.x + c1.y*cj.y + c1.z*cj.z), 0.f));
    lm2 = fminf(lm2, fmaxf(c2.w + cj.w - 2.f*(c2.x*cj.x + c2.y*cj.y + c2.z*cj.z), 0.f));
    lm3 = fminf(lm3, fmaxf(c3.w + cj.w - 2.f*(c3.x*cj.x + c3.y*cj.y + c3.z*cj.z), 0.f));
  }
  const float Th0 = sixteenth_of_minima(lm0);
  const float Th1 = sixteenth_of_minima(lm1);
  const float Th2 = sixteenth_of_minima(lm2);
  const float Th3 = sixteenth_of_minima(lm3);

  float dk0 = INFINITY, dk1 = INFINITY, dk2 = INFINITY, dk3 = INFINITY;
  int   ik0 = 0, ik1 = 0, ik2 = 0, ik3 = 0;
  float T0 = Th0, T1 = Th1, T2 = Th2, T3 = Th3;

  // ---- main pass: all candidates, events only below the tight bound
  for (int it = 0; it < N_/64; ++it) {
    const int jbase = it*64;
    const float4 cj = cb[jbase + lane];
    const float d0 = fmaxf(c0.w + cj.w - 2.f*(c0.x*cj.x + c0.y*cj.y + c0.z*cj.z), 0.f);
    const float d1 = fmaxf(c1.w + cj.w - 2.f*(c1.x*cj.x + c1.y*cj.y + c1.z*cj.z), 0.f);
    const float d2 = fmaxf(c2.w + cj.w - 2.f*(c2.x*cj.x + c2.y*cj.y + c2.z*cj.z), 0.f);
    const float d3 = fmaxf(c3.w + cj.w - 2.f*(c3.x*cj.x + c3.y*cj.y + c3.z*cj.z), 0.f);
    KNN_CHUNK(d0, dk0, ik0, T0, Th0);
    KNN_CHUNK(d1, dk1, ik1, T1, Th1);
    KNN_CHUNK(d2, dk2, ik2, T2, Th2);
    KNN_CHUNK(d3, dk3, ik3, T3, Th3);
  }

  if (lane < K_) {
    knn_idx[(size_t)(p0+0)*K_ + lane] = ik0;
    knn_idx[(size_t)(p0+1)*K_ + lane] = ik1;
    knn_idx[(size_t)(p0+2)*K_ + lane] = ik2;
    knn_idx[(size_t)(p0+3)*K_ + lane] = ik3;
  }
}

// ---------------- MFMA local_agg with LDS-staged neighbor rows ----------------
template<int KS, int NPASS>
__global__ __launch_bounds__(256) void aggm_kernel(
    const _Float16* __restrict__ fx, const int* __restrict__ knn_idx,
    const _Float16* __restrict__ midT, const _Float16* __restrict__ difT,
    const float* __restrict__ bw,
    _Float16* __restrict__ fo, const int ostr) {
  const int XD  = KS*32;
  const int XDP = XD + 8;
  const int CH  = KS*4;                 // uint4 chunks per row
  const int p0 = blockIdx.x * 16;
  const int bb = (p0 >> 13) << 13;
  const int tid = threadIdx.x;
  const int w = tid >> 6, lane = tid & 63, col = lane & 15, quad = lane >> 4;
  const int koff = quad * 8;

  __shared__ int s_idx[256];
  __shared__ _Float16 sA[128*(KS*32+8)];

  s_idx[tid] = knn_idx[p0*K_ + tid];

  // ---- C part (k-independent): own 16 rows x difT, for all passes ----
  f4v cacc[NPASS][2];
  {
    h8v Ao[KS];
    const _Float16* ap = fx + (size_t)(p0+col)*XD + koff;
#pragma unroll
    for (int kk = 0; kk < KS; ++kk) Ao[kk] = *(const h8v*)(ap + kk*32);
#pragma unroll
    for (int ps = 0; ps < NPASS; ++ps) {
      const int o0 = ps*128 + w*32;
      const _Float16* b0 = difT + (size_t)(o0 + col)*XD + koff;
      const _Float16* b1 = difT + (size_t)(o0 + 16 + col)*XD + koff;
      f4v c0 = {0.f,0.f,0.f,0.f}, c1 = {0.f,0.f,0.f,0.f};
#pragma unroll
      for (int kk = 0; kk < KS; ++kk) {
        c0 = MFMA16(Ao[kk], *(const h8v*)(b0 + kk*32), c0);
        c1 = MFMA16(Ao[kk], *(const h8v*)(b1 + kk*32), c1);
      }
      cacc[ps][0] = c0; cacc[ps][1] = c1;
    }
  }
  __syncthreads();   // s_idx ready

  for (int half = 0; half < 2; ++half) {
    // ---- stage 128 neighbor rows into LDS ----
    for (int c = tid; c < 128*CH; c += 256) {
      const int r = c / CH, o = c - r*CH;
      const _Float16* src = fx + (size_t)(bb + s_idx[half*128 + r])*XD + o*8;
      *(uint4*)&sA[r*XDP + o*8] = *(const uint4*)src;
    }
    __syncthreads();

#pragma unroll
    for (int ps = 0; ps < NPASS; ++ps) {
      const int o0 = ps*128 + w*32;
      const int oa = o0 + col, ob = oa + 16;
      h8v B0[KS], B1[KS];
#pragma unroll
      for (int kk = 0; kk < KS; ++kk) {
        B0[kk] = *(const h8v*)(midT + (size_t)oa*XD + kk*32 + koff);
        B1[kk] = *(const h8v*)(midT + (size_t)ob*XD + kk*32 + koff);
      }
      const float bias0 = bw[oa], bias1 = bw[ob];

      for (int g8 = 0; g8 < 8; ++g8) {
        const int g = half*8 + g8;
        const _Float16* ap = &sA[(g8*16 + col)*XDP + koff];
        f4v a0 = {0.f,0.f,0.f,0.f}, a1 = {0.f,0.f,0.f,0.f};
#pragma unroll
        for (int kk = 0; kk < KS; ++kk) {
          const h8v av = *(const h8v*)(ap + kk*32);
          a0 = MFMA16(av, B0[kk], a0);
          a1 = MFMA16(av, B1[kk], a1);
        }
        float m0 = fmaxf(fmaxf(a0[0],a0[1]), fmaxf(a0[2],a0[3]));
        float m1 = fmaxf(fmaxf(a1[0],a1[1]), fmaxf(a1[2],a1[3]));
        m0 = fmaxf(m0, __shfl_xor(m0,16,64)); m0 = fmaxf(m0, __shfl_xor(m0,32,64));
        m1 = fmaxf(m1, __shfl_xor(m1,16,64)); m1 = fmaxf(m1, __shfl_xor(m1,32,64));
        const int src = ((g >> 2) << 4) + col;   // C[g][col]: quad g>>2, reg g&3
        const float c0 = __shfl(cacc[ps][0][g & 3], src, 64);
        const float c1 = __shfl(cacc[ps][1][g & 3], src, 64);
        if (lane < 16) {
          fo[(size_t)(p0+g)*ostr + oa] = (_Float16)fmaxf(m0 + c0 + bias0, 0.f);
          fo[(size_t)(p0+g)*ostr + ob] = (_Float16)fmaxf(m1 + c1 + bias1, 0.f);
        }
      }
    }
    if (half == 0) __syncthreads();   // drain reads before restaging
  }
}

// ---------------- global max (stage 1): coalesced uint4 loads ----------------
__global__ __launch_bounds__(256) void gmax_kernel(
    const _Float16* __restrict__ f2h, float* __restrict__ part) {
  const int b = blockIdx.x >> 5;
  const int seg = blockIdx.x & 31;
  const int tid = threadIdx.x;
  const int rg = tid >> 5;            // 0..7
  const int cc = (tid & 31) * 8;      // col chunk base
  __shared__ float smax[8][256];
  const size_t rbase = (size_t)(b << 13) + seg*256;
  _Float16 mh[8];
#pragma unroll
  for (int j = 0; j < 8; ++j) mh[j] = (_Float16)0.f;   // relu outputs >= 0
  for (int n = rg; n < 256; n += 8) {
    const h8v v = *(const h8v*)&f2h[(rbase + n)*W2_ + cc];
#pragma unroll
    for (int j = 0; j < 8; ++j) mh[j] = (v[j] > mh[j]) ? v[j] : mh[j];
  }
#pragma unroll
  for (int j = 0; j < 8; ++j) smax[rg][cc + j] = (float)mh[j];
  __syncthreads();
  float m = smax[0][tid];
#pragma unroll
  for (int g = 1; g < 8; ++g) m = fmaxf(m, smax[g][tid]);
  part[(size_t)blockIdx.x*W2_ + tid] = m;
}

// ---------------- global max reduce + glob FC -> g2h fp16 ----------------
__global__ __launch_bounds__(256) void gfc_kernel(
    const float* __restrict__ part, const float* __restrict__ gw,
    const float* __restrict__ gb, _Float16* __restrict__ g2h) {
  const int b = blockIdx.x;
  const int o = threadIdx.x;
  __shared__ float s_g[W2_];
  float m = -INFINITY;
  for (int s = 0; s < 32; ++s) m = fmaxf(m, part[(size_t)(b*32+s)*W2_ + o]);
  s_g[o] = m;
  __syncthreads();
  float acc = gb[o];
  for (int d = 0; d < W2_; ++d) acc += s_g[d]*gw[d*W2_ + o];
  g2h[b*W2_ + o] = (_Float16)fmaxf(acc, 0.f);
}

// ---------------- head: 32 points/block MFMA GEMM + tiny second layer ----------------
__global__ __launch_bounds__(256) void headm_kernel(
    const _Float16* __restrict__ f2h, const _Float16* __restrict__ g2h,
    const _Float16* __restrict__ h1wT, const float* __restrict__ h1b,
    const float* __restrict__ h2w, const float* __restrict__ h2b,
    const float* __restrict__ x,
    const float* __restrict__ thresh, const float* __restrict__ sharp,
    const float* __restrict__ scale,
    float* __restrict__ out) {
  const int p0 = blockIdx.x * 32;
  const int b = p0 >> 13;
  const int tid = threadIdx.x;
  const int w = tid >> 6, lane = tid & 63, col = lane & 15, quad = lane >> 4;

  __shared__ _Float16 sA[32*520];   // 32 points x 512 (padded to 520)
  __shared__ float    sh[32*260];   // relu(h1) f32

  for (int t = tid; t < 32*32; t += 256) {       // f2h part (16B chunks)
    const int r = t >> 5, cc = (t & 31) * 8;
    *(uint4*)&sA[r*520 + cc] = *(const uint4*)&f2h[(size_t)(p0+r)*W2_ + cc];
  }
  for (int t = tid; t < 32*32; t += 256) {       // g2h broadcast part
    const int r = t >> 5, cc = (t & 31) * 8;
    *(uint4*)&sA[r*520 + 256 + cc] = *(const uint4*)&g2h[b*W2_ + cc];
  }
  __syncthreads();

  f4v acc[2][4];
#pragma unroll
  for (int r = 0; r < 2; ++r)
#pragma unroll
    for (int t = 0; t < 4; ++t) acc[r][t] = (f4v){0.f,0.f,0.f,0.f};

  for (int kk = 0; kk < 16; ++kk) {
    const h8v a0 = *(const h8v*)&sA[col*520 + kk*32 + quad*8];
    const h8v a1 = *(const h8v*)&sA[(16+col)*520 + kk*32 + quad*8];
#pragma unroll
    for (int t = 0; t < 4; ++t) {
      const h8v bt = *(const h8v*)&h1wT[(size_t)(w*64 + t*16 + col)*512 + kk*32 + quad*8];
      acc[0][t] = MFMA16(a0, bt, acc[0][t]);
      acc[1][t] = MFMA16(a1, bt, acc[1][t]);
    }
  }
#pragma unroll
  for (int r = 0; r < 2; ++r)
#pragma unroll
    for (int t = 0; t < 4; ++t) {
      const int o = w*64 + t*16 + col;
      const float bv = h1b[o];
#pragma unroll
      for (int reg = 0; reg < 4; ++reg)
        sh[(r*16 + quad*4 + reg)*260 + o] = fmaxf(acc[r][t][reg] + bv, 0.f);
    }
  __syncthreads();

  if (tid < 96) {
    const int pp = tid / 3, c = tid % 3;
    float s = h2b[c];
    for (int d = 0; d < 256; ++d) s += sh[pp*260 + d] * h2w[d*3 + c];
    if (c == 0) {
      const float hag = x[(size_t)(p0+pp)*4 + 3];
      s += scale[0] / (1.f + expf(-sharp[0]*(thresh[0] - hag)));
    }
    out[(size_t)(p0+pp)*3 + c] = s;
  }
}

// ---------------- launch ----------------
extern "C" void kernel_launch(void* const* d_in, const int* in_sizes, int n_in,
                              void* d_out, int out_size, void* d_ws, size_t ws_size,
                              hipStream_t stream) {
  const float* x       = (const float*)d_in[0];
  const float* hmix_a  = (const float*)d_in[1];
  const float* hmix_b  = (const float*)d_in[2];
  const float* hmix_c  = (const float*)d_in[3];
  const float* stem_w  = (const float*)d_in[4];
  const float* stem_b  = (const float*)d_in[5];
  const float* b1_w    = (const float*)d_in[6];
  const float* b1_b    = (const float*)d_in[7];
  const float* b2_w    = (const float*)d_in[8];
  const float* b2_b    = (const float*)d_in[9];
  const float* glob_w  = (const float*)d_in[10];
  const float* glob_b  = (const float*)d_in[11];
  const float* head1_w = (const float*)d_in[12];
  const float* head1_b = (const float*)d_in[13];
  const float* head2_w = (const float*)d_in[14];
  const float* head2_b = (const float*)d_in[15];
  const float* thresh  = (const float*)d_in[16];
  const float* sharp   = (const float*)d_in[17];
  const float* scale   = (const float*)d_in[18];
  float* out = (float*)d_out;

  char* base = (char*)d_ws;
  float*     coords4 = (float*)    (base + 0);          // 512 KB
  int*       idxb    = (int*)      (base + 524288);     // 2 MB
  _Float16*  fx0     = (_Float16*) (base + 2621440);    // 6 MB   (32768*96*2)
  _Float16*  fx1     = (_Float16*) (base + 8912896);    // 10 MB  (32768*160*2)
  _Float16*  f2h     = (_Float16*) (base + 19398656);   // 16 MB  (32768*256*2)
  _Float16*  w1m     = (_Float16*) (base + 36175872);   // 24 KB  (128*96*2)
  _Float16*  w1d     = (_Float16*) (base + 36200448);   // 24 KB
  _Float16*  w2m     = (_Float16*) (base + 36225024);   // 80 KB  (256*160*2)
  _Float16*  w2d     = (_Float16*) (base + 36306944);   // 80 KB
  _Float16*  h1wT    = (_Float16*) (base + 36388864);   // 256 KB (256*512*2)
  float*     part    = (float*)    (base + 36651008);   // 128 KB
  _Float16*  g2h     = (_Float16*) (base + 36782080);   // 2 KB

  const int NP = B_ * N_;   // 32768 points

  wconv_kernel<W0_, W1_, X0_><<<W1_, X0_, 0, stream>>>(b1_w, w1m, w1d);
  wconv_kernel<W1_, W2_, X1_><<<W2_, X1_, 0, stream>>>(b2_w, w2m, w2d);
  htrans_kernel<<<W2_, 256, 0, stream>>>(head1_w, h1wT);
  prep_kernel<<<NP, 64, 0, stream>>>(x, stem_w, stem_b, hmix_a, hmix_b, hmix_c,
                                     coords4, fx0, fx1);
  knn_kernel<<<NP/4, 64, 0, stream>>>(coords4, idxb);
  aggm_kernel<3, 1><<<NP/16, 256, 0, stream>>>(fx0, idxb, w1m, w1d, b1_b, fx1, X1_);
  aggm_kernel<5, 2><<<NP/16, 256, 0, stream>>>(fx1, idxb, w2m, w2d, b2_b, f2h, W2_);
  gmax_kernel<<<B_*32, 256, 0, stream>>>(f2h, part);
  gfc_kernel<<<B_, 256, 0, stream>>>(part, glob_w, glob_b, g2h);
  headm_kernel<<<NP/32, 256, 0, stream>>>(f2h, g2h, h1wT, head1_b, head2_w, head2_b,
                                          x, thresh, sharp, scale, out);
}

// Round 10
// 484.797 us; speedup vs baseline: 4.8161x; 1.0090x over previous
//
#include <hip/hip_runtime.h>
#include <math.h>

typedef unsigned long long u64;
typedef unsigned int u32;
typedef _Float16 h8v __attribute__((ext_vector_type(8)));  // 8 fp16 (4 VGPRs)
typedef float    f4v __attribute__((ext_vector_type(4)));  // MFMA acc

#define MFMA16(a,b,c) __builtin_amdgcn_mfma_f32_16x16x32_f16(a, b, c, 0, 0, 0)

#define B_ 4
#define N_ 8192
#define K_ 16
#define W0_ 64
#define W1_ 128
#define W2_ 256
#define X0_ 96   // padded K-dim layer-1 inputs (64 feat + 3 coord + 29 zero)
#define X1_ 160  // padded K-dim layer-2 inputs (128 feat + 3 coord + 29 zero)

// ---------------- prep: coords4 + stem MLP -> fx0 (+ fx1 tail, fused) ----------------
__global__ __launch_bounds__(64) void prep_kernel(
    const float* __restrict__ x,
    const float* __restrict__ stem_w, const float* __restrict__ stem_b,
    const float* __restrict__ hmix_a, const float* __restrict__ hmix_b,
    const float* __restrict__ hmix_c,
    float* __restrict__ coords4, _Float16* __restrict__ fx0,
    _Float16* __restrict__ fx1) {
  const int p = blockIdx.x;
  const int o = threadIdx.x;
  const float x0 = x[p*4+0], x1 = x[p*4+1], x2 = x[p*4+2], x3 = x[p*4+3];
  const float z = hmix_a[0]*x2 + hmix_b[0]*x3 + hmix_c[0];
  float acc = stem_b[o] + x0*stem_w[0*W0_+o] + x1*stem_w[1*W0_+o]
            + x2*stem_w[2*W0_+o] + x3*stem_w[3*W0_+o];
  fx0[p*X0_+o] = (_Float16)fmaxf(acc, 0.f);
  if (o < 32) {   // tail: 3 coords + 29 zeros (both layers' inputs)
    const float tv = (o==0) ? x0 : (o==1) ? x1 : (o==2) ? z : 0.f;
    fx0[p*X0_+W0_+o] = (_Float16)tv;
    fx1[(size_t)p*X1_+W1_+o] = (_Float16)tv;
  }
  if (o == 0) {
    const float xx = x0*x0 + x1*x1 + z*z;
    ((float4*)coords4)[p] = make_float4(x0, x1, z, xx);
  }
}

// ---------------- weight conversion: transposed, extended, fp16 ----------------
template<int DIN, int DOUT, int XDIM>
__global__ void wconv_kernel(const float* __restrict__ w,
    _Float16* __restrict__ midT, _Float16* __restrict__ difT) {
  const int o = blockIdx.x;
  const int c = threadIdx.x;
  float mv = 0.f, dv = 0.f;
  if (c < DIN)        { const float wm = w[(DIN+c)*DOUT+o]; mv = wm; dv = w[c*DOUT+o] - wm; }
  else if (c < DIN+3) { const float wp = w[(2*DIN+(c-DIN))*DOUT+o]; mv = wp; dv = -wp; }
  midT[o*XDIM+c] = (_Float16)mv;
  difT[o*XDIM+c] = (_Float16)dv;
}

// ---------------- head1 weight transpose -> fp16 ----------------
__global__ __launch_bounds__(256) void htrans_kernel(
    const float* __restrict__ h1w, _Float16* __restrict__ h1wT) {
  const int o = blockIdx.x;
  for (int c = threadIdx.x; c < 512; c += 256)
    h1wT[(size_t)o*512 + c] = (_Float16)h1w[(size_t)c*256 + o];
}

// ---------------- knn: 256-thr block = 4 waves x 4 points, threshold pre-pass ----------------
// Occupancy fix: 64-thr blocks hit the per-CU workgroup-slot cap (~59% occ);
// 4 waves/block reaches 32 waves/CU so the ~200-cyc L2 coords load is hidden.
// Selection logic unchanged from r9 (exact; see r9 comments for the bound proof).
#define DPP_SHR1(v) __builtin_amdgcn_update_dpp(0, (v), 0x138, 0xF, 0xF, false)

#define DPP_MIN(v, ctrl)                                                        \
  { const int _t = __builtin_amdgcn_update_dpp(__float_as_int(v),               \
      __float_as_int(v), ctrl, 0xF, 0xF, false);                                \
    v = fminf(v, __int_as_float(_t)); }

// 16th smallest (distinct) of the 64 lane values; upper bound on d16.
__device__ __forceinline__ float sixteenth_of_minima(float v) {
  float th = 0.f;
#pragma unroll
  for (int r = 0; r < 16; ++r) {
    float w = v;
    DPP_MIN(w, 0x111); DPP_MIN(w, 0x112); DPP_MIN(w, 0x114); DPP_MIN(w, 0x118);
    DPP_MIN(w, 0x142); DPP_MIN(w, 0x143);   // row_bcast15 / row_bcast31
    const float mv = __int_as_float(
        __builtin_amdgcn_readlane(__float_as_int(w), 63));
    th = mv;
    v = (v == mv) ? INFINITY : v;
  }
  return th;
}

#define KNN_EVT(d, dk, ik)                                                      \
  {                                                                             \
    const int s = (int)__ffsll((unsigned long long)m) - 1;  m &= m - 1;         \
    const float dc = __int_as_float(__builtin_amdgcn_readlane(                  \
                       __float_as_int(d), s));                                  \
    const bool cnd = dc < dk;                                                   \
    const u64 cm = __ballot(cnd) << 1;                                          \
    const float pd = __int_as_float(DPP_SHR1(__float_as_int(dk)));              \
    const int   pi = DPP_SHR1(ik);                                              \
    const bool pc = (cm >> lane) & 1;                                           \
    dk = cnd ? (pc ? pd : dc) : dk;                                             \
    ik = cnd ? (pc ? pi : (jbase + s)) : ik;                                    \
  }

#define KNN_CHUNK(d, dk, ik, T, Th)                                             \
  { u64 m = __ballot(d <= T);                                                   \
    if (m) {                                                                    \
      do { KNN_EVT(d, dk, ik) } while (m);                                      \
      T = fminf(Th, __int_as_float(__builtin_amdgcn_readlane(                   \
            __float_as_int(dk), 15)));                                          \
    }                                                                           \
  }

__global__ __launch_bounds__(256, 8) void knn_kernel(
    const float* __restrict__ coords4, int* __restrict__ knn_idx) {
  const int tid = threadIdx.x;
  const int wid = tid >> 6;
  const int lane = tid & 63;
  const int p0 = blockIdx.x * 16 + wid * 4;   // block of 16 never straddles batch
  const int b = p0 >> 13;
  const float4* cb = ((const float4*)coords4) + (b << 13);
  const float4 c0 = ((const float4*)coords4)[p0+0];
  const float4 c1 = ((const float4*)coords4)[p0+1];
  const float4 c2 = ((const float4*)coords4)[p0+2];
  const float4 c3 = ((const float4*)coords4)[p0+3];

  // ---- pass A: per-lane minima over the first half (straight-line, no events)
  float lm0 = INFINITY, lm1 = INFINITY, lm2 = INFINITY, lm3 = INFINITY;
  for (int it = 0; it < 64; ++it) {
    const float4 cj = cb[it*64 + lane];
    lm0 = fminf(lm0, fmaxf(c0.w + cj.w - 2.f*(c0.x*cj.x + c0.y*cj.y + c0.z*cj.z), 0.f));
    lm1 = fminf(lm1, fmaxf(c1.w + cj.w - 2.f*(c1.x*cj.x + c1.y*cj.y + c1.z*cj.z), 0.f));
    lm2 = fminf(lm2, fmaxf(c2.w + cj.w - 2.f*(c2.x*cj.x + c2.y*cj.y + c2.z*cj.z), 0.f));
    lm3 = fminf(lm3, fmaxf(c3.w + cj.w - 2.f*(c3.x*cj.x + c3.y*cj.y + c3.z*cj.z), 0.f));
  }
  const float Th0 = sixteenth_of_minima(lm0);
  const float Th1 = sixteenth_of_minima(lm1);
  const float Th2 = sixteenth_of_minima(lm2);
  const float Th3 = sixteenth_of_minima(lm3);

  float dk0 = INFINITY, dk1 = INFINITY, dk2 = INFINITY, dk3 = INFINITY;
  int   ik0 = 0, ik1 = 0, ik2 = 0, ik3 = 0;
  float T0 = Th0, T1 = Th1, T2 = Th2, T3 = Th3;

  // ---- main pass: all candidates, events only below the tight bound
  for (int it = 0; it < N_/64; ++it) {
    const int jbase = it*64;
    const float4 cj = cb[jbase + lane];
    const float d0 = fmaxf(c0.w + cj.w - 2.f*(c0.x*cj.x + c0.y*cj.y + c0.z*cj.z), 0.f);
    const float d1 = fmaxf(c1.w + cj.w - 2.f*(c1.x*cj.x + c1.y*cj.y + c1.z*cj.z), 0.f);
    const float d2 = fmaxf(c2.w + cj.w - 2.f*(c2.x*cj.x + c2.y*cj.y + c2.z*cj.z), 0.f);
    const float d3 = fmaxf(c3.w + cj.w - 2.f*(c3.x*cj.x + c3.y*cj.y + c3.z*cj.z), 0.f);
    KNN_CHUNK(d0, dk0, ik0, T0, Th0);
    KNN_CHUNK(d1, dk1, ik1, T1, Th1);
    KNN_CHUNK(d2, dk2, ik2, T2, Th2);
    KNN_CHUNK(d3, dk3, ik3, T3, Th3);
  }

  if (lane < K_) {
    knn_idx[(size_t)(p0+0)*K_ + lane] = ik0;
    knn_idx[(size_t)(p0+1)*K_ + lane] = ik1;
    knn_idx[(size_t)(p0+2)*K_ + lane] = ik2;
    knn_idx[(size_t)(p0+3)*K_ + lane] = ik3;
  }
}

// ---------------- MFMA local_agg with LDS-staged neighbor rows ----------------
// r10: 2 g-rows per inner iteration -> 4 independent MFMA chains (fills the
// MFMA pipe; latency ~4x issue rate, 2 chains were half-filling it).
#define AGG_EPI(a0v, a1v, gg)                                                   \
  { float m0 = fmaxf(fmaxf(a0v[0],a0v[1]), fmaxf(a0v[2],a0v[3]));               \
    float m1 = fmaxf(fmaxf(a1v[0],a1v[1]), fmaxf(a1v[2],a1v[3]));               \
    m0 = fmaxf(m0, __shfl_xor(m0,16,64)); m0 = fmaxf(m0, __shfl_xor(m0,32,64)); \
    m1 = fmaxf(m1, __shfl_xor(m1,16,64)); m1 = fmaxf(m1, __shfl_xor(m1,32,64)); \
    const int srcl = (((gg) >> 2) << 4) + col;                                  \
    const float c0 = __shfl(cacc[ps][0][(gg) & 3], srcl, 64);                   \
    const float c1 = __shfl(cacc[ps][1][(gg) & 3], srcl, 64);                   \
    if (lane < 16) {                                                            \
      fo[(size_t)(p0+(gg))*ostr + oa] = (_Float16)fmaxf(m0 + c0 + bias0, 0.f);  \
      fo[(size_t)(p0+(gg))*ostr + ob] = (_Float16)fmaxf(m1 + c1 + bias1, 0.f);  \
    } }

template<int KS, int NPASS>
__global__ __launch_bounds__(256) void aggm_kernel(
    const _Float16* __restrict__ fx, const int* __restrict__ knn_idx,
    const _Float16* __restrict__ midT, const _Float16* __restrict__ difT,
    const float* __restrict__ bw,
    _Float16* __restrict__ fo, const int ostr) {
  const int XD  = KS*32;
  const int XDP = XD + 8;
  const int CH  = KS*4;                 // uint4 chunks per row
  const int p0 = blockIdx.x * 16;
  const int bb = (p0 >> 13) << 13;
  const int tid = threadIdx.x;
  const int w = tid >> 6, lane = tid & 63, col = lane & 15, quad = lane >> 4;
  const int koff = quad * 8;

  __shared__ int s_idx[256];
  __shared__ _Float16 sA[128*(KS*32+8)];

  s_idx[tid] = knn_idx[p0*K_ + tid];

  // ---- C part (k-independent): own 16 rows x difT, for all passes ----
  f4v cacc[NPASS][2];
  {
    h8v Ao[KS];
    const _Float16* ap = fx + (size_t)(p0+col)*XD + koff;
#pragma unroll
    for (int kk = 0; kk < KS; ++kk) Ao[kk] = *(const h8v*)(ap + kk*32);
#pragma unroll
    for (int ps = 0; ps < NPASS; ++ps) {
      const int o0 = ps*128 + w*32;
      const _Float16* b0 = difT + (size_t)(o0 + col)*XD + koff;
      const _Float16* b1 = difT + (size_t)(o0 + 16 + col)*XD + koff;
      f4v c0 = {0.f,0.f,0.f,0.f}, c1 = {0.f,0.f,0.f,0.f};
#pragma unroll
      for (int kk = 0; kk < KS; ++kk) {
        c0 = MFMA16(Ao[kk], *(const h8v*)(b0 + kk*32), c0);
        c1 = MFMA16(Ao[kk], *(const h8v*)(b1 + kk*32), c1);
      }
      cacc[ps][0] = c0; cacc[ps][1] = c1;
    }
  }
  __syncthreads();   // s_idx ready

  for (int half = 0; half < 2; ++half) {
    // ---- stage 128 neighbor rows into LDS ----
    for (int c = tid; c < 128*CH; c += 256) {
      const int r = c / CH, o = c - r*CH;
      const _Float16* src = fx + (size_t)(bb + s_idx[half*128 + r])*XD + o*8;
      *(uint4*)&sA[r*XDP + o*8] = *(const uint4*)src;
    }
    __syncthreads();

#pragma unroll
    for (int ps = 0; ps < NPASS; ++ps) {
      const int o0 = ps*128 + w*32;
      const int oa = o0 + col, ob = oa + 16;
      h8v B0[KS], B1[KS];
#pragma unroll
      for (int kk = 0; kk < KS; ++kk) {
        B0[kk] = *(const h8v*)(midT + (size_t)oa*XD + kk*32 + koff);
        B1[kk] = *(const h8v*)(midT + (size_t)ob*XD + kk*32 + koff);
      }
      const float bias0 = bw[oa], bias1 = bw[ob];

      for (int g8 = 0; g8 < 8; g8 += 2) {
        const int g = half*8 + g8;
        const _Float16* apA = &sA[(g8*16 + col)*XDP + koff];
        const _Float16* apB = &sA[((g8+1)*16 + col)*XDP + koff];
        f4v a00 = {0.f,0.f,0.f,0.f}, a01 = {0.f,0.f,0.f,0.f};
        f4v a10 = {0.f,0.f,0.f,0.f}, a11 = {0.f,0.f,0.f,0.f};
#pragma unroll
        for (int kk = 0; kk < KS; ++kk) {
          const h8v avA = *(const h8v*)(apA + kk*32);
          const h8v avB = *(const h8v*)(apB + kk*32);
          a00 = MFMA16(avA, B0[kk], a00);
          a10 = MFMA16(avB, B0[kk], a10);
          a01 = MFMA16(avA, B1[kk], a01);
          a11 = MFMA16(avB, B1[kk], a11);
        }
        AGG_EPI(a00, a01, g);
        AGG_EPI(a10, a11, g+1);
      }
    }
    if (half == 0) __syncthreads();   // drain reads before restaging
  }
}

// ---------------- global max (stage 1): coalesced uint4 loads ----------------
__global__ __launch_bounds__(256) void gmax_kernel(
    const _Float16* __restrict__ f2h, float* __restrict__ part) {
  const int b = blockIdx.x >> 5;
  const int seg = blockIdx.x & 31;
  const int tid = threadIdx.x;
  const int rg = tid >> 5;            // 0..7
  const int cc = (tid & 31) * 8;      // col chunk base
  __shared__ float smax[8][256];
  const size_t rbase = (size_t)(b << 13) + seg*256;
  _Float16 mh[8];
#pragma unroll
  for (int j = 0; j < 8; ++j) mh[j] = (_Float16)0.f;   // relu outputs >= 0
  for (int n = rg; n < 256; n += 8) {
    const h8v v = *(const h8v*)&f2h[(rbase + n)*W2_ + cc];
#pragma unroll
    for (int j = 0; j < 8; ++j) mh[j] = (v[j] > mh[j]) ? v[j] : mh[j];
  }
#pragma unroll
  for (int j = 0; j < 8; ++j) smax[rg][cc + j] = (float)mh[j];
  __syncthreads();
  float m = smax[0][tid];
#pragma unroll
  for (int g = 1; g < 8; ++g) m = fmaxf(m, smax[g][tid]);
  part[(size_t)blockIdx.x*W2_ + tid] = m;
}

// ---------------- global max reduce + glob FC -> g2h fp16 ----------------
__global__ __launch_bounds__(256) void gfc_kernel(
    const float* __restrict__ part, const float* __restrict__ gw,
    const float* __restrict__ gb, _Float16* __restrict__ g2h) {
  const int b = blockIdx.x;
  const int o = threadIdx.x;
  __shared__ float s_g[W2_];
  float m = -INFINITY;
  for (int s = 0; s < 32; ++s) m = fmaxf(m, part[(size_t)(b*32+s)*W2_ + o]);
  s_g[o] = m;
  __syncthreads();
  float acc = gb[o];
  for (int d = 0; d < W2_; ++d) acc += s_g[d]*gw[d*W2_ + o];
  g2h[b*W2_ + o] = (_Float16)fmaxf(acc, 0.f);
}

// ---------------- head: 32 points/block MFMA GEMM + tiny second layer ----------------
__global__ __launch_bounds__(256) void headm_kernel(
    const _Float16* __restrict__ f2h, const _Float16* __restrict__ g2h,
    const _Float16* __restrict__ h1wT, const float* __restrict__ h1b,
    const float* __restrict__ h2w, const float* __restrict__ h2b,
    const float* __restrict__ x,
    const float* __restrict__ thresh, const float* __restrict__ sharp,
    const float* __restrict__ scale,
    float* __restrict__ out) {
  const int p0 = blockIdx.x * 32;
  const int b = p0 >> 13;
  const int tid = threadIdx.x;
  const int w = tid >> 6, lane = tid & 63, col = lane & 15, quad = lane >> 4;

  __shared__ _Float16 sA[32*520];   // 32 points x 512 (padded to 520)
  __shared__ float    sh[32*260];   // relu(h1) f32

  for (int t = tid; t < 32*32; t += 256) {       // f2h part (16B chunks)
    const int r = t >> 5, cc = (t & 31) * 8;
    *(uint4*)&sA[r*520 + cc] = *(const uint4*)&f2h[(size_t)(p0+r)*W2_ + cc];
  }
  for (int t = tid; t < 32*32; t += 256) {       // g2h broadcast part
    const int r = t >> 5, cc = (t & 31) * 8;
    *(uint4*)&sA[r*520 + 256 + cc] = *(const uint4*)&g2h[b*W2_ + cc];
  }
  __syncthreads();

  f4v acc[2][4];
#pragma unroll
  for (int r = 0; r < 2; ++r)
#pragma unroll
    for (int t = 0; t < 4; ++t) acc[r][t] = (f4v){0.f,0.f,0.f,0.f};

  for (int kk = 0; kk < 16; ++kk) {
    const h8v a0 = *(const h8v*)&sA[col*520 + kk*32 + quad*8];
    const h8v a1 = *(const h8v*)&sA[(16+col)*520 + kk*32 + quad*8];
#pragma unroll
    for (int t = 0; t < 4; ++t) {
      const h8v bt = *(const h8v*)&h1wT[(size_t)(w*64 + t*16 + col)*512 + kk*32 + quad*8];
      acc[0][t] = MFMA16(a0, bt, acc[0][t]);
      acc[1][t] = MFMA16(a1, bt, acc[1][t]);
    }
  }
#pragma unroll
  for (int r = 0; r < 2; ++r)
#pragma unroll
    for (int t = 0; t < 4; ++t) {
      const int o = w*64 + t*16 + col;
      const float bv = h1b[o];
#pragma unroll
      for (int reg = 0; reg < 4; ++reg)
        sh[(r*16 + quad*4 + reg)*260 + o] = fmaxf(acc[r][t][reg] + bv, 0.f);
    }
  __syncthreads();

  if (tid < 96) {
    const int pp = tid / 3, c = tid % 3;
    float s = h2b[c];
    for (int d = 0; d < 256; ++d) s += sh[pp*260 + d] * h2w[d*3 + c];
    if (c == 0) {
      const float hag = x[(size_t)(p0+pp)*4 + 3];
      s += scale[0] / (1.f + expf(-sharp[0]*(thresh[0] - hag)));
    }
    out[(size_t)(p0+pp)*3 + c] = s;
  }
}

// ---------------- launch ----------------
extern "C" void kernel_launch(void* const* d_in, const int* in_sizes, int n_in,
                              void* d_out, int out_size, void* d_ws, size_t ws_size,
                              hipStream_t stream) {
  const float* x       = (const float*)d_in[0];
  const float* hmix_a  = (const float*)d_in[1];
  const float* hmix_b  = (const float*)d_in[2];
  const float* hmix_c  = (const float*)d_in[3];
  const float* stem_w  = (const float*)d_in[4];
  const float* stem_b  = (const float*)d_in[5];
  const float* b1_w    = (const float*)d_in[6];
  const float* b1_b    = (const float*)d_in[7];
  const float* b2_w    = (const float*)d_in[8];
  const float* b2_b    = (const float*)d_in[9];
  const float* glob_w  = (const float*)d_in[10];
  const float* glob_b  = (const float*)d_in[11];
  const float* head1_w = (const float*)d_in[12];
  const float* head1_b = (const float*)d_in[13];
  const float* head2_w = (const float*)d_in[14];
  const float* head2_b = (const float*)d_in[15];
  const float* thresh  = (const float*)d_in[16];
  const float* sharp   = (const float*)d_in[17];
  const float* scale   = (const float*)d_in[18];
  float* out = (float*)d_out;

  char* base = (char*)d_ws;
  float*     coords4 = (float*)    (base + 0);          // 512 KB
  int*       idxb    = (int*)      (base + 524288);     // 2 MB
  _Float16*  fx0     = (_Float16*) (base + 2621440);    // 6 MB   (32768*96*2)
  _Float16*  fx1     = (_Float16*) (base + 8912896);    // 10 MB  (32768*160*2)
  _Float16*  f2h     = (_Float16*) (base + 19398656);   // 16 MB  (32768*256*2)
  _Float16*  w1m     = (_Float16*) (base + 36175872);   // 24 KB  (128*96*2)
  _Float16*  w1d     = (_Float16*) (base + 36200448);   // 24 KB
  _Float16*  w2m     = (_Float16*) (base + 36225024);   // 80 KB  (256*160*2)
  _Float16*  w2d     = (_Float16*) (base + 36306944);   // 80 KB
  _Float16*  h1wT    = (_Float16*) (base + 36388864);   // 256 KB (256*512*2)
  float*     part    = (float*)    (base + 36651008);   // 128 KB
  _Float16*  g2h     = (_Float16*) (base + 36782080);   // 2 KB

  const int NP = B_ * N_;   // 32768 points

  wconv_kernel<W0_, W1_, X0_><<<W1_, X0_, 0, stream>>>(b1_w, w1m, w1d);
  wconv_kernel<W1_, W2_, X1_><<<W2_, X1_, 0, stream>>>(b2_w, w2m, w2d);
  htrans_kernel<<<W2_, 256, 0, stream>>>(head1_w, h1wT);
  prep_kernel<<<NP, 64, 0, stream>>>(x, stem_w, stem_b, hmix_a, hmix_b, hmix_c,
                                     coords4, fx0, fx1);
  knn_kernel<<<NP/16, 256, 0, stream>>>(coords4, idxb);
  aggm_kernel<3, 1><<<NP/16, 256, 0, stream>>>(fx0, idxb, w1m, w1d, b1_b, fx1, X1_);
  aggm_kernel<5, 2><<<NP/16, 256, 0, stream>>>(fx1, idxb, w2m, w2d, b2_b, f2h, W2_);
  gmax_kernel<<<B_*32, 256, 0, stream>>>(f2h, part);
  gfc_kernel<<<B_, 256, 0, stream>>>(part, glob_w, glob_b, g2h);
  headm_kernel<<<NP/32, 256, 0, stream>>>(f2h, g2h, h1wT, head1_b, head2_w, head2_b,
                                          x, thresh, sharp, scale, out);
}

// Round 11
// 475.274 us; speedup vs baseline: 4.9126x; 1.0200x over previous
//
#include <hip/hip_runtime.h>
#include <math.h>

typedef unsigned long long u64;
typedef unsigned int u32;
typedef _Float16 h8v __attribute__((ext_vector_type(8)));  // 8 fp16 (4 VGPRs)
typedef float    f4v __attribute__((ext_vector_type(4)));  // MFMA acc
typedef float    f2v __attribute__((ext_vector_type(2)));  // v_pk_*_f32 pair

#define MFMA16(a,b,c) __builtin_amdgcn_mfma_f32_16x16x32_f16(a, b, c, 0, 0, 0)

#define B_ 4
#define N_ 8192
#define K_ 16
#define W0_ 64
#define W1_ 128
#define W2_ 256
#define X0_ 96   // padded K-dim layer-1 inputs (64 feat + 3 coord + 29 zero)
#define X1_ 160  // padded K-dim layer-2 inputs (128 feat + 3 coord + 29 zero)

// ---------------- prep: 4 points/block (256 thr) -> coords4, fx0, fx1 tail ----------------
__global__ __launch_bounds__(256) void prep_kernel(
    const float* __restrict__ x,
    const float* __restrict__ stem_w, const float* __restrict__ stem_b,
    const float* __restrict__ hmix_a, const float* __restrict__ hmix_b,
    const float* __restrict__ hmix_c,
    float* __restrict__ coords4, _Float16* __restrict__ fx0,
    _Float16* __restrict__ fx1) {
  const int p = blockIdx.x * 4 + (threadIdx.x >> 6);
  const int o = threadIdx.x & 63;
  const float x0 = x[p*4+0], x1 = x[p*4+1], x2 = x[p*4+2], x3 = x[p*4+3];
  const float z = hmix_a[0]*x2 + hmix_b[0]*x3 + hmix_c[0];
  float acc = stem_b[o] + x0*stem_w[0*W0_+o] + x1*stem_w[1*W0_+o]
            + x2*stem_w[2*W0_+o] + x3*stem_w[3*W0_+o];
  fx0[p*X0_+o] = (_Float16)fmaxf(acc, 0.f);
  if (o < 32) {   // tail: 3 coords + 29 zeros (both layers' inputs)
    const float tv = (o==0) ? x0 : (o==1) ? x1 : (o==2) ? z : 0.f;
    fx0[p*X0_+W0_+o] = (_Float16)tv;
    fx1[(size_t)p*X1_+W1_+o] = (_Float16)tv;
  }
  if (o == 0) {
    const float xx = x0*x0 + x1*x1 + z*z;
    ((float4*)coords4)[p] = make_float4(x0, x1, z, xx);
  }
}

// ---------------- weight conversion: transposed, extended, fp16 ----------------
template<int DIN, int DOUT, int XDIM>
__global__ void wconv_kernel(const float* __restrict__ w,
    _Float16* __restrict__ midT, _Float16* __restrict__ difT) {
  const int o = blockIdx.x;
  const int c = threadIdx.x;
  float mv = 0.f, dv = 0.f;
  if (c < DIN)        { const float wm = w[(DIN+c)*DOUT+o]; mv = wm; dv = w[c*DOUT+o] - wm; }
  else if (c < DIN+3) { const float wp = w[(2*DIN+(c-DIN))*DOUT+o]; mv = wp; dv = -wp; }
  midT[o*XDIM+c] = (_Float16)mv;
  difT[o*XDIM+c] = (_Float16)dv;
}

// ---------------- head1 weight transpose -> fp16 ----------------
__global__ __launch_bounds__(256) void htrans_kernel(
    const float* __restrict__ h1w, _Float16* __restrict__ h1wT) {
  const int o = blockIdx.x;
  for (int c = threadIdx.x; c < 512; c += 256)
    h1wT[(size_t)o*512 + c] = (_Float16)h1w[(size_t)c*256 + o];
}

// ---------------- knn: 4 waves x 4 points, packed-f32 distance math ----------------
// Distances for point-pairs via v_pk_fma_f32 (2 f32/inst); clamp/compare and the
// selection machinery stay scalar -> selection semantics identical to r9/r10
// (exact; see r9 comments for the threshold-bound proof).
#define DPP_SHR1(v) __builtin_amdgcn_update_dpp(0, (v), 0x138, 0xF, 0xF, false)

#define DPP_MIN(v, ctrl)                                                        \
  { const int _t = __builtin_amdgcn_update_dpp(__float_as_int(v),               \
      __float_as_int(v), ctrl, 0xF, 0xF, false);                                \
    v = fminf(v, __int_as_float(_t)); }

// 16th smallest (distinct) of the 64 lane values; upper bound on d16.
__device__ __forceinline__ float sixteenth_of_minima(float v) {
  float th = 0.f;
#pragma unroll
  for (int r = 0; r < 16; ++r) {
    float w = v;
    DPP_MIN(w, 0x111); DPP_MIN(w, 0x112); DPP_MIN(w, 0x114); DPP_MIN(w, 0x118);
    DPP_MIN(w, 0x142); DPP_MIN(w, 0x143);   // row_bcast15 / row_bcast31
    const float mv = __int_as_float(
        __builtin_amdgcn_readlane(__float_as_int(w), 63));
    th = mv;
    v = (v == mv) ? INFINITY : v;
  }
  return th;
}

#define KNN_EVT(d, dk, ik)                                                      \
  {                                                                             \
    const int s = (int)__ffsll((unsigned long long)m) - 1;  m &= m - 1;         \
    const float dc = __int_as_float(__builtin_amdgcn_readlane(                  \
                       __float_as_int(d), s));                                  \
    const bool cnd = dc < dk;                                                   \
    const u64 cm = __ballot(cnd) << 1;                                          \
    const float pd = __int_as_float(DPP_SHR1(__float_as_int(dk)));              \
    const int   pi = DPP_SHR1(ik);                                              \
    const bool pc = (cm >> lane) & 1;                                           \
    dk = cnd ? (pc ? pd : dc) : dk;                                             \
    ik = cnd ? (pc ? pi : (jbase + s)) : ik;                                    \
  }

#define KNN_CHUNK(d, dk, ik, T, Th)                                             \
  { u64 m = __ballot(d <= T);                                                   \
    if (m) {                                                                    \
      do { KNN_EVT(d, dk, ik) } while (m);                                      \
      T = fminf(Th, __int_as_float(__builtin_amdgcn_readlane(                   \
            __float_as_int(dk), 15)));                                          \
    }                                                                           \
  }

// packed distance for a point-pair: d = (cw + cjw) - 2*dot
#define KNN_DIST2(dA, dB)                                                       \
  const f2v cjx = {cj.x, cj.x}, cjy = {cj.y, cj.y},                             \
            cjz = {cj.z, cj.z}, cjw = {cj.w, cj.w};                             \
  f2v tA = cAx * cjx;                                                           \
  tA = __builtin_elementwise_fma(cAy, cjy, tA);                                 \
  tA = __builtin_elementwise_fma(cAz, cjz, tA);                                 \
  const f2v dA = __builtin_elementwise_fma(tA, m2, cAw + cjw);                  \
  f2v tB = cBx * cjx;                                                           \
  tB = __builtin_elementwise_fma(cBy, cjy, tB);                                 \
  tB = __builtin_elementwise_fma(cBz, cjz, tB);                                 \
  const f2v dB = __builtin_elementwise_fma(tB, m2, cBw + cjw);

__global__ __launch_bounds__(256, 8) void knn_kernel(
    const float* __restrict__ coords4, int* __restrict__ knn_idx) {
  const int tid = threadIdx.x;
  const int wid = tid >> 6;
  const int lane = tid & 63;
  const int p0 = blockIdx.x * 16 + wid * 4;   // block of 16 never straddles batch
  const int b = p0 >> 13;
  const float4* cb = ((const float4*)coords4) + (b << 13);
  const float4 c0 = ((const float4*)coords4)[p0+0];
  const float4 c1 = ((const float4*)coords4)[p0+1];
  const float4 c2 = ((const float4*)coords4)[p0+2];
  const float4 c3 = ((const float4*)coords4)[p0+3];
  const f2v m2 = {-2.f, -2.f};
  const f2v cAx = {c0.x, c1.x}, cAy = {c0.y, c1.y}, cAz = {c0.z, c1.z}, cAw = {c0.w, c1.w};
  const f2v cBx = {c2.x, c3.x}, cBy = {c2.y, c3.y}, cBz = {c2.z, c3.z}, cBw = {c2.w, c3.w};

  // ---- pass A: per-lane minima over the first half (straight-line, no events)
  float lm0 = INFINITY, lm1 = INFINITY, lm2 = INFINITY, lm3 = INFINITY;
  for (int it = 0; it < 64; ++it) {
    const float4 cj = cb[it*64 + lane];
    KNN_DIST2(dA, dB)
    lm0 = fminf(lm0, fmaxf(dA[0], 0.f));
    lm1 = fminf(lm1, fmaxf(dA[1], 0.f));
    lm2 = fminf(lm2, fmaxf(dB[0], 0.f));
    lm3 = fminf(lm3, fmaxf(dB[1], 0.f));
  }
  const float Th0 = sixteenth_of_minima(lm0);
  const float Th1 = sixteenth_of_minima(lm1);
  const float Th2 = sixteenth_of_minima(lm2);
  const float Th3 = sixteenth_of_minima(lm3);

  float dk0 = INFINITY, dk1 = INFINITY, dk2 = INFINITY, dk3 = INFINITY;
  int   ik0 = 0, ik1 = 0, ik2 = 0, ik3 = 0;
  float T0 = Th0, T1 = Th1, T2 = Th2, T3 = Th3;

  // ---- main pass: all candidates, events only below the tight bound
  for (int it = 0; it < N_/64; ++it) {
    const int jbase = it*64;
    const float4 cj = cb[jbase + lane];
    KNN_DIST2(dA, dB)
    const float d0 = fmaxf(dA[0], 0.f);
    const float d1 = fmaxf(dA[1], 0.f);
    const float d2 = fmaxf(dB[0], 0.f);
    const float d3 = fmaxf(dB[1], 0.f);
    KNN_CHUNK(d0, dk0, ik0, T0, Th0);
    KNN_CHUNK(d1, dk1, ik1, T1, Th1);
    KNN_CHUNK(d2, dk2, ik2, T2, Th2);
    KNN_CHUNK(d3, dk3, ik3, T3, Th3);
  }

  if (lane < K_) {
    knn_idx[(size_t)(p0+0)*K_ + lane] = ik0;
    knn_idx[(size_t)(p0+1)*K_ + lane] = ik1;
    knn_idx[(size_t)(p0+2)*K_ + lane] = ik2;
    knn_idx[(size_t)(p0+3)*K_ + lane] = ik3;
  }
}

// ---------------- MFMA local_agg with LDS-staged neighbor rows ----------------
// 2 g-rows per inner iteration -> 4 independent MFMA chains.
#define AGG_EPI(a0v, a1v, gg)                                                   \
  { float m0 = fmaxf(fmaxf(a0v[0],a0v[1]), fmaxf(a0v[2],a0v[3]));               \
    float m1 = fmaxf(fmaxf(a1v[0],a1v[1]), fmaxf(a1v[2],a1v[3]));               \
    m0 = fmaxf(m0, __shfl_xor(m0,16,64)); m0 = fmaxf(m0, __shfl_xor(m0,32,64)); \
    m1 = fmaxf(m1, __shfl_xor(m1,16,64)); m1 = fmaxf(m1, __shfl_xor(m1,32,64)); \
    const int srcl = (((gg) >> 2) << 4) + col;                                  \
    const float c0 = __shfl(cacc[ps][0][(gg) & 3], srcl, 64);                   \
    const float c1 = __shfl(cacc[ps][1][(gg) & 3], srcl, 64);                   \
    if (lane < 16) {                                                            \
      fo[(size_t)(p0+(gg))*ostr + oa] = (_Float16)fmaxf(m0 + c0 + bias0, 0.f);  \
      fo[(size_t)(p0+(gg))*ostr + ob] = (_Float16)fmaxf(m1 + c1 + bias1, 0.f);  \
    } }

template<int KS, int NPASS>
__global__ __launch_bounds__(256) void aggm_kernel(
    const _Float16* __restrict__ fx, const int* __restrict__ knn_idx,
    const _Float16* __restrict__ midT, const _Float16* __restrict__ difT,
    const float* __restrict__ bw,
    _Float16* __restrict__ fo, const int ostr) {
  const int XD  = KS*32;
  const int XDP = XD + 8;
  const int CH  = KS*4;                 // uint4 chunks per row
  const int p0 = blockIdx.x * 16;
  const int bb = (p0 >> 13) << 13;
  const int tid = threadIdx.x;
  const int w = tid >> 6, lane = tid & 63, col = lane & 15, quad = lane >> 4;
  const int koff = quad * 8;

  __shared__ int s_idx[256];
  __shared__ _Float16 sA[128*(KS*32+8)];

  s_idx[tid] = knn_idx[p0*K_ + tid];

  // ---- C part (k-independent): own 16 rows x difT, for all passes ----
  f4v cacc[NPASS][2];
  {
    h8v Ao[KS];
    const _Float16* ap = fx + (size_t)(p0+col)*XD + koff;
#pragma unroll
    for (int kk = 0; kk < KS; ++kk) Ao[kk] = *(const h8v*)(ap + kk*32);
#pragma unroll
    for (int ps = 0; ps < NPASS; ++ps) {
      const int o0 = ps*128 + w*32;
      const _Float16* b0 = difT + (size_t)(o0 + col)*XD + koff;
      const _Float16* b1 = difT + (size_t)(o0 + 16 + col)*XD + koff;
      f4v c0 = {0.f,0.f,0.f,0.f}, c1 = {0.f,0.f,0.f,0.f};
#pragma unroll
      for (int kk = 0; kk < KS; ++kk) {
        c0 = MFMA16(Ao[kk], *(const h8v*)(b0 + kk*32), c0);
        c1 = MFMA16(Ao[kk], *(const h8v*)(b1 + kk*32), c1);
      }
      cacc[ps][0] = c0; cacc[ps][1] = c1;
    }
  }
  __syncthreads();   // s_idx ready

  for (int half = 0; half < 2; ++half) {
    // ---- stage 128 neighbor rows into LDS ----
    for (int c = tid; c < 128*CH; c += 256) {
      const int r = c / CH, o = c - r*CH;
      const _Float16* src = fx + (size_t)(bb + s_idx[half*128 + r])*XD + o*8;
      *(uint4*)&sA[r*XDP + o*8] = *(const uint4*)src;
    }
    __syncthreads();

#pragma unroll
    for (int ps = 0; ps < NPASS; ++ps) {
      const int o0 = ps*128 + w*32;
      const int oa = o0 + col, ob = oa + 16;
      h8v B0[KS], B1[KS];
#pragma unroll
      for (int kk = 0; kk < KS; ++kk) {
        B0[kk] = *(const h8v*)(midT + (size_t)oa*XD + kk*32 + koff);
        B1[kk] = *(const h8v*)(midT + (size_t)ob*XD + kk*32 + koff);
      }
      const float bias0 = bw[oa], bias1 = bw[ob];

      for (int g8 = 0; g8 < 8; g8 += 2) {
        const int g = half*8 + g8;
        const _Float16* apA = &sA[(g8*16 + col)*XDP + koff];
        const _Float16* apB = &sA[((g8+1)*16 + col)*XDP + koff];
        f4v a00 = {0.f,0.f,0.f,0.f}, a01 = {0.f,0.f,0.f,0.f};
        f4v a10 = {0.f,0.f,0.f,0.f}, a11 = {0.f,0.f,0.f,0.f};
#pragma unroll
        for (int kk = 0; kk < KS; ++kk) {
          const h8v avA = *(const h8v*)(apA + kk*32);
          const h8v avB = *(const h8v*)(apB + kk*32);
          a00 = MFMA16(avA, B0[kk], a00);
          a10 = MFMA16(avB, B0[kk], a10);
          a01 = MFMA16(avA, B1[kk], a01);
          a11 = MFMA16(avB, B1[kk], a11);
        }
        AGG_EPI(a00, a01, g);
        AGG_EPI(a10, a11, g+1);
      }
    }
    if (half == 0) __syncthreads();   // drain reads before restaging
  }
}

// ---------------- global max (stage 1): coalesced uint4 loads ----------------
__global__ __launch_bounds__(256) void gmax_kernel(
    const _Float16* __restrict__ f2h, float* __restrict__ part) {
  const int b = blockIdx.x >> 5;
  const int seg = blockIdx.x & 31;
  const int tid = threadIdx.x;
  const int rg = tid >> 5;            // 0..7
  const int cc = (tid & 31) * 8;      // col chunk base
  __shared__ float smax[8][256];
  const size_t rbase = (size_t)(b << 13) + seg*256;
  _Float16 mh[8];
#pragma unroll
  for (int j = 0; j < 8; ++j) mh[j] = (_Float16)0.f;   // relu outputs >= 0
  for (int n = rg; n < 256; n += 8) {
    const h8v v = *(const h8v*)&f2h[(rbase + n)*W2_ + cc];
#pragma unroll
    for (int j = 0; j < 8; ++j) mh[j] = (v[j] > mh[j]) ? v[j] : mh[j];
  }
#pragma unroll
  for (int j = 0; j < 8; ++j) smax[rg][cc + j] = (float)mh[j];
  __syncthreads();
  float m = smax[0][tid];
#pragma unroll
  for (int g = 1; g < 8; ++g) m = fmaxf(m, smax[g][tid]);
  part[(size_t)blockIdx.x*W2_ + tid] = m;
}

// ---------------- global max reduce + glob FC -> g2h fp16 ----------------
__global__ __launch_bounds__(256) void gfc_kernel(
    const float* __restrict__ part, const float* __restrict__ gw,
    const float* __restrict__ gb, _Float16* __restrict__ g2h) {
  const int b = blockIdx.x;
  const int o = threadIdx.x;
  __shared__ float s_g[W2_];
  float m = -INFINITY;
  for (int s = 0; s < 32; ++s) m = fmaxf(m, part[(size_t)(b*32+s)*W2_ + o]);
  s_g[o] = m;
  __syncthreads();
  float acc = gb[o];
  for (int d = 0; d < W2_; ++d) acc += s_g[d]*gw[d*W2_ + o];
  g2h[b*W2_ + o] = (_Float16)fmaxf(acc, 0.f);
}

// ---------------- head: 32 points/block MFMA GEMM + tiny second layer ----------------
__global__ __launch_bounds__(256) void headm_kernel(
    const _Float16* __restrict__ f2h, const _Float16* __restrict__ g2h,
    const _Float16* __restrict__ h1wT, const float* __restrict__ h1b,
    const float* __restrict__ h2w, const float* __restrict__ h2b,
    const float* __restrict__ x,
    const float* __restrict__ thresh, const float* __restrict__ sharp,
    const float* __restrict__ scale,
    float* __restrict__ out) {
  const int p0 = blockIdx.x * 32;
  const int b = p0 >> 13;
  const int tid = threadIdx.x;
  const int w = tid >> 6, lane = tid & 63, col = lane & 15, quad = lane >> 4;

  __shared__ _Float16 sA[32*520];   // 32 points x 512 (padded to 520)
  __shared__ float    sh[32*260];   // relu(h1) f32

  for (int t = tid; t < 32*32; t += 256) {       // f2h part (16B chunks)
    const int r = t >> 5, cc = (t & 31) * 8;
    *(uint4*)&sA[r*520 + cc] = *(const uint4*)&f2h[(size_t)(p0+r)*W2_ + cc];
  }
  for (int t = tid; t < 32*32; t += 256) {       // g2h broadcast part
    const int r = t >> 5, cc = (t & 31) * 8;
    *(uint4*)&sA[r*520 + 256 + cc] = *(const uint4*)&g2h[b*W2_ + cc];
  }
  __syncthreads();

  f4v acc[2][4];
#pragma unroll
  for (int r = 0; r < 2; ++r)
#pragma unroll
    for (int t = 0; t < 4; ++t) acc[r][t] = (f4v){0.f,0.f,0.f,0.f};

  for (int kk = 0; kk < 16; ++kk) {
    const h8v a0 = *(const h8v*)&sA[col*520 + kk*32 + quad*8];
    const h8v a1 = *(const h8v*)&sA[(16+col)*520 + kk*32 + quad*8];
#pragma unroll
    for (int t = 0; t < 4; ++t) {
      const h8v bt = *(const h8v*)&h1wT[(size_t)(w*64 + t*16 + col)*512 + kk*32 + quad*8];
      acc[0][t] = MFMA16(a0, bt, acc[0][t]);
      acc[1][t] = MFMA16(a1, bt, acc[1][t]);
    }
  }
#pragma unroll
  for (int r = 0; r < 2; ++r)
#pragma unroll
    for (int t = 0; t < 4; ++t) {
      const int o = w*64 + t*16 + col;
      const float bv = h1b[o];
#pragma unroll
      for (int reg = 0; reg < 4; ++reg)
        sh[(r*16 + quad*4 + reg)*260 + o] = fmaxf(acc[r][t][reg] + bv, 0.f);
    }
  __syncthreads();

  if (tid < 96) {
    const int pp = tid / 3, c = tid % 3;
    float s = h2b[c];
    for (int d = 0; d < 256; ++d) s += sh[pp*260 + d] * h2w[d*3 + c];
    if (c == 0) {
      const float hag = x[(size_t)(p0+pp)*4 + 3];
      s += scale[0] / (1.f + expf(-sharp[0]*(thresh[0] - hag)));
    }
    out[(size_t)(p0+pp)*3 + c] = s;
  }
}

// ---------------- launch ----------------
extern "C" void kernel_launch(void* const* d_in, const int* in_sizes, int n_in,
                              void* d_out, int out_size, void* d_ws, size_t ws_size,
                              hipStream_t stream) {
  const float* x       = (const float*)d_in[0];
  const float* hmix_a  = (const float*)d_in[1];
  const float* hmix_b  = (const float*)d_in[2];
  const float* hmix_c  = (const float*)d_in[3];
  const float* stem_w  = (const float*)d_in[4];
  const float* stem_b  = (const float*)d_in[5];
  const float* b1_w    = (const float*)d_in[6];
  const float* b1_b    = (const float*)d_in[7];
  const float* b2_w    = (const float*)d_in[8];
  const float* b2_b    = (const float*)d_in[9];
  const float* glob_w  = (const float*)d_in[10];
  const float* glob_b  = (const float*)d_in[11];
  const float* head1_w = (const float*)d_in[12];
  const float* head1_b = (const float*)d_in[13];
  const float* head2_w = (const float*)d_in[14];
  const float* head2_b = (const float*)d_in[15];
  const float* thresh  = (const float*)d_in[16];
  const float* sharp   = (const float*)d_in[17];
  const float* scale   = (const float*)d_in[18];
  float* out = (float*)d_out;

  char* base = (char*)d_ws;
  float*     coords4 = (float*)    (base + 0);          // 512 KB
  int*       idxb    = (int*)      (base + 524288);     // 2 MB
  _Float16*  fx0     = (_Float16*) (base + 2621440);    // 6 MB   (32768*96*2)
  _Float16*  fx1     = (_Float16*) (base + 8912896);    // 10 MB  (32768*160*2)
  _Float16*  f2h     = (_Float16*) (base + 19398656);   // 16 MB  (32768*256*2)
  _Float16*  w1m     = (_Float16*) (base + 36175872);   // 24 KB  (128*96*2)
  _Float16*  w1d     = (_Float16*) (base + 36200448);   // 24 KB
  _Float16*  w2m     = (_Float16*) (base + 36225024);   // 80 KB  (256*160*2)
  _Float16*  w2d     = (_Float16*) (base + 36306944);   // 80 KB
  _Float16*  h1wT    = (_Float16*) (base + 36388864);   // 256 KB (256*512*2)
  float*     part    = (float*)    (base + 36651008);   // 128 KB
  _Float16*  g2h     = (_Float16*) (base + 36782080);   // 2 KB

  const int NP = B_ * N_;   // 32768 points

  wconv_kernel<W0_, W1_, X0_><<<W1_, X0_, 0, stream>>>(b1_w, w1m, w1d);
  wconv_kernel<W1_, W2_, X1_><<<W2_, X1_, 0, stream>>>(b2_w, w2m, w2d);
  htrans_kernel<<<W2_, 256, 0, stream>>>(head1_w, h1wT);
  prep_kernel<<<NP/4, 256, 0, stream>>>(x, stem_w, stem_b, hmix_a, hmix_b, hmix_c,
                                        coords4, fx0, fx1);
  knn_kernel<<<NP/16, 256, 0, stream>>>(coords4, idxb);
  aggm_kernel<3, 1><<<NP/16, 256, 0, stream>>>(fx0, idxb, w1m, w1d, b1_b, fx1, X1_);
  aggm_kernel<5, 2><<<NP/16, 256, 0, stream>>>(fx1, idxb, w2m, w2d, b2_b, f2h, W2_);
  gmax_kernel<<<B_*32, 256, 0, stream>>>(f2h, part);
  gfc_kernel<<<B_, 256, 0, stream>>>(part, glob_w, glob_b, g2h);
  headm_kernel<<<NP/32, 256, 0, stream>>>(f2h, g2h, h1wT, head1_b, head2_w, head2_b,
                                          x, thresh, sharp, scale, out);
}

// Round 12
// 474.494 us; speedup vs baseline: 4.9207x; 1.0016x over previous
//
#include <hip/hip_runtime.h>
#include <math.h>

typedef unsigned long long u64;
typedef unsigned int u32;
typedef _Float16 h8v __attribute__((ext_vector_type(8)));  // 8 fp16 (4 VGPRs)
typedef float    f4v __attribute__((ext_vector_type(4)));  // MFMA acc
typedef float    f2v __attribute__((ext_vector_type(2)));  // v_pk_*_f32 pair

#define MFMA16(a,b,c) __builtin_amdgcn_mfma_f32_16x16x32_f16(a, b, c, 0, 0, 0)

#define B_ 4
#define N_ 8192
#define K_ 16
#define W0_ 64
#define W1_ 128
#define W2_ 256
#define X0_ 96   // padded K-dim layer-1 inputs (64 feat + 3 coord + 29 zero)
#define X1_ 160  // padded K-dim layer-2 inputs (128 feat + 3 coord + 29 zero)

// ---------------- prep: 4 points/block (256 thr) -> coords4, fx0, fx1 tail ----------------
__global__ __launch_bounds__(256) void prep_kernel(
    const float* __restrict__ x,
    const float* __restrict__ stem_w, const float* __restrict__ stem_b,
    const float* __restrict__ hmix_a, const float* __restrict__ hmix_b,
    const float* __restrict__ hmix_c,
    float* __restrict__ coords4, _Float16* __restrict__ fx0,
    _Float16* __restrict__ fx1) {
  const int p = blockIdx.x * 4 + (threadIdx.x >> 6);
  const int o = threadIdx.x & 63;
  const float x0 = x[p*4+0], x1 = x[p*4+1], x2 = x[p*4+2], x3 = x[p*4+3];
  const float z = hmix_a[0]*x2 + hmix_b[0]*x3 + hmix_c[0];
  float acc = stem_b[o] + x0*stem_w[0*W0_+o] + x1*stem_w[1*W0_+o]
            + x2*stem_w[2*W0_+o] + x3*stem_w[3*W0_+o];
  fx0[p*X0_+o] = (_Float16)fmaxf(acc, 0.f);
  if (o < 32) {   // tail: 3 coords + 29 zeros (both layers' inputs)
    const float tv = (o==0) ? x0 : (o==1) ? x1 : (o==2) ? z : 0.f;
    fx0[p*X0_+W0_+o] = (_Float16)tv;
    fx1[(size_t)p*X1_+W1_+o] = (_Float16)tv;
  }
  if (o == 0) {
    const float xx = x0*x0 + x1*x1 + z*z;
    ((float4*)coords4)[p] = make_float4(x0, x1, z, xx);
  }
}

// ---------------- weight conversion: transposed, extended, fp16 ----------------
template<int DIN, int DOUT, int XDIM>
__global__ void wconv_kernel(const float* __restrict__ w,
    _Float16* __restrict__ midT, _Float16* __restrict__ difT) {
  const int o = blockIdx.x;
  const int c = threadIdx.x;
  float mv = 0.f, dv = 0.f;
  if (c < DIN)        { const float wm = w[(DIN+c)*DOUT+o]; mv = wm; dv = w[c*DOUT+o] - wm; }
  else if (c < DIN+3) { const float wp = w[(2*DIN+(c-DIN))*DOUT+o]; mv = wp; dv = -wp; }
  midT[o*XDIM+c] = (_Float16)mv;
  difT[o*XDIM+c] = (_Float16)dv;
}

// ---------------- head1 weight transpose -> fp16 ----------------
__global__ __launch_bounds__(256) void htrans_kernel(
    const float* __restrict__ h1w, _Float16* __restrict__ h1wT) {
  const int o = blockIdx.x;
  for (int c = threadIdx.x; c < 512; c += 256)
    h1wT[(size_t)o*512 + c] = (_Float16)h1w[(size_t)c*256 + o];
}

// ---------------- knn: 4 waves x 4 points, packed-f32 distances, threshold pre-pass ----------------
// Selection exact (see r9 bound proof); unchanged from r11.
#define DPP_SHR1(v) __builtin_amdgcn_update_dpp(0, (v), 0x138, 0xF, 0xF, false)

#define DPP_MIN(v, ctrl)                                                        \
  { const int _t = __builtin_amdgcn_update_dpp(__float_as_int(v),               \
      __float_as_int(v), ctrl, 0xF, 0xF, false);                                \
    v = fminf(v, __int_as_float(_t)); }

__device__ __forceinline__ float sixteenth_of_minima(float v) {
  float th = 0.f;
#pragma unroll
  for (int r = 0; r < 16; ++r) {
    float w = v;
    DPP_MIN(w, 0x111); DPP_MIN(w, 0x112); DPP_MIN(w, 0x114); DPP_MIN(w, 0x118);
    DPP_MIN(w, 0x142); DPP_MIN(w, 0x143);   // row_bcast15 / row_bcast31
    const float mv = __int_as_float(
        __builtin_amdgcn_readlane(__float_as_int(w), 63));
    th = mv;
    v = (v == mv) ? INFINITY : v;
  }
  return th;
}

#define KNN_EVT(d, dk, ik)                                                      \
  {                                                                             \
    const int s = (int)__ffsll((unsigned long long)m) - 1;  m &= m - 1;         \
    const float dc = __int_as_float(__builtin_amdgcn_readlane(                  \
                       __float_as_int(d), s));                                  \
    const bool cnd = dc < dk;                                                   \
    const u64 cm = __ballot(cnd) << 1;                                          \
    const float pd = __int_as_float(DPP_SHR1(__float_as_int(dk)));              \
    const int   pi = DPP_SHR1(ik);                                              \
    const bool pc = (cm >> lane) & 1;                                           \
    dk = cnd ? (pc ? pd : dc) : dk;                                             \
    ik = cnd ? (pc ? pi : (jbase + s)) : ik;                                    \
  }

#define KNN_CHUNK(d, dk, ik, T, Th)                                             \
  { u64 m = __ballot(d <= T);                                                   \
    if (m) {                                                                    \
      do { KNN_EVT(d, dk, ik) } while (m);                                      \
      T = fminf(Th, __int_as_float(__builtin_amdgcn_readlane(                   \
            __float_as_int(dk), 15)));                                          \
    }                                                                           \
  }

#define KNN_DIST2(dA, dB)                                                       \
  const f2v cjx = {cj.x, cj.x}, cjy = {cj.y, cj.y},                             \
            cjz = {cj.z, cj.z}, cjw = {cj.w, cj.w};                             \
  f2v tA = cAx * cjx;                                                           \
  tA = __builtin_elementwise_fma(cAy, cjy, tA);                                 \
  tA = __builtin_elementwise_fma(cAz, cjz, tA);                                 \
  const f2v dA = __builtin_elementwise_fma(tA, m2, cAw + cjw);                  \
  f2v tB = cBx * cjx;                                                           \
  tB = __builtin_elementwise_fma(cBy, cjy, tB);                                 \
  tB = __builtin_elementwise_fma(cBz, cjz, tB);                                 \
  const f2v dB = __builtin_elementwise_fma(tB, m2, cBw + cjw);

__global__ __launch_bounds__(256, 8) void knn_kernel(
    const float* __restrict__ coords4, int* __restrict__ knn_idx) {
  const int tid = threadIdx.x;
  const int wid = tid >> 6;
  const int lane = tid & 63;
  const int p0 = blockIdx.x * 16 + wid * 4;   // block of 16 never straddles batch
  const int b = p0 >> 13;
  const float4* cb = ((const float4*)coords4) + (b << 13);
  const float4 c0 = ((const float4*)coords4)[p0+0];
  const float4 c1 = ((const float4*)coords4)[p0+1];
  const float4 c2 = ((const float4*)coords4)[p0+2];
  const float4 c3 = ((const float4*)coords4)[p0+3];
  const f2v m2 = {-2.f, -2.f};
  const f2v cAx = {c0.x, c1.x}, cAy = {c0.y, c1.y}, cAz = {c0.z, c1.z}, cAw = {c0.w, c1.w};
  const f2v cBx = {c2.x, c3.x}, cBy = {c2.y, c3.y}, cBz = {c2.z, c3.z}, cBw = {c2.w, c3.w};

  // ---- pass A: per-lane minima over the first half (straight-line, no events)
  float lm0 = INFINITY, lm1 = INFINITY, lm2 = INFINITY, lm3 = INFINITY;
  for (int it = 0; it < 64; ++it) {
    const float4 cj = cb[it*64 + lane];
    KNN_DIST2(dA, dB)
    lm0 = fminf(lm0, fmaxf(dA[0], 0.f));
    lm1 = fminf(lm1, fmaxf(dA[1], 0.f));
    lm2 = fminf(lm2, fmaxf(dB[0], 0.f));
    lm3 = fminf(lm3, fmaxf(dB[1], 0.f));
  }
  const float Th0 = sixteenth_of_minima(lm0);
  const float Th1 = sixteenth_of_minima(lm1);
  const float Th2 = sixteenth_of_minima(lm2);
  const float Th3 = sixteenth_of_minima(lm3);

  float dk0 = INFINITY, dk1 = INFINITY, dk2 = INFINITY, dk3 = INFINITY;
  int   ik0 = 0, ik1 = 0, ik2 = 0, ik3 = 0;
  float T0 = Th0, T1 = Th1, T2 = Th2, T3 = Th3;

  // ---- main pass: all candidates, events only below the tight bound
  for (int it = 0; it < N_/64; ++it) {
    const int jbase = it*64;
    const float4 cj = cb[jbase + lane];
    KNN_DIST2(dA, dB)
    const float d0 = fmaxf(dA[0], 0.f);
    const float d1 = fmaxf(dA[1], 0.f);
    const float d2 = fmaxf(dB[0], 0.f);
    const float d3 = fmaxf(dB[1], 0.f);
    KNN_CHUNK(d0, dk0, ik0, T0, Th0);
    KNN_CHUNK(d1, dk1, ik1, T1, Th1);
    KNN_CHUNK(d2, dk2, ik2, T2, Th2);
    KNN_CHUNK(d3, dk3, ik3, T3, Th3);
  }

  if (lane < K_) {
    knn_idx[(size_t)(p0+0)*K_ + lane] = ik0;
    knn_idx[(size_t)(p0+1)*K_ + lane] = ik1;
    knn_idx[(size_t)(p0+2)*K_ + lane] = ik2;
    knn_idx[(size_t)(p0+3)*K_ + lane] = ik3;
  }
}

// ---------------- MFMA local_agg, transposed role assignment ----------------
// A-tile = neighbor-slot k of all 16 points (D rows = points, cols = outputs).
// max-over-k = element-wise register max between k iterations; epilogue is
// layout-aligned with the C-part (same D layout) -> zero cross-lane ops.
// No LDS staging (direct global gather + k+1 prefetch; staging proved neutral r7).
template<int KS, int NPASS>
__global__ __launch_bounds__(256) void aggm_kernel(
    const _Float16* __restrict__ fx, const int* __restrict__ knn_idx,
    const _Float16* __restrict__ midT, const _Float16* __restrict__ difT,
    const float* __restrict__ bw,
    _Float16* __restrict__ fo, const int ostr) {
  const int XD = KS*32;
  const int p0 = blockIdx.x * 16;
  const int bb = (p0 >> 13) << 13;
  const int tid = threadIdx.x;
  const int w = tid >> 6, lane = tid & 63, col = lane & 15, quad = lane >> 4;
  const int koff = quad * 8;

  __shared__ int s_idx[256];   // [point_local 0..15][k 0..15]
  s_idx[tid] = knn_idx[p0*K_ + tid];

  // ---- C part (k-independent): A = own 16 point rows, B = difT ----
  f4v cacc[NPASS][2];
  {
    h8v Ao[KS];
    const _Float16* ap = fx + (size_t)(p0+col)*XD + koff;
#pragma unroll
    for (int kk = 0; kk < KS; ++kk) Ao[kk] = *(const h8v*)(ap + kk*32);
#pragma unroll
    for (int ps = 0; ps < NPASS; ++ps) {
      const int o0 = ps*128 + w*32;
      const _Float16* b0 = difT + (size_t)(o0 + col)*XD + koff;
      const _Float16* b1 = difT + (size_t)(o0 + 16 + col)*XD + koff;
      f4v c0 = {0.f,0.f,0.f,0.f}, c1 = {0.f,0.f,0.f,0.f};
#pragma unroll
      for (int kk = 0; kk < KS; ++kk) {
        c0 = MFMA16(Ao[kk], *(const h8v*)(b0 + kk*32), c0);
        c1 = MFMA16(Ao[kk], *(const h8v*)(b1 + kk*32), c1);
      }
      cacc[ps][0] = c0; cacc[ps][1] = c1;
    }
  }
  __syncthreads();   // s_idx ready

#pragma unroll
  for (int ps = 0; ps < NPASS; ++ps) {
    const int o0 = ps*128 + w*32;
    const int oa = o0 + col, ob = oa + 16;
    h8v B0[KS], B1[KS];
#pragma unroll
    for (int kk = 0; kk < KS; ++kk) {
      B0[kk] = *(const h8v*)(midT + (size_t)oa*XD + kk*32 + koff);
      B1[kk] = *(const h8v*)(midT + (size_t)ob*XD + kk*32 + koff);
    }
    const float bias0 = bw[oa], bias1 = bw[ob];

    // A[m][*] = neighbor-k row of point m (m = col); prefetch k+1 while MFMAing k
    h8v Ac[KS];
    {
      const _Float16* ap = fx + (size_t)(bb + s_idx[(col<<4)])*XD + koff;
#pragma unroll
      for (int kk = 0; kk < KS; ++kk) Ac[kk] = *(const h8v*)(ap + kk*32);
    }
    f4v M0 = {-INFINITY,-INFINITY,-INFINITY,-INFINITY};
    f4v M1 = {-INFINITY,-INFINITY,-INFINITY,-INFINITY};
    for (int k = 0; k < 16; ++k) {
      h8v An[KS];
      {
        const int kn = (k < 15) ? k + 1 : 15;
        const _Float16* ap = fx + (size_t)(bb + s_idx[(col<<4) + kn])*XD + koff;
#pragma unroll
        for (int kk = 0; kk < KS; ++kk) An[kk] = *(const h8v*)(ap + kk*32);
      }
      f4v d0 = {0.f,0.f,0.f,0.f}, d1 = {0.f,0.f,0.f,0.f};
#pragma unroll
      for (int kk = 0; kk < KS; ++kk) {
        d0 = MFMA16(Ac[kk], B0[kk], d0);
        d1 = MFMA16(Ac[kk], B1[kk], d1);
      }
#pragma unroll
      for (int e = 0; e < 4; ++e) {
        M0[e] = fmaxf(M0[e], d0[e]);
        M1[e] = fmaxf(M1[e], d1[e]);
      }
#pragma unroll
      for (int kk = 0; kk < KS; ++kk) Ac[kk] = An[kk];
    }

    // epilogue: out[p][o] = max(M + C + bias, 0); lane holds rows quad*4+reg
    const int prow = p0 + (quad << 2);
#pragma unroll
    for (int reg = 0; reg < 4; ++reg) {
      fo[(size_t)(prow+reg)*ostr + oa] =
          (_Float16)fmaxf(M0[reg] + cacc[ps][0][reg] + bias0, 0.f);
      fo[(size_t)(prow+reg)*ostr + ob] =
          (_Float16)fmaxf(M1[reg] + cacc[ps][1][reg] + bias1, 0.f);
    }
  }
}

// ---------------- global max (stage 1): coalesced uint4 loads ----------------
__global__ __launch_bounds__(256) void gmax_kernel(
    const _Float16* __restrict__ f2h, float* __restrict__ part) {
  const int b = blockIdx.x >> 5;
  const int seg = blockIdx.x & 31;
  const int tid = threadIdx.x;
  const int rg = tid >> 5;            // 0..7
  const int cc = (tid & 31) * 8;      // col chunk base
  __shared__ float smax[8][256];
  const size_t rbase = (size_t)(b << 13) + seg*256;
  _Float16 mh[8];
#pragma unroll
  for (int j = 0; j < 8; ++j) mh[j] = (_Float16)0.f;   // relu outputs >= 0
  for (int n = rg; n < 256; n += 8) {
    const h8v v = *(const h8v*)&f2h[(rbase + n)*W2_ + cc];
#pragma unroll
    for (int j = 0; j < 8; ++j) mh[j] = (v[j] > mh[j]) ? v[j] : mh[j];
  }
#pragma unroll
  for (int j = 0; j < 8; ++j) smax[rg][cc + j] = (float)mh[j];
  __syncthreads();
  float m = smax[0][tid];
#pragma unroll
  for (int g = 1; g < 8; ++g) m = fmaxf(m, smax[g][tid]);
  part[(size_t)blockIdx.x*W2_ + tid] = m;
}

// ---------------- global max reduce + glob FC -> g2h fp16 ----------------
__global__ __launch_bounds__(256) void gfc_kernel(
    const float* __restrict__ part, const float* __restrict__ gw,
    const float* __restrict__ gb, _Float16* __restrict__ g2h) {
  const int b = blockIdx.x;
  const int o = threadIdx.x;
  __shared__ float s_g[W2_];
  float m = -INFINITY;
  for (int s = 0; s < 32; ++s) m = fmaxf(m, part[(size_t)(b*32+s)*W2_ + o]);
  s_g[o] = m;
  __syncthreads();
  float acc = gb[o];
  for (int d = 0; d < W2_; ++d) acc += s_g[d]*gw[d*W2_ + o];
  g2h[b*W2_ + o] = (_Float16)fmaxf(acc, 0.f);
}

// ---------------- head: 32 points/block MFMA GEMM + tiny second layer ----------------
__global__ __launch_bounds__(256) void headm_kernel(
    const _Float16* __restrict__ f2h, const _Float16* __restrict__ g2h,
    const _Float16* __restrict__ h1wT, const float* __restrict__ h1b,
    const float* __restrict__ h2w, const float* __restrict__ h2b,
    const float* __restrict__ x,
    const float* __restrict__ thresh, const float* __restrict__ sharp,
    const float* __restrict__ scale,
    float* __restrict__ out) {
  const int p0 = blockIdx.x * 32;
  const int b = p0 >> 13;
  const int tid = threadIdx.x;
  const int w = tid >> 6, lane = tid & 63, col = lane & 15, quad = lane >> 4;

  __shared__ _Float16 sA[32*520];   // 32 points x 512 (padded to 520)
  __shared__ float    sh[32*260];   // relu(h1) f32

  for (int t = tid; t < 32*32; t += 256) {       // f2h part (16B chunks)
    const int r = t >> 5, cc = (t & 31) * 8;
    *(uint4*)&sA[r*520 + cc] = *(const uint4*)&f2h[(size_t)(p0+r)*W2_ + cc];
  }
  for (int t = tid; t < 32*32; t += 256) {       // g2h broadcast part
    const int r = t >> 5, cc = (t & 31) * 8;
    *(uint4*)&sA[r*520 + 256 + cc] = *(const uint4*)&g2h[b*W2_ + cc];
  }
  __syncthreads();

  f4v acc[2][4];
#pragma unroll
  for (int r = 0; r < 2; ++r)
#pragma unroll
    for (int t = 0; t < 4; ++t) acc[r][t] = (f4v){0.f,0.f,0.f,0.f};

  for (int kk = 0; kk < 16; ++kk) {
    const h8v a0 = *(const h8v*)&sA[col*520 + kk*32 + quad*8];
    const h8v a1 = *(const h8v*)&sA[(16+col)*520 + kk*32 + quad*8];
#pragma unroll
    for (int t = 0; t < 4; ++t) {
      const h8v bt = *(const h8v*)&h1wT[(size_t)(w*64 + t*16 + col)*512 + kk*32 + quad*8];
      acc[0][t] = MFMA16(a0, bt, acc[0][t]);
      acc[1][t] = MFMA16(a1, bt, acc[1][t]);
    }
  }
#pragma unroll
  for (int r = 0; r < 2; ++r)
#pragma unroll
    for (int t = 0; t < 4; ++t) {
      const int o = w*64 + t*16 + col;
      const float bv = h1b[o];
#pragma unroll
      for (int reg = 0; reg < 4; ++reg)
        sh[(r*16 + quad*4 + reg)*260 + o] = fmaxf(acc[r][t][reg] + bv, 0.f);
    }
  __syncthreads();

  if (tid < 96) {
    const int pp = tid / 3, c = tid % 3;
    float s = h2b[c];
    for (int d = 0; d < 256; ++d) s += sh[pp*260 + d] * h2w[d*3 + c];
    if (c == 0) {
      const float hag = x[(size_t)(p0+pp)*4 + 3];
      s += scale[0] / (1.f + expf(-sharp[0]*(thresh[0] - hag)));
    }
    out[(size_t)(p0+pp)*3 + c] = s;
  }
}

// ---------------- launch ----------------
extern "C" void kernel_launch(void* const* d_in, const int* in_sizes, int n_in,
                              void* d_out, int out_size, void* d_ws, size_t ws_size,
                              hipStream_t stream) {
  const float* x       = (const float*)d_in[0];
  const float* hmix_a  = (const float*)d_in[1];
  const float* hmix_b  = (const float*)d_in[2];
  const float* hmix_c  = (const float*)d_in[3];
  const float* stem_w  = (const float*)d_in[4];
  const float* stem_b  = (const float*)d_in[5];
  const float* b1_w    = (const float*)d_in[6];
  const float* b1_b    = (const float*)d_in[7];
  const float* b2_w    = (const float*)d_in[8];
  const float* b2_b    = (const float*)d_in[9];
  const float* glob_w  = (const float*)d_in[10];
  const float* glob_b  = (const float*)d_in[11];
  const float* head1_w = (const float*)d_in[12];
  const float* head1_b = (const float*)d_in[13];
  const float* head2_w = (const float*)d_in[14];
  const float* head2_b = (const float*)d_in[15];
  const float* thresh  = (const float*)d_in[16];
  const float* sharp   = (const float*)d_in[17];
  const float* scale   = (const float*)d_in[18];
  float* out = (float*)d_out;

  char* base = (char*)d_ws;
  float*     coords4 = (float*)    (base + 0);          // 512 KB
  int*       idxb    = (int*)      (base + 524288);     // 2 MB
  _Float16*  fx0     = (_Float16*) (base + 2621440);    // 6 MB   (32768*96*2)
  _Float16*  fx1     = (_Float16*) (base + 8912896);    // 10 MB  (32768*160*2)
  _Float16*  f2h     = (_Float16*) (base + 19398656);   // 16 MB  (32768*256*2)
  _Float16*  w1m     = (_Float16*) (base + 36175872);   // 24 KB  (128*96*2)
  _Float16*  w1d     = (_Float16*) (base + 36200448);   // 24 KB
  _Float16*  w2m     = (_Float16*) (base + 36225024);   // 80 KB  (256*160*2)
  _Float16*  w2d     = (_Float16*) (base + 36306944);   // 80 KB
  _Float16*  h1wT    = (_Float16*) (base + 36388864);   // 256 KB (256*512*2)
  float*     part    = (float*)    (base + 36651008);   // 128 KB
  _Float16*  g2h     = (_Float16*) (base + 36782080);   // 2 KB

  const int NP = B_ * N_;   // 32768 points

  wconv_kernel<W0_, W1_, X0_><<<W1_, X0_, 0, stream>>>(b1_w, w1m, w1d);
  wconv_kernel<W1_, W2_, X1_><<<W2_, X1_, 0, stream>>>(b2_w, w2m, w2d);
  htrans_kernel<<<W2_, 256, 0, stream>>>(head1_w, h1wT);
  prep_kernel<<<NP/4, 256, 0, stream>>>(x, stem_w, stem_b, hmix_a, hmix_b, hmix_c,
                                        coords4, fx0, fx1);
  knn_kernel<<<NP/16, 256, 0, stream>>>(coords4, idxb);
  aggm_kernel<3, 1><<<NP/16, 256, 0, stream>>>(fx0, idxb, w1m, w1d, b1_b, fx1, X1_);
  aggm_kernel<5, 2><<<NP/16, 256, 0, stream>>>(fx1, idxb, w2m, w2d, b2_b, f2h, W2_);
  gmax_kernel<<<B_*32, 256, 0, stream>>>(f2h, part);
  gfc_kernel<<<B_, 256, 0, stream>>>(part, glob_w, glob_b, g2h);
  headm_kernel<<<NP/32, 256, 0, stream>>>(f2h, g2h, h1wT, head1_b, head2_w, head2_b,
                                          x, thresh, sharp, scale, out);
}

// Round 13
// 453.846 us; speedup vs baseline: 5.1446x; 1.0455x over previous
//
#include <hip/hip_runtime.h>
#include <math.h>

typedef unsigned long long u64;
typedef unsigned int u32;
typedef _Float16 h8v __attribute__((ext_vector_type(8)));  // 8 fp16 (4 VGPRs)
typedef float    f4v __attribute__((ext_vector_type(4)));  // MFMA acc
typedef float    f2v __attribute__((ext_vector_type(2)));  // v_pk_*_f32 pair

#define MFMA16(a,b,c) __builtin_amdgcn_mfma_f32_16x16x32_f16(a, b, c, 0, 0, 0)

#define B_ 4
#define N_ 8192
#define K_ 16
#define W0_ 64
#define W1_ 128
#define W2_ 256
#define X0_ 96   // padded K-dim layer-1 inputs (64 feat + 3 coord + 29 zero)
#define X1_ 160  // padded K-dim layer-2 inputs (128 feat + 3 coord + 29 zero)

// ---------------- prep: 4 points/block (256 thr) -> coords4, fx0, fx1 tail ----------------
__global__ __launch_bounds__(256) void prep_kernel(
    const float* __restrict__ x,
    const float* __restrict__ stem_w, const float* __restrict__ stem_b,
    const float* __restrict__ hmix_a, const float* __restrict__ hmix_b,
    const float* __restrict__ hmix_c,
    float* __restrict__ coords4, _Float16* __restrict__ fx0,
    _Float16* __restrict__ fx1) {
  const int p = blockIdx.x * 4 + (threadIdx.x >> 6);
  const int o = threadIdx.x & 63;
  const float x0 = x[p*4+0], x1 = x[p*4+1], x2 = x[p*4+2], x3 = x[p*4+3];
  const float z = hmix_a[0]*x2 + hmix_b[0]*x3 + hmix_c[0];
  float acc = stem_b[o] + x0*stem_w[0*W0_+o] + x1*stem_w[1*W0_+o]
            + x2*stem_w[2*W0_+o] + x3*stem_w[3*W0_+o];
  fx0[p*X0_+o] = (_Float16)fmaxf(acc, 0.f);
  if (o < 32) {   // tail: 3 coords + 29 zeros (both layers' inputs)
    const float tv = (o==0) ? x0 : (o==1) ? x1 : (o==2) ? z : 0.f;
    fx0[p*X0_+W0_+o] = (_Float16)tv;
    fx1[(size_t)p*X1_+W1_+o] = (_Float16)tv;
  }
  if (o == 0) {
    const float xx = x0*x0 + x1*x1 + z*z;
    ((float4*)coords4)[p] = make_float4(x0, x1, z, xx);
  }
}

// ---------------- weight conversion: transposed, extended, fp16 ----------------
template<int DIN, int DOUT, int XDIM>
__global__ void wconv_kernel(const float* __restrict__ w,
    _Float16* __restrict__ midT, _Float16* __restrict__ difT) {
  const int o = blockIdx.x;
  const int c = threadIdx.x;
  float mv = 0.f, dv = 0.f;
  if (c < DIN)        { const float wm = w[(DIN+c)*DOUT+o]; mv = wm; dv = w[c*DOUT+o] - wm; }
  else if (c < DIN+3) { const float wp = w[(2*DIN+(c-DIN))*DOUT+o]; mv = wp; dv = -wp; }
  midT[o*XDIM+c] = (_Float16)mv;
  difT[o*XDIM+c] = (_Float16)dv;
}

// ---------------- head1 weight transpose -> fp16 ----------------
__global__ __launch_bounds__(256) void htrans_kernel(
    const float* __restrict__ h1w, _Float16* __restrict__ h1wT) {
  const int o = blockIdx.x;
  for (int c = threadIdx.x; c < 512; c += 256)
    h1wT[(size_t)o*512 + c] = (_Float16)h1w[(size_t)c*256 + o];
}

// ---------------- knn: 4 waves x 4 points, packed-f32 distances, threshold pre-pass ----------------
// Selection exact (see r9 bound proof); unchanged from r11/r12.
#define DPP_SHR1(v) __builtin_amdgcn_update_dpp(0, (v), 0x138, 0xF, 0xF, false)

#define DPP_MIN(v, ctrl)                                                        \
  { const int _t = __builtin_amdgcn_update_dpp(__float_as_int(v),               \
      __float_as_int(v), ctrl, 0xF, 0xF, false);                                \
    v = fminf(v, __int_as_float(_t)); }

__device__ __forceinline__ float sixteenth_of_minima(float v) {
  float th = 0.f;
#pragma unroll
  for (int r = 0; r < 16; ++r) {
    float w = v;
    DPP_MIN(w, 0x111); DPP_MIN(w, 0x112); DPP_MIN(w, 0x114); DPP_MIN(w, 0x118);
    DPP_MIN(w, 0x142); DPP_MIN(w, 0x143);   // row_bcast15 / row_bcast31
    const float mv = __int_as_float(
        __builtin_amdgcn_readlane(__float_as_int(w), 63));
    th = mv;
    v = (v == mv) ? INFINITY : v;
  }
  return th;
}

#define KNN_EVT(d, dk, ik)                                                      \
  {                                                                             \
    const int s = (int)__ffsll((unsigned long long)m) - 1;  m &= m - 1;         \
    const float dc = __int_as_float(__builtin_amdgcn_readlane(                  \
                       __float_as_int(d), s));                                  \
    const bool cnd = dc < dk;                                                   \
    const u64 cm = __ballot(cnd) << 1;                                          \
    const float pd = __int_as_float(DPP_SHR1(__float_as_int(dk)));              \
    const int   pi = DPP_SHR1(ik);                                              \
    const bool pc = (cm >> lane) & 1;                                           \
    dk = cnd ? (pc ? pd : dc) : dk;                                             \
    ik = cnd ? (pc ? pi : (jbase + s)) : ik;                                    \
  }

#define KNN_CHUNK(d, dk, ik, T, Th)                                             \
  { u64 m = __ballot(d <= T);                                                   \
    if (m) {                                                                    \
      do { KNN_EVT(d, dk, ik) } while (m);                                      \
      T = fminf(Th, __int_as_float(__builtin_amdgcn_readlane(                   \
            __float_as_int(dk), 15)));                                          \
    }                                                                           \
  }

#define KNN_DIST2(dA, dB)                                                       \
  const f2v cjx = {cj.x, cj.x}, cjy = {cj.y, cj.y},                             \
            cjz = {cj.z, cj.z}, cjw = {cj.w, cj.w};                             \
  f2v tA = cAx * cjx;                                                           \
  tA = __builtin_elementwise_fma(cAy, cjy, tA);                                 \
  tA = __builtin_elementwise_fma(cAz, cjz, tA);                                 \
  const f2v dA = __builtin_elementwise_fma(tA, m2, cAw + cjw);                  \
  f2v tB = cBx * cjx;                                                           \
  tB = __builtin_elementwise_fma(cBy, cjy, tB);                                 \
  tB = __builtin_elementwise_fma(cBz, cjz, tB);                                 \
  const f2v dB = __builtin_elementwise_fma(tB, m2, cBw + cjw);

__global__ __launch_bounds__(256, 8) void knn_kernel(
    const float* __restrict__ coords4, int* __restrict__ knn_idx) {
  const int tid = threadIdx.x;
  const int wid = tid >> 6;
  const int lane = tid & 63;
  const int p0 = blockIdx.x * 16 + wid * 4;   // block of 16 never straddles batch
  const int b = p0 >> 13;
  const float4* cb = ((const float4*)coords4) + (b << 13);
  const float4 c0 = ((const float4*)coords4)[p0+0];
  const float4 c1 = ((const float4*)coords4)[p0+1];
  const float4 c2 = ((const float4*)coords4)[p0+2];
  const float4 c3 = ((const float4*)coords4)[p0+3];
  const f2v m2 = {-2.f, -2.f};
  const f2v cAx = {c0.x, c1.x}, cAy = {c0.y, c1.y}, cAz = {c0.z, c1.z}, cAw = {c0.w, c1.w};
  const f2v cBx = {c2.x, c3.x}, cBy = {c2.y, c3.y}, cBz = {c2.z, c3.z}, cBw = {c2.w, c3.w};

  // ---- pass A: per-lane minima over the first half (straight-line, no events)
  float lm0 = INFINITY, lm1 = INFINITY, lm2 = INFINITY, lm3 = INFINITY;
  for (int it = 0; it < 64; ++it) {
    const float4 cj = cb[it*64 + lane];
    KNN_DIST2(dA, dB)
    lm0 = fminf(lm0, fmaxf(dA[0], 0.f));
    lm1 = fminf(lm1, fmaxf(dA[1], 0.f));
    lm2 = fminf(lm2, fmaxf(dB[0], 0.f));
    lm3 = fminf(lm3, fmaxf(dB[1], 0.f));
  }
  const float Th0 = sixteenth_of_minima(lm0);
  const float Th1 = sixteenth_of_minima(lm1);
  const float Th2 = sixteenth_of_minima(lm2);
  const float Th3 = sixteenth_of_minima(lm3);

  float dk0 = INFINITY, dk1 = INFINITY, dk2 = INFINITY, dk3 = INFINITY;
  int   ik0 = 0, ik1 = 0, ik2 = 0, ik3 = 0;
  float T0 = Th0, T1 = Th1, T2 = Th2, T3 = Th3;

  // ---- main pass: all candidates, events only below the tight bound
  for (int it = 0; it < N_/64; ++it) {
    const int jbase = it*64;
    const float4 cj = cb[jbase + lane];
    KNN_DIST2(dA, dB)
    const float d0 = fmaxf(dA[0], 0.f);
    const float d1 = fmaxf(dA[1], 0.f);
    const float d2 = fmaxf(dB[0], 0.f);
    const float d3 = fmaxf(dB[1], 0.f);
    KNN_CHUNK(d0, dk0, ik0, T0, Th0);
    KNN_CHUNK(d1, dk1, ik1, T1, Th1);
    KNN_CHUNK(d2, dk2, ik2, T2, Th2);
    KNN_CHUNK(d3, dk3, ik3, T3, Th3);
  }

  if (lane < K_) {
    knn_idx[(size_t)(p0+0)*K_ + lane] = ik0;
    knn_idx[(size_t)(p0+1)*K_ + lane] = ik1;
    knn_idx[(size_t)(p0+2)*K_ + lane] = ik2;
    knn_idx[(size_t)(p0+3)*K_ + lane] = ik3;
  }
}

// ---------------- MFMA local_agg: transposed layout + LDS dbuf per-k staging ----------------
// r12 layout (A rows = points, max-over-k in registers, no cross-lane epilogue)
// + r13: the 16 rows of neighbor-slot k are staged into LDS ONCE per block and
// shared by all 4 waves and both passes (k outer, pass inner) -> global A-traffic
// drops 8x to the K-fold minimum. Double-buffered, one barrier per k.
template<int KS, int NPASS>
__global__ __launch_bounds__(256) void aggm_kernel(
    const _Float16* __restrict__ fx, const int* __restrict__ knn_idx,
    const _Float16* __restrict__ midT, const _Float16* __restrict__ difT,
    const float* __restrict__ bw,
    _Float16* __restrict__ fo, const int ostr) {
  const int XD  = KS*32;
  const int XDP = XD + 8;               // +16B pad per row
  const int CH  = KS*4;                 // uint4 chunks per row
  const int p0 = blockIdx.x * 16;
  const int bb = (p0 >> 13) << 13;
  const int tid = threadIdx.x;
  const int w = tid >> 6, lane = tid & 63, col = lane & 15, quad = lane >> 4;
  const int koff = quad * 8;

  __shared__ int s_idx[256];            // [point m][k]
  __shared__ _Float16 sA[2][16*(KS*32+8)];

  s_idx[tid] = knn_idx[p0*K_ + tid];

  // ---- C part (k-independent): A = own 16 point rows, B = difT ----
  f4v cacc[NPASS][2];
  {
    h8v Ao[KS];
    const _Float16* ap = fx + (size_t)(p0+col)*XD + koff;
#pragma unroll
    for (int kk = 0; kk < KS; ++kk) Ao[kk] = *(const h8v*)(ap + kk*32);
#pragma unroll
    for (int ps = 0; ps < NPASS; ++ps) {
      const int o0 = ps*128 + w*32;
      const _Float16* b0 = difT + (size_t)(o0 + col)*XD + koff;
      const _Float16* b1 = difT + (size_t)(o0 + 16 + col)*XD + koff;
      f4v c0 = {0.f,0.f,0.f,0.f}, c1 = {0.f,0.f,0.f,0.f};
#pragma unroll
      for (int kk = 0; kk < KS; ++kk) {
        c0 = MFMA16(Ao[kk], *(const h8v*)(b0 + kk*32), c0);
        c1 = MFMA16(Ao[kk], *(const h8v*)(b1 + kk*32), c1);
      }
      cacc[ps][0] = c0; cacc[ps][1] = c1;
    }
  }

  // ---- B fragments for ALL passes in registers ----
  h8v Bf[NPASS][2][KS];
  float bias[NPASS][2];
#pragma unroll
  for (int ps = 0; ps < NPASS; ++ps) {
    const int o0 = ps*128 + w*32;
#pragma unroll
    for (int kk = 0; kk < KS; ++kk) {
      Bf[ps][0][kk] = *(const h8v*)(midT + (size_t)(o0 + col)*XD + kk*32 + koff);
      Bf[ps][1][kk] = *(const h8v*)(midT + (size_t)(o0 + 16 + col)*XD + kk*32 + koff);
    }
    bias[ps][0] = bw[o0 + col];
    bias[ps][1] = bw[o0 + 16 + col];
  }
  __syncthreads();   // s_idx ready

  // ---- stage k=0 ----
  for (int c = tid; c < 16*CH; c += 256) {
    const int r = c / CH, o = c - r*CH;
    *(uint4*)&sA[0][r*XDP + o*8] =
        *(const uint4*)(fx + (size_t)(bb + s_idx[r<<4])*XD + o*8);
  }
  __syncthreads();

  f4v M[NPASS][2];
#pragma unroll
  for (int ps = 0; ps < NPASS; ++ps) {
    M[ps][0] = (f4v){-INFINITY,-INFINITY,-INFINITY,-INFINITY};
    M[ps][1] = (f4v){-INFINITY,-INFINITY,-INFINITY,-INFINITY};
  }

  for (int k = 0; k < 16; ++k) {
    const int buf = k & 1;
    if (k < 15) {   // stage k+1 into the other buffer
      for (int c = tid; c < 16*CH; c += 256) {
        const int r = c / CH, o = c - r*CH;
        *(uint4*)&sA[buf^1][r*XDP + o*8] =
            *(const uint4*)(fx + (size_t)(bb + s_idx[(r<<4) + k + 1])*XD + o*8);
      }
    }
    h8v Ac[KS];
    const _Float16* ap = &sA[buf][col*XDP + koff];
#pragma unroll
    for (int kk = 0; kk < KS; ++kk) Ac[kk] = *(const h8v*)(ap + kk*32);
#pragma unroll
    for (int ps = 0; ps < NPASS; ++ps) {
      f4v d0 = {0.f,0.f,0.f,0.f}, d1 = {0.f,0.f,0.f,0.f};
#pragma unroll
      for (int kk = 0; kk < KS; ++kk) {
        d0 = MFMA16(Ac[kk], Bf[ps][0][kk], d0);
        d1 = MFMA16(Ac[kk], Bf[ps][1][kk], d1);
      }
#pragma unroll
      for (int e = 0; e < 4; ++e) {
        M[ps][0][e] = fmaxf(M[ps][0][e], d0[e]);
        M[ps][1][e] = fmaxf(M[ps][1][e], d1[e]);
      }
    }
    __syncthreads();   // staged data visible; readers done before overwrite
  }

  // ---- epilogue: out[p][o] = max(M + C + bias, 0); lane holds rows quad*4+reg ----
  const int prow = p0 + (quad << 2);
#pragma unroll
  for (int ps = 0; ps < NPASS; ++ps) {
    const int o0 = ps*128 + w*32;
    const int oa = o0 + col, ob = oa + 16;
#pragma unroll
    for (int reg = 0; reg < 4; ++reg) {
      fo[(size_t)(prow+reg)*ostr + oa] =
          (_Float16)fmaxf(M[ps][0][reg] + cacc[ps][0][reg] + bias[ps][0], 0.f);
      fo[(size_t)(prow+reg)*ostr + ob] =
          (_Float16)fmaxf(M[ps][1][reg] + cacc[ps][1][reg] + bias[ps][1], 0.f);
    }
  }
}

// ---------------- global max (stage 1): coalesced uint4 loads ----------------
__global__ __launch_bounds__(256) void gmax_kernel(
    const _Float16* __restrict__ f2h, float* __restrict__ part) {
  const int b = blockIdx.x >> 5;
  const int seg = blockIdx.x & 31;
  const int tid = threadIdx.x;
  const int rg = tid >> 5;            // 0..7
  const int cc = (tid & 31) * 8;      // col chunk base
  __shared__ float smax[8][256];
  const size_t rbase = (size_t)(b << 13) + seg*256;
  _Float16 mh[8];
#pragma unroll
  for (int j = 0; j < 8; ++j) mh[j] = (_Float16)0.f;   // relu outputs >= 0
  for (int n = rg; n < 256; n += 8) {
    const h8v v = *(const h8v*)&f2h[(rbase + n)*W2_ + cc];
#pragma unroll
    for (int j = 0; j < 8; ++j) mh[j] = (v[j] > mh[j]) ? v[j] : mh[j];
  }
#pragma unroll
  for (int j = 0; j < 8; ++j) smax[rg][cc + j] = (float)mh[j];
  __syncthreads();
  float m = smax[0][tid];
#pragma unroll
  for (int g = 1; g < 8; ++g) m = fmaxf(m, smax[g][tid]);
  part[(size_t)blockIdx.x*W2_ + tid] = m;
}

// ---------------- global max reduce + glob FC -> g2h fp16 ----------------
__global__ __launch_bounds__(256) void gfc_kernel(
    const float* __restrict__ part, const float* __restrict__ gw,
    const float* __restrict__ gb, _Float16* __restrict__ g2h) {
  const int b = blockIdx.x;
  const int o = threadIdx.x;
  __shared__ float s_g[W2_];
  float m = -INFINITY;
  for (int s = 0; s < 32; ++s) m = fmaxf(m, part[(size_t)(b*32+s)*W2_ + o]);
  s_g[o] = m;
  __syncthreads();
  float acc = gb[o];
  for (int d = 0; d < W2_; ++d) acc += s_g[d]*gw[d*W2_ + o];
  g2h[b*W2_ + o] = (_Float16)fmaxf(acc, 0.f);
}

// ---------------- head: 32 points/block MFMA GEMM + tiny second layer ----------------
__global__ __launch_bounds__(256) void headm_kernel(
    const _Float16* __restrict__ f2h, const _Float16* __restrict__ g2h,
    const _Float16* __restrict__ h1wT, const float* __restrict__ h1b,
    const float* __restrict__ h2w, const float* __restrict__ h2b,
    const float* __restrict__ x,
    const float* __restrict__ thresh, const float* __restrict__ sharp,
    const float* __restrict__ scale,
    float* __restrict__ out) {
  const int p0 = blockIdx.x * 32;
  const int b = p0 >> 13;
  const int tid = threadIdx.x;
  const int w = tid >> 6, lane = tid & 63, col = lane & 15, quad = lane >> 4;

  __shared__ _Float16 sA[32*520];   // 32 points x 512 (padded to 520)
  __shared__ float    sh[32*260];   // relu(h1) f32

  for (int t = tid; t < 32*32; t += 256) {       // f2h part (16B chunks)
    const int r = t >> 5, cc = (t & 31) * 8;
    *(uint4*)&sA[r*520 + cc] = *(const uint4*)&f2h[(size_t)(p0+r)*W2_ + cc];
  }
  for (int t = tid; t < 32*32; t += 256) {       // g2h broadcast part
    const int r = t >> 5, cc = (t & 31) * 8;
    *(uint4*)&sA[r*520 + 256 + cc] = *(const uint4*)&g2h[b*W2_ + cc];
  }
  __syncthreads();

  f4v acc[2][4];
#pragma unroll
  for (int r = 0; r < 2; ++r)
#pragma unroll
    for (int t = 0; t < 4; ++t) acc[r][t] = (f4v){0.f,0.f,0.f,0.f};

  for (int kk = 0; kk < 16; ++kk) {
    const h8v a0 = *(const h8v*)&sA[col*520 + kk*32 + quad*8];
    const h8v a1 = *(const h8v*)&sA[(16+col)*520 + kk*32 + quad*8];
#pragma unroll
    for (int t = 0; t < 4; ++t) {
      const h8v bt = *(const h8v*)&h1wT[(size_t)(w*64 + t*16 + col)*512 + kk*32 + quad*8];
      acc[0][t] = MFMA16(a0, bt, acc[0][t]);
      acc[1][t] = MFMA16(a1, bt, acc[1][t]);
    }
  }
#pragma unroll
  for (int r = 0; r < 2; ++r)
#pragma unroll
    for (int t = 0; t < 4; ++t) {
      const int o = w*64 + t*16 + col;
      const float bv = h1b[o];
#pragma unroll
      for (int reg = 0; reg < 4; ++reg)
        sh[(r*16 + quad*4 + reg)*260 + o] = fmaxf(acc[r][t][reg] + bv, 0.f);
    }
  __syncthreads();

  if (tid < 96) {
    const int pp = tid / 3, c = tid % 3;
    float s = h2b[c];
    for (int d = 0; d < 256; ++d) s += sh[pp*260 + d] * h2w[d*3 + c];
    if (c == 0) {
      const float hag = x[(size_t)(p0+pp)*4 + 3];
      s += scale[0] / (1.f + expf(-sharp[0]*(thresh[0] - hag)));
    }
    out[(size_t)(p0+pp)*3 + c] = s;
  }
}

// ---------------- launch ----------------
extern "C" void kernel_launch(void* const* d_in, const int* in_sizes, int n_in,
                              void* d_out, int out_size, void* d_ws, size_t ws_size,
                              hipStream_t stream) {
  const float* x       = (const float*)d_in[0];
  const float* hmix_a  = (const float*)d_in[1];
  const float* hmix_b  = (const float*)d_in[2];
  const float* hmix_c  = (const float*)d_in[3];
  const float* stem_w  = (const float*)d_in[4];
  const float* stem_b  = (const float*)d_in[5];
  const float* b1_w    = (const float*)d_in[6];
  const float* b1_b    = (const float*)d_in[7];
  const float* b2_w    = (const float*)d_in[8];
  const float* b2_b    = (const float*)d_in[9];
  const float* glob_w  = (const float*)d_in[10];
  const float* glob_b  = (const float*)d_in[11];
  const float* head1_w = (const float*)d_in[12];
  const float* head1_b = (const float*)d_in[13];
  const float* head2_w = (const float*)d_in[14];
  const float* head2_b = (const float*)d_in[15];
  const float* thresh  = (const float*)d_in[16];
  const float* sharp   = (const float*)d_in[17];
  const float* scale   = (const float*)d_in[18];
  float* out = (float*)d_out;

  char* base = (char*)d_ws;
  float*     coords4 = (float*)    (base + 0);          // 512 KB
  int*       idxb    = (int*)      (base + 524288);     // 2 MB
  _Float16*  fx0     = (_Float16*) (base + 2621440);    // 6 MB   (32768*96*2)
  _Float16*  fx1     = (_Float16*) (base + 8912896);    // 10 MB  (32768*160*2)
  _Float16*  f2h     = (_Float16*) (base + 19398656);   // 16 MB  (32768*256*2)
  _Float16*  w1m     = (_Float16*) (base + 36175872);   // 24 KB  (128*96*2)
  _Float16*  w1d     = (_Float16*) (base + 36200448);   // 24 KB
  _Float16*  w2m     = (_Float16*) (base + 36225024);   // 80 KB  (256*160*2)
  _Float16*  w2d     = (_Float16*) (base + 36306944);   // 80 KB
  _Float16*  h1wT    = (_Float16*) (base + 36388864);   // 256 KB (256*512*2)
  float*     part    = (float*)    (base + 36651008);   // 128 KB
  _Float16*  g2h     = (_Float16*) (base + 36782080);   // 2 KB

  const int NP = B_ * N_;   // 32768 points

  wconv_kernel<W0_, W1_, X0_><<<W1_, X0_, 0, stream>>>(b1_w, w1m, w1d);
  wconv_kernel<W1_, W2_, X1_><<<W2_, X1_, 0, stream>>>(b2_w, w2m, w2d);
  htrans_kernel<<<W2_, 256, 0, stream>>>(head1_w, h1wT);
  prep_kernel<<<NP/4, 256, 0, stream>>>(x, stem_w, stem_b, hmix_a, hmix_b, hmix_c,
                                        coords4, fx0, fx1);
  knn_kernel<<<NP/16, 256, 0, stream>>>(coords4, idxb);
  aggm_kernel<3, 1><<<NP/16, 256, 0, stream>>>(fx0, idxb, w1m, w1d, b1_b, fx1, X1_);
  aggm_kernel<5, 2><<<NP/16, 256, 0, stream>>>(fx1, idxb, w2m, w2d, b2_b, f2h, W2_);
  gmax_kernel<<<B_*32, 256, 0, stream>>>(f2h, part);
  gfc_kernel<<<B_, 256, 0, stream>>>(part, glob_w, glob_b, g2h);
  headm_kernel<<<NP/32, 256, 0, stream>>>(f2h, g2h, h1wT, head1_b, head2_w, head2_b,
                                          x, thresh, sharp, scale, out);
}

// Round 14
// 445.056 us; speedup vs baseline: 5.2462x; 1.0198x over previous
//
#include <hip/hip_runtime.h>
#include <math.h>

typedef unsigned long long u64;
typedef unsigned int u32;
typedef _Float16 h8v __attribute__((ext_vector_type(8)));  // 8 fp16 (4 VGPRs)
typedef float    f4v __attribute__((ext_vector_type(4)));  // MFMA acc
typedef float    f2v __attribute__((ext_vector_type(2)));  // v_pk_*_f32 pair

#define MFMA16(a,b,c) __builtin_amdgcn_mfma_f32_16x16x32_f16(a, b, c, 0, 0, 0)

#define B_ 4
#define N_ 8192
#define K_ 16
#define W0_ 64
#define W1_ 128
#define W2_ 256
#define X0_ 96   // padded K-dim layer-1 inputs (64 feat + 3 coord + 29 zero)
#define X1_ 160  // padded K-dim layer-2 inputs (128 feat + 3 coord + 29 zero)

// ---------------- merged prep: points + all weight conversions in ONE dispatch ----------------
// blocks [0, 8192): 4 points each -> coords4, fx0, fx1 tail
// blocks [8192, 8320): wconv layer1 (DIN=64,  DOUT=128, XDIM=96)
// blocks [8320, 8576): wconv layer2 (DIN=128, DOUT=256, XDIM=160)
// blocks [8576, 8832): head1 weight transpose -> fp16
__global__ __launch_bounds__(256) void prep_kernel(
    const float* __restrict__ x,
    const float* __restrict__ stem_w, const float* __restrict__ stem_b,
    const float* __restrict__ hmix_a, const float* __restrict__ hmix_b,
    const float* __restrict__ hmix_c,
    float* __restrict__ coords4, _Float16* __restrict__ fx0,
    _Float16* __restrict__ fx1,
    const float* __restrict__ b1_w, const float* __restrict__ b2_w,
    const float* __restrict__ h1w,
    _Float16* __restrict__ w1m, _Float16* __restrict__ w1d,
    _Float16* __restrict__ w2m, _Float16* __restrict__ w2d,
    _Float16* __restrict__ h1wT) {
  const int bi = blockIdx.x;
  const int tid = threadIdx.x;
  const int PB = (B_*N_)/4;          // 8192
  if (bi < PB) {
    const int p = bi * 4 + (tid >> 6);
    const int o = tid & 63;
    const float x0 = x[p*4+0], x1 = x[p*4+1], x2 = x[p*4+2], x3 = x[p*4+3];
    const float z = hmix_a[0]*x2 + hmix_b[0]*x3 + hmix_c[0];
    float acc = stem_b[o] + x0*stem_w[0*W0_+o] + x1*stem_w[1*W0_+o]
              + x2*stem_w[2*W0_+o] + x3*stem_w[3*W0_+o];
    fx0[p*X0_+o] = (_Float16)fmaxf(acc, 0.f);
    if (o < 32) {   // tail: 3 coords + 29 zeros (both layers' inputs)
      const float tv = (o==0) ? x0 : (o==1) ? x1 : (o==2) ? z : 0.f;
      fx0[p*X0_+W0_+o] = (_Float16)tv;
      fx1[(size_t)p*X1_+W1_+o] = (_Float16)tv;
    }
    if (o == 0) {
      const float xx = x0*x0 + x1*x1 + z*z;
      ((float4*)coords4)[p] = make_float4(x0, x1, z, xx);
    }
  } else if (bi < PB + W1_) {        // wconv layer1
    const int o = bi - PB, c = tid;
    if (c < X0_) {
      float mv = 0.f, dv = 0.f;
      if (c < W0_)        { const float wm = b1_w[(W0_+c)*W1_+o]; mv = wm; dv = b1_w[c*W1_+o] - wm; }
      else if (c < W0_+3) { const float wp = b1_w[(2*W0_+(c-W0_))*W1_+o]; mv = wp; dv = -wp; }
      w1m[o*X0_+c] = (_Float16)mv;
      w1d[o*X0_+c] = (_Float16)dv;
    }
  } else if (bi < PB + W1_ + W2_) {  // wconv layer2
    const int o = bi - PB - W1_, c = tid;
    if (c < X1_) {
      float mv = 0.f, dv = 0.f;
      if (c < W1_)        { const float wm = b2_w[(W1_+c)*W2_+o]; mv = wm; dv = b2_w[c*W2_+o] - wm; }
      else if (c < W1_+3) { const float wp = b2_w[(2*W1_+(c-W1_))*W2_+o]; mv = wp; dv = -wp; }
      w2m[o*X1_+c] = (_Float16)mv;
      w2d[o*X1_+c] = (_Float16)dv;
    }
  } else {                           // head1 transpose
    const int o = bi - PB - W1_ - W2_;
    for (int c = tid; c < 512; c += 256)
      h1wT[(size_t)o*512 + c] = (_Float16)h1w[(size_t)c*256 + o];
  }
}

// ---------------- knn: 4 waves x 4 points, packed-f32 distances, threshold pre-pass ----------------
// Selection exact (see r9 bound proof); UNCHANGED from r13 (control dispatch).
#define DPP_SHR1(v) __builtin_amdgcn_update_dpp(0, (v), 0x138, 0xF, 0xF, false)

#define DPP_MIN(v, ctrl)                                                        \
  { const int _t = __builtin_amdgcn_update_dpp(__float_as_int(v),               \
      __float_as_int(v), ctrl, 0xF, 0xF, false);                                \
    v = fminf(v, __int_as_float(_t)); }

__device__ __forceinline__ float sixteenth_of_minima(float v) {
  float th = 0.f;
#pragma unroll
  for (int r = 0; r < 16; ++r) {
    float w = v;
    DPP_MIN(w, 0x111); DPP_MIN(w, 0x112); DPP_MIN(w, 0x114); DPP_MIN(w, 0x118);
    DPP_MIN(w, 0x142); DPP_MIN(w, 0x143);   // row_bcast15 / row_bcast31
    const float mv = __int_as_float(
        __builtin_amdgcn_readlane(__float_as_int(w), 63));
    th = mv;
    v = (v == mv) ? INFINITY : v;
  }
  return th;
}

#define KNN_EVT(d, dk, ik)                                                      \
  {                                                                             \
    const int s = (int)__ffsll((unsigned long long)m) - 1;  m &= m - 1;         \
    const float dc = __int_as_float(__builtin_amdgcn_readlane(                  \
                       __float_as_int(d), s));                                  \
    const bool cnd = dc < dk;                                                   \
    const u64 cm = __ballot(cnd) << 1;                                          \
    const float pd = __int_as_float(DPP_SHR1(__float_as_int(dk)));              \
    const int   pi = DPP_SHR1(ik);                                              \
    const bool pc = (cm >> lane) & 1;                                           \
    dk = cnd ? (pc ? pd : dc) : dk;                                             \
    ik = cnd ? (pc ? pi : (jbase + s)) : ik;                                    \
  }

#define KNN_CHUNK(d, dk, ik, T, Th)                                             \
  { u64 m = __ballot(d <= T);                                                   \
    if (m) {                                                                    \
      do { KNN_EVT(d, dk, ik) } while (m);                                      \
      T = fminf(Th, __int_as_float(__builtin_amdgcn_readlane(                   \
            __float_as_int(dk), 15)));                                          \
    }                                                                           \
  }

#define KNN_DIST2(dA, dB)                                                       \
  const f2v cjx = {cj.x, cj.x}, cjy = {cj.y, cj.y},                             \
            cjz = {cj.z, cj.z}, cjw = {cj.w, cj.w};                             \
  f2v tA = cAx * cjx;                                                           \
  tA = __builtin_elementwise_fma(cAy, cjy, tA);                                 \
  tA = __builtin_elementwise_fma(cAz, cjz, tA);                                 \
  const f2v dA = __builtin_elementwise_fma(tA, m2, cAw + cjw);                  \
  f2v tB = cBx * cjx;                                                           \
  tB = __builtin_elementwise_fma(cBy, cjy, tB);                                 \
  tB = __builtin_elementwise_fma(cBz, cjz, tB);                                 \
  const f2v dB = __builtin_elementwise_fma(tB, m2, cBw + cjw);

__global__ __launch_bounds__(256, 8) void knn_kernel(
    const float* __restrict__ coords4, int* __restrict__ knn_idx) {
  const int tid = threadIdx.x;
  const int wid = tid >> 6;
  const int lane = tid & 63;
  const int p0 = blockIdx.x * 16 + wid * 4;   // block of 16 never straddles batch
  const int b = p0 >> 13;
  const float4* cb = ((const float4*)coords4) + (b << 13);
  const float4 c0 = ((const float4*)coords4)[p0+0];
  const float4 c1 = ((const float4*)coords4)[p0+1];
  const float4 c2 = ((const float4*)coords4)[p0+2];
  const float4 c3 = ((const float4*)coords4)[p0+3];
  const f2v m2 = {-2.f, -2.f};
  const f2v cAx = {c0.x, c1.x}, cAy = {c0.y, c1.y}, cAz = {c0.z, c1.z}, cAw = {c0.w, c1.w};
  const f2v cBx = {c2.x, c3.x}, cBy = {c2.y, c3.y}, cBz = {c2.z, c3.z}, cBw = {c2.w, c3.w};

  // ---- pass A: per-lane minima over the first half (straight-line, no events)
  float lm0 = INFINITY, lm1 = INFINITY, lm2 = INFINITY, lm3 = INFINITY;
  for (int it = 0; it < 64; ++it) {
    const float4 cj = cb[it*64 + lane];
    KNN_DIST2(dA, dB)
    lm0 = fminf(lm0, fmaxf(dA[0], 0.f));
    lm1 = fminf(lm1, fmaxf(dA[1], 0.f));
    lm2 = fminf(lm2, fmaxf(dB[0], 0.f));
    lm3 = fminf(lm3, fmaxf(dB[1], 0.f));
  }
  const float Th0 = sixteenth_of_minima(lm0);
  const float Th1 = sixteenth_of_minima(lm1);
  const float Th2 = sixteenth_of_minima(lm2);
  const float Th3 = sixteenth_of_minima(lm3);

  float dk0 = INFINITY, dk1 = INFINITY, dk2 = INFINITY, dk3 = INFINITY;
  int   ik0 = 0, ik1 = 0, ik2 = 0, ik3 = 0;
  float T0 = Th0, T1 = Th1, T2 = Th2, T3 = Th3;

  // ---- main pass: all candidates, events only below the tight bound
  for (int it = 0; it < N_/64; ++it) {
    const int jbase = it*64;
    const float4 cj = cb[jbase + lane];
    KNN_DIST2(dA, dB)
    const float d0 = fmaxf(dA[0], 0.f);
    const float d1 = fmaxf(dA[1], 0.f);
    const float d2 = fmaxf(dB[0], 0.f);
    const float d3 = fmaxf(dB[1], 0.f);
    KNN_CHUNK(d0, dk0, ik0, T0, Th0);
    KNN_CHUNK(d1, dk1, ik1, T1, Th1);
    KNN_CHUNK(d2, dk2, ik2, T2, Th2);
    KNN_CHUNK(d3, dk3, ik3, T3, Th3);
  }

  if (lane < K_) {
    knn_idx[(size_t)(p0+0)*K_ + lane] = ik0;
    knn_idx[(size_t)(p0+1)*K_ + lane] = ik1;
    knn_idx[(size_t)(p0+2)*K_ + lane] = ik2;
    knn_idx[(size_t)(p0+3)*K_ + lane] = ik3;
  }
}

// ---------------- MFMA local_agg: transposed layout + LDS dbuf + optional fused gmax ----------------
// r12/r13 structure; GMAX adds block-local max + one atomicMax(u32) per output
// per block (valid float order: all values >= 0 after relu).
template<int KS, int NPASS, bool GMAX>
__global__ __launch_bounds__(256) void aggm_kernel(
    const _Float16* __restrict__ fx, const int* __restrict__ knn_idx,
    const _Float16* __restrict__ midT, const _Float16* __restrict__ difT,
    const float* __restrict__ bw,
    _Float16* __restrict__ fo, const int ostr, u32* __restrict__ part) {
  const int XD  = KS*32;
  const int XDP = XD + 8;               // +16B pad per row
  const int CH  = KS*4;                 // uint4 chunks per row
  const int p0 = blockIdx.x * 16;
  const int bb = (p0 >> 13) << 13;
  const int tid = threadIdx.x;
  const int w = tid >> 6, lane = tid & 63, col = lane & 15, quad = lane >> 4;
  const int koff = quad * 8;

  __shared__ int s_idx[256];            // [point m][k]
  __shared__ _Float16 sA[2][16*(KS*32+8)];

  s_idx[tid] = knn_idx[p0*K_ + tid];

  // ---- C part (k-independent): A = own 16 point rows, B = difT ----
  f4v cacc[NPASS][2];
  {
    h8v Ao[KS];
    const _Float16* ap = fx + (size_t)(p0+col)*XD + koff;
#pragma unroll
    for (int kk = 0; kk < KS; ++kk) Ao[kk] = *(const h8v*)(ap + kk*32);
#pragma unroll
    for (int ps = 0; ps < NPASS; ++ps) {
      const int o0 = ps*128 + w*32;
      const _Float16* b0 = difT + (size_t)(o0 + col)*XD + koff;
      const _Float16* b1 = difT + (size_t)(o0 + 16 + col)*XD + koff;
      f4v c0 = {0.f,0.f,0.f,0.f}, c1 = {0.f,0.f,0.f,0.f};
#pragma unroll
      for (int kk = 0; kk < KS; ++kk) {
        c0 = MFMA16(Ao[kk], *(const h8v*)(b0 + kk*32), c0);
        c1 = MFMA16(Ao[kk], *(const h8v*)(b1 + kk*32), c1);
      }
      cacc[ps][0] = c0; cacc[ps][1] = c1;
    }
  }

  // ---- B fragments for ALL passes in registers ----
  h8v Bf[NPASS][2][KS];
  float bias[NPASS][2];
#pragma unroll
  for (int ps = 0; ps < NPASS; ++ps) {
    const int o0 = ps*128 + w*32;
#pragma unroll
    for (int kk = 0; kk < KS; ++kk) {
      Bf[ps][0][kk] = *(const h8v*)(midT + (size_t)(o0 + col)*XD + kk*32 + koff);
      Bf[ps][1][kk] = *(const h8v*)(midT + (size_t)(o0 + 16 + col)*XD + kk*32 + koff);
    }
    bias[ps][0] = bw[o0 + col];
    bias[ps][1] = bw[o0 + 16 + col];
  }
  __syncthreads();   // s_idx ready

  // ---- stage k=0 ----
  for (int c = tid; c < 16*CH; c += 256) {
    const int r = c / CH, o = c - r*CH;
    *(uint4*)&sA[0][r*XDP + o*8] =
        *(const uint4*)(fx + (size_t)(bb + s_idx[r<<4])*XD + o*8);
  }
  __syncthreads();

  f4v M[NPASS][2];
#pragma unroll
  for (int ps = 0; ps < NPASS; ++ps) {
    M[ps][0] = (f4v){-INFINITY,-INFINITY,-INFINITY,-INFINITY};
    M[ps][1] = (f4v){-INFINITY,-INFINITY,-INFINITY,-INFINITY};
  }

  for (int k = 0; k < 16; ++k) {
    const int buf = k & 1;
    if (k < 15) {   // stage k+1 into the other buffer
      for (int c = tid; c < 16*CH; c += 256) {
        const int r = c / CH, o = c - r*CH;
        *(uint4*)&sA[buf^1][r*XDP + o*8] =
            *(const uint4*)(fx + (size_t)(bb + s_idx[(r<<4) + k + 1])*XD + o*8);
      }
    }
    h8v Ac[KS];
    const _Float16* ap = &sA[buf][col*XDP + koff];
#pragma unroll
    for (int kk = 0; kk < KS; ++kk) Ac[kk] = *(const h8v*)(ap + kk*32);
#pragma unroll
    for (int ps = 0; ps < NPASS; ++ps) {
      f4v d0 = {0.f,0.f,0.f,0.f}, d1 = {0.f,0.f,0.f,0.f};
#pragma unroll
      for (int kk = 0; kk < KS; ++kk) {
        d0 = MFMA16(Ac[kk], Bf[ps][0][kk], d0);
        d1 = MFMA16(Ac[kk], Bf[ps][1][kk], d1);
      }
#pragma unroll
      for (int e = 0; e < 4; ++e) {
        M[ps][0][e] = fmaxf(M[ps][0][e], d0[e]);
        M[ps][1][e] = fmaxf(M[ps][1][e], d1[e]);
      }
    }
    __syncthreads();   // staged data visible; readers done before overwrite
  }

  // ---- epilogue: out[p][o] = max(M + C + bias, 0); lane holds rows quad*4+reg ----
  const int prow = p0 + (quad << 2);
  const int bq = p0 >> 13;
#pragma unroll
  for (int ps = 0; ps < NPASS; ++ps) {
    const int o0 = ps*128 + w*32;
    const int oa = o0 + col, ob = oa + 16;
    float v0[4], v1[4];
#pragma unroll
    for (int reg = 0; reg < 4; ++reg) {
      v0[reg] = fmaxf(M[ps][0][reg] + cacc[ps][0][reg] + bias[ps][0], 0.f);
      v1[reg] = fmaxf(M[ps][1][reg] + cacc[ps][1][reg] + bias[ps][1], 0.f);
      fo[(size_t)(prow+reg)*ostr + oa] = (_Float16)v0[reg];
      fo[(size_t)(prow+reg)*ostr + ob] = (_Float16)v1[reg];
    }
    if (GMAX) {   // block-local max over 16 points, then one atomic per output
      float bm0 = fmaxf(fmaxf(v0[0], v0[1]), fmaxf(v0[2], v0[3]));
      float bm1 = fmaxf(fmaxf(v1[0], v1[1]), fmaxf(v1[2], v1[3]));
      bm0 = fmaxf(bm0, __shfl_xor(bm0, 16, 64));
      bm0 = fmaxf(bm0, __shfl_xor(bm0, 32, 64));
      bm1 = fmaxf(bm1, __shfl_xor(bm1, 16, 64));
      bm1 = fmaxf(bm1, __shfl_xor(bm1, 32, 64));
      if (quad == 0) {
        atomicMax(part + bq*W2_ + oa, __float_as_uint(bm0));
        atomicMax(part + bq*W2_ + ob, __float_as_uint(bm1));
      }
    }
  }
}

// ---------------- glob FC from fused-max part -> g2h fp16 ----------------
__global__ __launch_bounds__(256) void gfc_kernel(
    const float* __restrict__ part, const float* __restrict__ gw,
    const float* __restrict__ gb, _Float16* __restrict__ g2h) {
  const int b = blockIdx.x;
  const int o = threadIdx.x;
  __shared__ float s_g[W2_];
  s_g[o] = part[b*W2_ + o];   // bits written by atomicMax(u32) == float bits (>=0)
  __syncthreads();
  float acc = gb[o];
  for (int d = 0; d < W2_; ++d) acc += s_g[d]*gw[d*W2_ + o];
  g2h[b*W2_ + o] = (_Float16)fmaxf(acc, 0.f);
}

// ---------------- head: 32 points/block MFMA GEMM + tiny second layer ----------------
__global__ __launch_bounds__(256) void headm_kernel(
    const _Float16* __restrict__ f2h, const _Float16* __restrict__ g2h,
    const _Float16* __restrict__ h1wT, const float* __restrict__ h1b,
    const float* __restrict__ h2w, const float* __restrict__ h2b,
    const float* __restrict__ x,
    const float* __restrict__ thresh, const float* __restrict__ sharp,
    const float* __restrict__ scale,
    float* __restrict__ out) {
  const int p0 = blockIdx.x * 32;
  const int b = p0 >> 13;
  const int tid = threadIdx.x;
  const int w = tid >> 6, lane = tid & 63, col = lane & 15, quad = lane >> 4;

  __shared__ _Float16 sA[32*520];   // 32 points x 512 (padded to 520)
  __shared__ float    sh[32*260];   // relu(h1) f32

  for (int t = tid; t < 32*32; t += 256) {       // f2h part (16B chunks)
    const int r = t >> 5, cc = (t & 31) * 8;
    *(uint4*)&sA[r*520 + cc] = *(const uint4*)&f2h[(size_t)(p0+r)*W2_ + cc];
  }
  for (int t = tid; t < 32*32; t += 256) {       // g2h broadcast part
    const int r = t >> 5, cc = (t & 31) * 8;
    *(uint4*)&sA[r*520 + 256 + cc] = *(const uint4*)&g2h[b*W2_ + cc];
  }
  __syncthreads();

  f4v acc[2][4];
#pragma unroll
  for (int r = 0; r < 2; ++r)
#pragma unroll
    for (int t = 0; t < 4; ++t) acc[r][t] = (f4v){0.f,0.f,0.f,0.f};

  for (int kk = 0; kk < 16; ++kk) {
    const h8v a0 = *(const h8v*)&sA[col*520 + kk*32 + quad*8];
    const h8v a1 = *(const h8v*)&sA[(16+col)*520 + kk*32 + quad*8];
#pragma unroll
    for (int t = 0; t < 4; ++t) {
      const h8v bt = *(const h8v*)&h1wT[(size_t)(w*64 + t*16 + col)*512 + kk*32 + quad*8];
      acc[0][t] = MFMA16(a0, bt, acc[0][t]);
      acc[1][t] = MFMA16(a1, bt, acc[1][t]);
    }
  }
#pragma unroll
  for (int r = 0; r < 2; ++r)
#pragma unroll
    for (int t = 0; t < 4; ++t) {
      const int o = w*64 + t*16 + col;
      const float bv = h1b[o];
#pragma unroll
      for (int reg = 0; reg < 4; ++reg)
        sh[(r*16 + quad*4 + reg)*260 + o] = fmaxf(acc[r][t][reg] + bv, 0.f);
    }
  __syncthreads();

  if (tid < 96) {
    const int pp = tid / 3, c = tid % 3;
    float s = h2b[c];
    for (int d = 0; d < 256; ++d) s += sh[pp*260 + d] * h2w[d*3 + c];
    if (c == 0) {
      const float hag = x[(size_t)(p0+pp)*4 + 3];
      s += scale[0] / (1.f + expf(-sharp[0]*(thresh[0] - hag)));
    }
    out[(size_t)(p0+pp)*3 + c] = s;
  }
}

// ---------------- launch ----------------
extern "C" void kernel_launch(void* const* d_in, const int* in_sizes, int n_in,
                              void* d_out, int out_size, void* d_ws, size_t ws_size,
                              hipStream_t stream) {
  const float* x       = (const float*)d_in[0];
  const float* hmix_a  = (const float*)d_in[1];
  const float* hmix_b  = (const float*)d_in[2];
  const float* hmix_c  = (const float*)d_in[3];
  const float* stem_w  = (const float*)d_in[4];
  const float* stem_b  = (const float*)d_in[5];
  const float* b1_w    = (const float*)d_in[6];
  const float* b1_b    = (const float*)d_in[7];
  const float* b2_w    = (const float*)d_in[8];
  const float* b2_b    = (const float*)d_in[9];
  const float* glob_w  = (const float*)d_in[10];
  const float* glob_b  = (const float*)d_in[11];
  const float* head1_w = (const float*)d_in[12];
  const float* head1_b = (const float*)d_in[13];
  const float* head2_w = (const float*)d_in[14];
  const float* head2_b = (const float*)d_in[15];
  const float* thresh  = (const float*)d_in[16];
  const float* sharp   = (const float*)d_in[17];
  const float* scale   = (const float*)d_in[18];
  float* out = (float*)d_out;

  char* base = (char*)d_ws;
  float*     coords4 = (float*)    (base + 0);          // 512 KB
  int*       idxb    = (int*)      (base + 524288);     // 2 MB
  _Float16*  fx0     = (_Float16*) (base + 2621440);    // 6 MB   (32768*96*2)
  _Float16*  fx1     = (_Float16*) (base + 8912896);    // 10 MB  (32768*160*2)
  _Float16*  f2h     = (_Float16*) (base + 19398656);   // 16 MB  (32768*256*2)
  _Float16*  w1m     = (_Float16*) (base + 36175872);   // 24 KB  (128*96*2)
  _Float16*  w1d     = (_Float16*) (base + 36200448);   // 24 KB
  _Float16*  w2m     = (_Float16*) (base + 36225024);   // 80 KB  (256*160*2)
  _Float16*  w2d     = (_Float16*) (base + 36306944);   // 80 KB
  _Float16*  h1wT    = (_Float16*) (base + 36388864);   // 256 KB (256*512*2)
  float*     part    = (float*)    (base + 36651008);   // 4 KB (4*256 f32, fused max)
  _Float16*  g2h     = (_Float16*) (base + 36782080);   // 2 KB

  const int NP = B_ * N_;   // 32768 points

  prep_kernel<<<NP/4 + W1_ + 2*W2_, 256, 0, stream>>>(
      x, stem_w, stem_b, hmix_a, hmix_b, hmix_c, coords4, fx0, fx1,
      b1_w, b2_w, head1_w, w1m, w1d, w2m, w2d, h1wT);
  hipMemsetAsync(part, 0, B_*W2_*sizeof(float), stream);
  knn_kernel<<<NP/16, 256, 0, stream>>>(coords4, idxb);
  aggm_kernel<3, 1, false><<<NP/16, 256, 0, stream>>>(
      fx0, idxb, w1m, w1d, b1_b, fx1, X1_, (u32*)0);
  aggm_kernel<5, 2, true><<<NP/16, 256, 0, stream>>>(
      fx1, idxb, w2m, w2d, b2_b, f2h, W2_, (u32*)part);
  gfc_kernel<<<B_, 256, 0, stream>>>(part, glob_w, glob_b, g2h);
  headm_kernel<<<NP/32, 256, 0, stream>>>(f2h, g2h, h1wT, head1_b, head2_w, head2_b,
                                          x, thresh, sharp, scale, out);
}